// Round 2
// baseline (2713.965 us; speedup 1.0000x reference)
//
#include <hip/hip_runtime.h>
#include <hip/hip_bf16.h>

namespace {
constexpr int cS = 16, cB = 16, cC = 256, cH = 4, cDH = 64, cHW = 293;
constexpr int cLQ = cS * cHW;      // 4688
constexpr int cLK = 128;
constexpr int cN  = cLQ * cB;      // 75008
constexpr size_t TX_OFF = 25600;         // 5120 + 16384 + 4096
constexpr size_t HX_OFF = 2122752;       // TX_OFF + 16*16*2*64*64
}

typedef unsigned short ushort_t;
typedef unsigned int uint_t;

__device__ __forceinline__ float bf2f(ushort_t u) {
  return __uint_as_float(((uint_t)u) << 16);
}
__device__ __forceinline__ ushort_t f2bf(float f) {
  __hip_bfloat16 h = __float2bfloat16(f);
  return *(ushort_t*)&h;
}
__device__ __forceinline__ float unlo(uint_t u) { return __uint_as_float(u << 16); }
__device__ __forceinline__ float unhi(uint_t u) { return __uint_as_float(u & 0xffff0000u); }

// ---------------- xq build + LayerNorm1 -> qn (bf16) ----------------
__global__ __launch_bounds__(256) void k_qn(
    const int* __restrict__ tq, const float* __restrict__ spatial,
    const float* __restrict__ temporal, const float* __restrict__ g,
    const float* __restrict__ bt, ushort_t* __restrict__ qn)
{
  int r = blockIdx.x;            // r = q*cB + b
  int b = r & 15, q = r >> 4;
  int s = q / cHW, hw = q % cHW;
  int t = tq[s * cB + b];
  int c = threadIdx.x;
  float v = temporal[t * cC + c] + spatial[hw * cC + c];
  float sum = v, sum2 = v * v;
  #pragma unroll
  for (int off = 32; off >= 1; off >>= 1) {
    sum  += __shfl_xor(sum,  off, 64);
    sum2 += __shfl_xor(sum2, off, 64);
  }
  __shared__ float rs[4], rs2[4];
  int wid = threadIdx.x >> 6;
  if ((threadIdx.x & 63) == 0) { rs[wid] = sum; rs2[wid] = sum2; }
  __syncthreads();
  float S1 = rs[0] + rs[1] + rs[2] + rs[3];
  float S2 = rs2[0] + rs2[1] + rs2[2] + rs2[3];
  float mean = S1 * (1.0f / cC);
  float var  = S2 * (1.0f / cC) - mean * mean;
  float inv  = rsqrtf(var + 1e-5f);
  qn[(size_t)r * cC + c] = f2bf((v - mean) * inv * g[c] + bt[c]);
}

// ---------------- K/V projection -> bf16 [b,h,k,d] ----------------
__global__ __launch_bounds__(256) void k_kv(
    const float* __restrict__ xk,
    const float* __restrict__ wk, const float* __restrict__ bk,
    const float* __restrict__ wv, const float* __restrict__ bv,
    ushort_t* __restrict__ Kt, ushort_t* __restrict__ Vt)
{
  const int row0 = blockIdx.x * 16;
  const int col  = threadIdx.x;
  const float* W  = blockIdx.y ? wv : wk;
  const float* Bi = blockIdx.y ? bv : bk;
  ushort_t* Out   = blockIdx.y ? Vt : Kt;
  float acc[16];
  float bvv = Bi[col];
  #pragma unroll
  for (int r = 0; r < 16; ++r) acc[r] = bvv;
  const float* Ap = xk + (size_t)row0 * cC;
  for (int c = 0; c < cC; c += 4) {
    float w0 = W[(c + 0) * cC + col];
    float w1 = W[(c + 1) * cC + col];
    float w2 = W[(c + 2) * cC + col];
    float w3 = W[(c + 3) * cC + col];
    #pragma unroll
    for (int r = 0; r < 16; ++r) {
      float4 av = *(const float4*)(Ap + (size_t)r * cC + c);
      acc[r] = fmaf(av.x, w0, fmaf(av.y, w1, fmaf(av.z, w2, fmaf(av.w, w3, acc[r]))));
    }
  }
  int h = col >> 6, d = col & 63;
  #pragma unroll
  for (int r = 0; r < 16; ++r) {
    int rg = row0 + r;
    int k = rg >> 4, b = rg & 15;      // xk rows are (k, b)
    Out[(((size_t)(b * cH + h)) * cLK + k) * cDH + d] = f2bf(acc[r]);
  }
}

// ---------------- Q projection (A bf16) -> bf16 [b,h,q,d] ----------------
__global__ __launch_bounds__(256) void k_qproj(
    const ushort_t* __restrict__ A, const float* __restrict__ W,
    const float* __restrict__ Bi, ushort_t* __restrict__ Qt)
{
  const int row0 = blockIdx.x * 16;
  const int col  = threadIdx.x;
  float acc[16];
  float bvv = Bi[col];
  #pragma unroll
  for (int r = 0; r < 16; ++r) acc[r] = bvv;
  const ushort_t* Ap = A + (size_t)row0 * cC;
  for (int c = 0; c < cC; c += 4) {
    float w0 = W[(c + 0) * cC + col];
    float w1 = W[(c + 1) * cC + col];
    float w2 = W[(c + 2) * cC + col];
    float w3 = W[(c + 3) * cC + col];
    #pragma unroll
    for (int r = 0; r < 16; ++r) {
      uint2 hv = *(const uint2*)(Ap + (size_t)r * cC + c);
      acc[r] = fmaf(unlo(hv.x), w0, fmaf(unhi(hv.x), w1,
               fmaf(unlo(hv.y), w2, fmaf(unhi(hv.y), w3, acc[r]))));
    }
  }
  int h = col >> 6, d = col & 63;
  #pragma unroll
  for (int r = 0; r < 16; ++r) {
    int rg = row0 + r;
    int q = rg >> 4, b = rg & 15;
    Qt[(((size_t)(b * cH + h)) * cLQ + q) * cDH + d] = f2bf(acc[r]);
  }
}

// ---------------- attention: per (b,h), 32 q-rows per block ----------------
// LDS total: 16640 + 32768 + 512 + 2048 + 4096 = 56,064 B  (< 64 KB)
__global__ __launch_bounds__(256) void k_attn(
    const ushort_t* __restrict__ Qt, const ushort_t* __restrict__ Kt,
    const ushort_t* __restrict__ Vt, const int* __restrict__ tq,
    const int* __restrict__ tk, const int* __restrict__ pad_q,
    const int* __restrict__ pad_k, ushort_t* __restrict__ aout)
{
  __shared__ ushort_t KtL[64 * 130];  // [d][k] bf16, stride 130
  __shared__ float Vl[128 * 64];      // [k][d] fp32
  __shared__ int   tkL[128];
  __shared__ float qrL[4][128];       // per-wave: 2 q rows
  __shared__ float pL[4][256];        // per-wave: 2 x 128 probs

  const int h = blockIdx.y, b = blockIdx.z;
  const int tid = threadIdx.x;
  const int lane = tid & 63, w = tid >> 6;
  const size_t kvbase = ((size_t)(b * cH + h)) * cLK * cDH;
  // K: bf16 -> bf16 transpose [k][d] -> [d][k]
  for (int i = tid; i < cLK * cDH; i += 256) {
    int k = i >> 6, d = i & 63;
    KtL[d * 130 + k] = Kt[kvbase + i];
  }
  // V: bf16 -> fp32, same layout
  const uint_t* Vg = (const uint_t*)(Vt + kvbase);
  for (int i = tid; i < cLK * cDH / 2; i += 256) {
    uint_t u = Vg[i];
    Vl[2 * i]     = unlo(u);
    Vl[2 * i + 1] = unhi(u);
  }
  if (tid < 128) tkL[tid] = tk[tid * cB + b];
  __syncthreads();
  const int pk = pad_k[b];
  const int pq = pad_q[b] * cHW;
  const size_t qbase = ((size_t)(b * cH + h)) * cLQ;

  for (int pr = 0; pr < 4; ++pr) {
    int q0 = blockIdx.x * 32 + w * 8 + pr * 2;
    if (q0 >= cLQ) continue;                  // wave-uniform
    int q1 = q0 + 1;
    bool has1 = (q1 < cLQ);
    int q1c = has1 ? q1 : q0;
    qrL[w][lane]      = bf2f(Qt[(qbase + q0) * cDH + lane]);
    qrL[w][64 + lane] = bf2f(Qt[(qbase + q1c) * cDH + lane]);
    float s00 = 0.f, s01 = 0.f, s10 = 0.f, s11 = 0.f;
    #pragma unroll 8
    for (int d = 0; d < 64; ++d) {
      float k0 = bf2f(KtL[d * 130 + lane]);
      float k1 = bf2f(KtL[d * 130 + 64 + lane]);
      float q0v = qrL[w][d];
      float q1v = qrL[w][64 + d];
      s00 = fmaf(q0v, k0, s00); s01 = fmaf(q0v, k1, s01);
      s10 = fmaf(q1v, k0, s10); s11 = fmaf(q1v, k1, s11);
    }
    int t0 = tq[(q0 / cHW) * cB + b];
    int t1 = tq[(q1c / cHW) * cB + b];
    bool qa0 = (q0 < pq), qa1 = (q1c < pq);
    int tk0 = tkL[lane], tk1 = tkL[64 + lane];
    bool k0ok = (lane < pk), k1ok = (64 + lane < pk);
    s00 = (qa0 && tk0 <= t0 && k0ok) ? s00 * 0.125f : -1e9f;
    s01 = (qa0 && tk1 <= t0 && k1ok) ? s01 * 0.125f : -1e9f;
    s10 = (qa1 && tk0 <= t1 && k0ok) ? s10 * 0.125f : -1e9f;
    s11 = (qa1 && tk1 <= t1 && k1ok) ? s11 * 0.125f : -1e9f;
    float m0 = fmaxf(s00, s01), m1 = fmaxf(s10, s11);
    #pragma unroll
    for (int off = 32; off >= 1; off >>= 1) {
      m0 = fmaxf(m0, __shfl_xor(m0, off, 64));
      m1 = fmaxf(m1, __shfl_xor(m1, off, 64));
    }
    float p00 = __expf(s00 - m0), p01 = __expf(s01 - m0);
    float p10 = __expf(s10 - m1), p11 = __expf(s11 - m1);
    float l0 = p00 + p01, l1 = p10 + p11;
    #pragma unroll
    for (int off = 32; off >= 1; off >>= 1) {
      l0 += __shfl_xor(l0, off, 64);
      l1 += __shfl_xor(l1, off, 64);
    }
    float i0 = 1.0f / l0, i1 = 1.0f / l1;
    pL[w][lane]       = p00 * i0;
    pL[w][64 + lane]  = p01 * i0;
    pL[w][128 + lane] = p10 * i1;
    pL[w][192 + lane] = p11 * i1;
    float o0 = 0.f, o1 = 0.f;
    #pragma unroll 8
    for (int k = 0; k < 128; ++k) {
      float vv = Vl[k * 64 + lane];
      o0 = fmaf(pL[w][k], vv, o0);
      o1 = fmaf(pL[w][128 + k], vv, o1);
    }
    aout[((size_t)q0 * cB + b) * cC + h * cDH + lane] = f2bf(o0);
    if (has1) aout[((size_t)q1 * cB + b) * cC + h * cDH + lane] = f2bf(o1);
  }
}

// ---------------- wo projection + recomputed-xq residual -> x (bf16) ----------------
__global__ __launch_bounds__(256) void k_wo(
    const ushort_t* __restrict__ A, const float* __restrict__ W,
    const float* __restrict__ Bi, const int* __restrict__ tq,
    const float* __restrict__ spatial, const float* __restrict__ temporal,
    ushort_t* __restrict__ xout)
{
  const int row0 = blockIdx.x * 16;
  const int col  = threadIdx.x;
  float acc[16];
  float bvv = Bi[col];
  #pragma unroll
  for (int r = 0; r < 16; ++r) acc[r] = bvv;
  const ushort_t* Ap = A + (size_t)row0 * cC;
  for (int c = 0; c < cC; c += 4) {
    float w0 = W[(c + 0) * cC + col];
    float w1 = W[(c + 1) * cC + col];
    float w2 = W[(c + 2) * cC + col];
    float w3 = W[(c + 3) * cC + col];
    #pragma unroll
    for (int r = 0; r < 16; ++r) {
      uint2 hv = *(const uint2*)(Ap + (size_t)r * cC + c);
      acc[r] = fmaf(unlo(hv.x), w0, fmaf(unhi(hv.x), w1,
               fmaf(unlo(hv.y), w2, fmaf(unhi(hv.y), w3, acc[r]))));
    }
  }
  // residual xq = temporal[t] + spatial[hw], recomputed
  const int q = row0 >> 4;               // all 16 rows share q
  const int s = q / cHW, hw = q % cHW;
  const float sp = spatial[hw * cC + col];
  #pragma unroll
  for (int r = 0; r < 16; ++r) {
    int t = tq[s * cB + r];              // b == r
    float xqv = temporal[t * cC + col] + sp;
    xout[(size_t)(row0 + r) * cC + col] = f2bf(acc[r] + xqv);
  }
}

// ---------------- fused LN2 + FFN1(gelu) + FFN2 + residual -> x2 (bf16) ----------------
// LDS: xlnT fp32 [256][16] = 16 KB ; hT bf16 [1024][16] = 32 KB  -> 48 KB
__global__ __launch_bounds__(256) void k_ffn(
    const ushort_t* __restrict__ xg, const float* __restrict__ g,
    const float* __restrict__ bt, const float* __restrict__ w1,
    const float* __restrict__ b1, const float* __restrict__ w2,
    const float* __restrict__ b2, ushort_t* __restrict__ x2)
{
  __shared__ float    xlnT[256 * 16];   // [c][r]
  __shared__ ushort_t hT[1024 * 16];    // [c2][r]
  const int row0 = blockIdx.x * 16;
  const int tid = threadIdx.x;
  const int lane = tid & 63, w = tid >> 6;

  // ---- LN2: wave w handles rows w*4 .. w*4+3; lane covers c = lane*4..+3
  {
    const int c0 = lane * 4;
    float4 g4 = *(const float4*)(g + c0);
    float4 b4 = *(const float4*)(bt + c0);
    for (int rr = 0; rr < 4; ++rr) {
      int r = w * 4 + rr;
      uint2 hv = *(const uint2*)(xg + (size_t)(row0 + r) * cC + c0);
      float v0 = unlo(hv.x), v1 = unhi(hv.x), v2 = unlo(hv.y), v3 = unhi(hv.y);
      float sum = v0 + v1 + v2 + v3;
      float sum2 = v0 * v0 + v1 * v1 + v2 * v2 + v3 * v3;
      #pragma unroll
      for (int off = 32; off >= 1; off >>= 1) {
        sum  += __shfl_xor(sum,  off, 64);
        sum2 += __shfl_xor(sum2, off, 64);
      }
      float mean = sum * (1.0f / cC);
      float var  = sum2 * (1.0f / cC) - mean * mean;
      float inv  = rsqrtf(var + 1e-5f);
      xlnT[(c0 + 0) * 16 + r] = (v0 - mean) * inv * g4.x + b4.x;
      xlnT[(c0 + 1) * 16 + r] = (v1 - mean) * inv * g4.y + b4.y;
      xlnT[(c0 + 2) * 16 + r] = (v2 - mean) * inv * g4.z + b4.z;
      xlnT[(c0 + 3) * 16 + r] = (v3 - mean) * inv * g4.w + b4.w;
    }
  }
  __syncthreads();

  // ---- FFN1 + GELU: 4 col-blocks, thread owns col j, 16 row accumulators
  for (int cb = 0; cb < 4; ++cb) {
    const int j = cb * 256 + tid;
    float facc[16];
    float bv = b1[j];
    #pragma unroll
    for (int r = 0; r < 16; ++r) facc[r] = bv;
    for (int c = 0; c < cC; ++c) {
      float4 xa = *(const float4*)&xlnT[c * 16 + 0];
      float4 xb = *(const float4*)&xlnT[c * 16 + 4];
      float4 xc = *(const float4*)&xlnT[c * 16 + 8];
      float4 xd = *(const float4*)&xlnT[c * 16 + 12];
      float wv = w1[c * 1024 + j];
      facc[0]  = fmaf(xa.x, wv, facc[0]);  facc[1]  = fmaf(xa.y, wv, facc[1]);
      facc[2]  = fmaf(xa.z, wv, facc[2]);  facc[3]  = fmaf(xa.w, wv, facc[3]);
      facc[4]  = fmaf(xb.x, wv, facc[4]);  facc[5]  = fmaf(xb.y, wv, facc[5]);
      facc[6]  = fmaf(xb.z, wv, facc[6]);  facc[7]  = fmaf(xb.w, wv, facc[7]);
      facc[8]  = fmaf(xc.x, wv, facc[8]);  facc[9]  = fmaf(xc.y, wv, facc[9]);
      facc[10] = fmaf(xc.z, wv, facc[10]); facc[11] = fmaf(xc.w, wv, facc[11]);
      facc[12] = fmaf(xd.x, wv, facc[12]); facc[13] = fmaf(xd.y, wv, facc[13]);
      facc[14] = fmaf(xd.z, wv, facc[14]); facc[15] = fmaf(xd.w, wv, facc[15]);
    }
    #pragma unroll
    for (int r = 0; r < 16; ++r) {
      float xx = facc[r];
      float u = 0.7978845608028654f * (xx + 0.044715f * xx * xx * xx);
      float t = tanhf(u);
      hT[j * 16 + r] = f2bf(0.5f * xx * (1.0f + t));
    }
  }
  __syncthreads();

  // ---- FFN2 + residual: thread owns col j = tid
  {
    const int j = tid;
    float acc[16];
    float bv = b2[j];
    #pragma unroll
    for (int r = 0; r < 16; ++r) acc[r] = bv;
    for (int c = 0; c < 1024; ++c) {
      uint4 ha = *(const uint4*)&hT[c * 16 + 0];   // 8 bf16
      uint4 hb = *(const uint4*)&hT[c * 16 + 8];   // 8 bf16
      float wv = w2[c * cC + j];
      acc[0]  = fmaf(unlo(ha.x), wv, acc[0]);  acc[1]  = fmaf(unhi(ha.x), wv, acc[1]);
      acc[2]  = fmaf(unlo(ha.y), wv, acc[2]);  acc[3]  = fmaf(unhi(ha.y), wv, acc[3]);
      acc[4]  = fmaf(unlo(ha.z), wv, acc[4]);  acc[5]  = fmaf(unhi(ha.z), wv, acc[5]);
      acc[6]  = fmaf(unlo(ha.w), wv, acc[6]);  acc[7]  = fmaf(unhi(ha.w), wv, acc[7]);
      acc[8]  = fmaf(unlo(hb.x), wv, acc[8]);  acc[9]  = fmaf(unhi(hb.x), wv, acc[9]);
      acc[10] = fmaf(unlo(hb.y), wv, acc[10]); acc[11] = fmaf(unhi(hb.y), wv, acc[11]);
      acc[12] = fmaf(unlo(hb.z), wv, acc[12]); acc[13] = fmaf(unhi(hb.z), wv, acc[13]);
      acc[14] = fmaf(unlo(hb.w), wv, acc[14]); acc[15] = fmaf(unhi(hb.w), wv, acc[15]);
    }
    #pragma unroll
    for (int r = 0; r < 16; ++r) {
      float xr = bf2f(xg[(size_t)(row0 + r) * cC + j]);
      x2[(size_t)(row0 + r) * cC + j] = f2bf(acc[r] + xr);
    }
  }
}

// ---------------- table/hand heads + upsample scatter ----------------
__global__ __launch_bounds__(256) void k_th(
    const ushort_t* __restrict__ x2, const float* __restrict__ tw,
    const float* __restrict__ tb, const float* __restrict__ hwgt,
    const float* __restrict__ hb, float* __restrict__ out)
{
  int x = blockIdx.x;                 // s*584 + hw*2 + half
  int s = x / 584;
  int rem = x % 584;
  int hw = rem >> 1, half = rem & 1;
  int j = threadIdx.x & 31, rr = threadIdx.x >> 5;
  int b = half * 8 + rr;
  const float* W;
  const float* Bi;
  if (hw < 256) { W = tw; Bi = tb; } else { W = hwgt; Bi = hb; }
  const ushort_t* row = x2 + ((size_t)(s * cHW + hw) * cB + b) * cC;
  float acc = Bi[j];
  for (int c = 0; c < cC; c += 4) {
    uint2 hv = *(const uint2*)(row + c);
    acc = fmaf(unlo(hv.x), W[(c + 0) * 32 + j], acc);
    acc = fmaf(unhi(hv.x), W[(c + 1) * 32 + j], acc);
    acc = fmaf(unlo(hv.y), W[(c + 2) * 32 + j], acc);
    acc = fmaf(unhi(hv.y), W[(c + 3) * 32 + j], acc);
  }
  int uh = j >> 3, uw = (j >> 1) & 3, uc = j & 1;
  size_t idx;
  if (hw < 256) {
    int th = hw >> 4, twi = hw & 15;
    idx = TX_OFF + ((((size_t)(s * cB + b)) * 2 + uc) * 64 + (th * 4 + uh)) * 64 + (twi * 4 + uw);
  } else {
    int h2 = hw - 256;
    int hh = h2 / 6, ww = h2 % 6;
    idx = HX_OFF + ((((size_t)(s * cB + b)) * 2 + uc) * 24 + (hh * 4 + uh)) * 24 + (ww * 4 + uw);
  }
  out[idx] = acc;
}

// ---------------- gx heads: mode / shape / color ----------------
__global__ __launch_bounds__(128) void k_gx(
    const ushort_t* __restrict__ x2,
    const float* __restrict__ mw, const float* __restrict__ mbi,
    const float* __restrict__ sw, const float* __restrict__ sbi,
    const float* __restrict__ cw, const float* __restrict__ cbi,
    float* __restrict__ out)
{
  int sb = blockIdx.x;              // s*16 + b
  int s = sb >> 4, b = sb & 15;
  __shared__ float rowL[256];
  const ushort_t* row = x2 + ((size_t)(s * cHW + 292) * cB + b) * cC;
  for (int i = threadIdx.x; i < 256; i += 128) rowL[i] = bf2f(row[i]);
  __syncthreads();
  int j = threadIdx.x;
  if (j < 100) {
    const float* W;
    const float* Bi;
    int jj, M;
    size_t off;
    if (j < 20)      { W = mw; Bi = mbi; jj = j;      M = 20; off = 0;     }
    else if (j < 84) { W = sw; Bi = sbi; jj = j - 20; M = 64; off = 5120;  }
    else             { W = cw; Bi = cbi; jj = j - 84; M = 16; off = 21504; }
    float acc = Bi[jj];
    for (int c = 0; c < 256; ++c) acc = fmaf(rowL[c], W[c * M + jj], acc);
    out[off + (size_t)sb * M + jj] = acc;
  }
}

extern "C" void kernel_launch(void* const* d_in, const int* in_sizes, int n_in,
                              void* d_out, int out_size, void* d_ws, size_t ws_size,
                              hipStream_t stream)
{
  const int*   tq       = (const int*)d_in[0];
  const int*   pad_q    = (const int*)d_in[1];
  const float* xk       = (const float*)d_in[2];
  const int*   tk       = (const int*)d_in[3];
  const int*   pad_k    = (const int*)d_in[4];
  // d_in[5..7]: *_activate, unused by reference math
  const float* spatial  = (const float*)d_in[8];
  const float* temporal = (const float*)d_in[9];
  const float* ln1_g    = (const float*)d_in[10];
  const float* ln1_b    = (const float*)d_in[11];
  const float* wq       = (const float*)d_in[12];
  const float* bq       = (const float*)d_in[13];
  const float* wk       = (const float*)d_in[14];
  const float* bk       = (const float*)d_in[15];
  const float* wv       = (const float*)d_in[16];
  const float* bv       = (const float*)d_in[17];
  const float* wo       = (const float*)d_in[18];
  const float* bo       = (const float*)d_in[19];
  const float* ln2_g    = (const float*)d_in[20];
  const float* ln2_b    = (const float*)d_in[21];
  const float* w1       = (const float*)d_in[22];
  const float* b1       = (const float*)d_in[23];
  const float* w2       = (const float*)d_in[24];
  const float* b2       = (const float*)d_in[25];
  const float* table_w  = (const float*)d_in[26];
  const float* table_b  = (const float*)d_in[27];
  const float* hand_w   = (const float*)d_in[28];
  const float* hand_b   = (const float*)d_in[29];
  const float* mode_w   = (const float*)d_in[30];
  const float* mode_b   = (const float*)d_in[31];
  const float* shape_w  = (const float*)d_in[32];
  const float* shape_b  = (const float*)d_in[33];
  const float* color_w  = (const float*)d_in[34];
  const float* color_b  = (const float*)d_in[35];
  float* out = (float*)d_out;

  // Workspace layout (bf16 activations): total ~79 MB
  char* ws = (char*)d_ws;
  const size_t NB = (size_t)cN * cC * sizeof(ushort_t);   // 38,404,096 B
  ushort_t* buf1 = (ushort_t*)ws;                         // qn -> a -> x2
  ushort_t* buf2 = (ushort_t*)(ws + NB);                  // Qt -> x
  ushort_t* Kt   = (ushort_t*)(ws + 2 * NB);              // 1 MB
  ushort_t* Vt   = Kt + (size_t)cB * cH * cLK * cDH;      // 1 MB

  k_qn<<<cN, 256, 0, stream>>>(tq, spatial, temporal, ln1_g, ln1_b, buf1);
  k_kv<<<dim3(cLK * cB / 16, 2), 256, 0, stream>>>(xk, wk, bk, wv, bv, Kt, Vt);
  k_qproj<<<cN / 16, 256, 0, stream>>>(buf1, wq, bq, buf2);
  k_attn<<<dim3((cLQ + 31) / 32, cH, cB), 256, 0, stream>>>(buf2, Kt, Vt, tq, tk,
                                                            pad_q, pad_k, buf1);
  k_wo<<<cN / 16, 256, 0, stream>>>(buf1, wo, bo, tq, spatial, temporal, buf2);
  k_ffn<<<cN / 16, 256, 0, stream>>>(buf2, ln2_g, ln2_b, w1, b1, w2, b2, buf1);
  k_th<<<cS * 292 * 2, 256, 0, stream>>>(buf1, table_w, table_b, hand_w, hand_b, out);
  k_gx<<<cS * cB, 128, 0, stream>>>(buf1, mode_w, mode_b, shape_w, shape_b,
                                    color_w, color_b, out);
}

// Round 3
// 1542.335 us; speedup vs baseline: 1.7596x; 1.7596x over previous
//
#include <hip/hip_runtime.h>
#include <hip/hip_bf16.h>

namespace {
constexpr int cS = 16, cB = 16, cC = 256, cH = 4, cDH = 64, cHW = 293;
constexpr int cLQ = cS * cHW;      // 4688
constexpr int cLK = 128;
constexpr int cN  = cLQ * cB;      // 75008
constexpr size_t TX_OFF = 25600;         // 5120 + 16384 + 4096
constexpr size_t HX_OFF = 2122752;       // TX_OFF + 16*16*2*64*64
}

typedef unsigned short ushort_t;
typedef unsigned int uint_t;
typedef __attribute__((ext_vector_type(8))) short short8;    // 8 bf16 (4 VGPRs)
typedef __attribute__((ext_vector_type(4))) float f32x4;     // MFMA C/D frag

__device__ __forceinline__ float bf2f(ushort_t u) {
  return __uint_as_float(((uint_t)u) << 16);
}
__device__ __forceinline__ ushort_t f2bf(float f) {
  __hip_bfloat16 h = __float2bfloat16(f);
  return *(ushort_t*)&h;
}

// ============ weight swizzle: W[K][N] fp32 -> frag order bf16 ============
// Ws slot (kc, nb, lane): 8 elems W[kc*32 + (lane>>4)*8 + i][nb*16 + (lane&15)]
__global__ __launch_bounds__(256) void k_swz(
    const float* __restrict__ W, ushort_t* __restrict__ Ws, int N)
{
  int slot = blockIdx.x * 256 + threadIdx.x;
  int lane = slot & 63;
  int fr   = slot >> 6;            // kc*(N/16) + nb
  int NB   = N >> 4;
  int nb   = fr % NB, kc = fr / NB;
  int n    = nb * 16 + (lane & 15);
  int k0   = kc * 32 + (lane >> 4) * 8;
  ushort_t tmp[8];
  #pragma unroll
  for (int i = 0; i < 8; ++i) tmp[i] = f2bf(W[(size_t)(k0 + i) * N + n]);
  *(uint4*)&Ws[(size_t)slot * 8] = *(uint4*)tmp;
}

// ============ fp32 -> bf16 convert ============
__global__ __launch_bounds__(256) void k_cvt(
    const float* __restrict__ src, ushort_t* __restrict__ dst, int n)
{
  int i = blockIdx.x * 256 + threadIdx.x;
  if (i < n) dst[i] = f2bf(src[i]);
}

// ============ xq build + LayerNorm1 -> qn (bf16) ============
__global__ __launch_bounds__(256) void k_qn(
    const int* __restrict__ tq, const float* __restrict__ spatial,
    const float* __restrict__ temporal, const float* __restrict__ g,
    const float* __restrict__ bt, ushort_t* __restrict__ qn)
{
  int r = blockIdx.x;            // r = q*cB + b
  int b = r & 15, q = r >> 4;
  int s = q / cHW, hw = q % cHW;
  int t = tq[s * cB + b];
  int c = threadIdx.x;
  float v = temporal[t * cC + c] + spatial[hw * cC + c];
  float sum = v, sum2 = v * v;
  #pragma unroll
  for (int off = 32; off >= 1; off >>= 1) {
    sum  += __shfl_xor(sum,  off, 64);
    sum2 += __shfl_xor(sum2, off, 64);
  }
  __shared__ float rs[4], rs2[4];
  int wid = threadIdx.x >> 6;
  if ((threadIdx.x & 63) == 0) { rs[wid] = sum; rs2[wid] = sum2; }
  __syncthreads();
  float S1 = rs[0] + rs[1] + rs[2] + rs[3];
  float S2 = rs2[0] + rs2[1] + rs2[2] + rs2[3];
  float mean = S1 * (1.0f / cC);
  float var  = S2 * (1.0f / cC) - mean * mean;
  float inv  = rsqrtf(var + 1e-5f);
  qn[(size_t)r * cC + c] = f2bf((v - mean) * inv * g[c] + bt[c]);
}

// ============ LayerNorm bf16 -> bf16 ============
__global__ __launch_bounds__(256) void k_ln(
    const ushort_t* __restrict__ src, const float* __restrict__ g,
    const float* __restrict__ bt, ushort_t* __restrict__ dst)
{
  int r = blockIdx.x;
  int c = threadIdx.x;
  float v = bf2f(src[(size_t)r * cC + c]);
  float sum = v, sum2 = v * v;
  #pragma unroll
  for (int off = 32; off >= 1; off >>= 1) {
    sum  += __shfl_xor(sum,  off, 64);
    sum2 += __shfl_xor(sum2, off, 64);
  }
  __shared__ float rs[4], rs2[4];
  int wid = threadIdx.x >> 6;
  if ((threadIdx.x & 63) == 0) { rs[wid] = sum; rs2[wid] = sum2; }
  __syncthreads();
  float S1 = rs[0] + rs[1] + rs[2] + rs[3];
  float S2 = rs2[0] + rs2[1] + rs2[2] + rs2[3];
  float mean = S1 * (1.0f / cC);
  float var  = S2 * (1.0f / cC) - mean * mean;
  float inv  = rsqrtf(var + 1e-5f);
  dst[(size_t)r * cC + c] = f2bf((v - mean) * inv * g[c] + bt[c]);
}

// ============ shared GEMM helpers (M-tile 64, K=256) ============
// A tile in LDS: [64][264] ushort (row pad 8 -> 528B stride, 2-way banks = free)
__device__ __forceinline__ void stage64(
    const ushort_t* __restrict__ src, ushort_t* aT, int tid, size_t row0)
{
  #pragma unroll
  for (int s = 0; s < 8; ++s) {
    int slot = tid + s * 256;
    int row = slot >> 5, cb = slot & 31;
    *(uint4*)&aT[row * 264 + cb * 8] =
        *(const uint4*)&src[(row0 + row) * 256 + cb * 8];
  }
}

__device__ __forceinline__ void mfma_gemm256(
    const ushort_t* aT, const ushort_t* __restrict__ Ws,
    int lane, int w, f32x4 c[16])
{
  const int lane15 = lane & 15, laneq = lane >> 4;
  const ushort_t* arow = aT + (w * 16 + lane15) * 264 + laneq * 8;
  #pragma unroll
  for (int kc = 0; kc < 8; ++kc) {
    short8 a = *(const short8*)(arow + kc * 32);
    const ushort_t* wp = Ws + ((size_t)(kc * 16) * 64 + lane) * 8;
    #pragma unroll
    for (int nb = 0; nb < 16; ++nb) {
      short8 b = *(const short8*)(wp + (size_t)nb * 64 * 8);
      c[nb] = __builtin_amdgcn_mfma_f32_16x16x32_bf16(a, b, c[nb], 0, 0, 0);
    }
  }
}

// ============ Q projection: qn @ wq + bq -> Q row-major bf16 ============
__global__ __launch_bounds__(256) void k_qproj(
    const ushort_t* __restrict__ A, const ushort_t* __restrict__ Ws,
    const float* __restrict__ Bi, ushort_t* __restrict__ Out)
{
  __shared__ ushort_t aT[64 * 264];
  const int tid = threadIdx.x, lane = tid & 63, w = tid >> 6;
  const size_t row0 = (size_t)blockIdx.x * 64;
  stage64(A, aT, tid, row0);
  __syncthreads();
  f32x4 z = {0.f, 0.f, 0.f, 0.f};
  f32x4 c[16];
  #pragma unroll
  for (int nb = 0; nb < 16; ++nb) c[nb] = z;
  mfma_gemm256(aT, Ws, lane, w, c);
  const int lane15 = lane & 15, laneq = lane >> 4;
  #pragma unroll
  for (int nb = 0; nb < 16; ++nb) {
    int col = nb * 16 + lane15;
    float bias = Bi[col];
    #pragma unroll
    for (int i = 0; i < 4; ++i) {
      size_t r = row0 + w * 16 + laneq * 4 + i;
      Out[r * 256 + col] = f2bf(c[nb][i] + bias);
    }
  }
}

// ============ K/V projections (A = xkb, rows k*16+b) ============
__global__ __launch_bounds__(256) void k_kv(
    const ushort_t* __restrict__ xkb, const ushort_t* __restrict__ wks,
    const ushort_t* __restrict__ wvs, const float* __restrict__ bk,
    const float* __restrict__ bv, ushort_t* __restrict__ Kb,
    ushort_t* __restrict__ Vb)
{
  __shared__ ushort_t aT[64 * 264];
  const ushort_t* Ws = blockIdx.y ? wvs : wks;
  const float* Bi = blockIdx.y ? bv : bk;
  ushort_t* Out = blockIdx.y ? Vb : Kb;
  const int tid = threadIdx.x, lane = tid & 63, w = tid >> 6;
  const size_t row0 = (size_t)blockIdx.x * 64;
  stage64(xkb, aT, tid, row0);
  __syncthreads();
  f32x4 z = {0.f, 0.f, 0.f, 0.f};
  f32x4 c[16];
  #pragma unroll
  for (int nb = 0; nb < 16; ++nb) c[nb] = z;
  mfma_gemm256(aT, Ws, lane, w, c);
  const int lane15 = lane & 15, laneq = lane >> 4;
  #pragma unroll
  for (int nb = 0; nb < 16; ++nb) {
    int col = nb * 16 + lane15;
    float bias = Bi[col];
    #pragma unroll
    for (int i = 0; i < 4; ++i) {
      size_t r = row0 + w * 16 + laneq * 4 + i;
      Out[r * 256 + col] = f2bf(c[nb][i] + bias);
    }
  }
}

// ============ wo projection + recomputed-xq residual -> x bf16 ============
__global__ __launch_bounds__(256) void k_wo(
    const ushort_t* __restrict__ A, const ushort_t* __restrict__ Ws,
    const float* __restrict__ Bi, const int* __restrict__ tq,
    const float* __restrict__ spatial, const float* __restrict__ temporal,
    ushort_t* __restrict__ Out)
{
  __shared__ ushort_t aT[64 * 264];
  const int tid = threadIdx.x, lane = tid & 63, w = tid >> 6;
  const size_t row0 = (size_t)blockIdx.x * 64;
  stage64(A, aT, tid, row0);
  __syncthreads();
  f32x4 z = {0.f, 0.f, 0.f, 0.f};
  f32x4 c[16];
  #pragma unroll
  for (int nb = 0; nb < 16; ++nb) c[nb] = z;
  mfma_gemm256(aT, Ws, lane, w, c);
  const int lane15 = lane & 15, laneq = lane >> 4;
  int tt[4], hws[4];
  size_t rr[4];
  #pragma unroll
  for (int i = 0; i < 4; ++i) {
    size_t r = row0 + w * 16 + laneq * 4 + i;
    int b = (int)(r & 15);
    int qq = (int)(r >> 4);
    int s = qq / cHW, hw = qq % cHW;
    rr[i] = r; hws[i] = hw; tt[i] = tq[s * cB + b];
  }
  #pragma unroll
  for (int nb = 0; nb < 16; ++nb) {
    int col = nb * 16 + lane15;
    float bias = Bi[col];
    #pragma unroll
    for (int i = 0; i < 4; ++i) {
      float xq = temporal[tt[i] * cC + col] + spatial[hws[i] * cC + col];
      Out[rr[i] * 256 + col] = f2bf(c[nb][i] + bias + xq);
    }
  }
}

// ============ fused FFN: xln @ w1 -> gelu -> @ w2 + resid, in-place x ============
// LDS: aT 64x264 ushort (33792 B) + hT 4x16x136 ushort (17408 B) = 51200 B
__global__ __launch_bounds__(256) void k_ffn(
    const ushort_t* __restrict__ xln, const ushort_t* __restrict__ w1s,
    const float* __restrict__ b1, const ushort_t* __restrict__ w2s,
    const float* __restrict__ b2, ushort_t* __restrict__ xbuf)
{
  __shared__ ushort_t aT[64 * 264];
  __shared__ ushort_t hT[4][16 * 136];
  const int tid = threadIdx.x, lane = tid & 63, w = tid >> 6;
  const size_t row0 = (size_t)blockIdx.x * 64;
  stage64(xln, aT, tid, row0);
  __syncthreads();
  const int lane15 = lane & 15, laneq = lane >> 4;
  f32x4 z = {0.f, 0.f, 0.f, 0.f};
  f32x4 c2[16];
  #pragma unroll
  for (int nb = 0; nb < 16; ++nb) c2[nb] = z;
  const ushort_t* arow = aT + (w * 16 + lane15) * 264 + laneq * 8;
  ushort_t* hrow = hT[w];

  for (int hc = 0; hc < 8; ++hc) {
    // ---- FFN1: c1(16x128) = A(16x256) @ w1[:, hc*128 : hc*128+128]
    f32x4 c1[8];
    #pragma unroll
    for (int nb = 0; nb < 8; ++nb) c1[nb] = z;
    #pragma unroll
    for (int kc = 0; kc < 8; ++kc) {
      short8 a = *(const short8*)(arow + kc * 32);
      const ushort_t* wp = w1s + ((size_t)(kc * 64 + hc * 8) * 64 + lane) * 8;
      #pragma unroll
      for (int nb = 0; nb < 8; ++nb) {
        short8 b = *(const short8*)(wp + (size_t)nb * 64 * 8);
        c1[nb] = __builtin_amdgcn_mfma_f32_16x16x32_bf16(a, b, c1[nb], 0, 0, 0);
      }
    }
    // ---- GELU (tanh approx) + write per-wave h tile [m][136]
    #pragma unroll
    for (int nb = 0; nb < 8; ++nb) {
      float bias = b1[hc * 128 + nb * 16 + lane15];
      #pragma unroll
      for (int i = 0; i < 4; ++i) {
        float xx = c1[nb][i] + bias;
        float u = 0.7978845608028654f * (xx + 0.044715f * xx * xx * xx);
        u = fminf(fmaxf(u, -15.f), 15.f);
        float e = __expf(2.f * u);
        float t = (e - 1.f) / (e + 1.f);
        hrow[(laneq * 4 + i) * 136 + nb * 16 + lane15] = f2bf(0.5f * xx * (1.f + t));
      }
    }
    // ---- FFN2 accumulate: c2 += h(16x128) @ w2[hc*128 : , :]
    #pragma unroll
    for (int kc2 = 0; kc2 < 4; ++kc2) {
      short8 a2 = *(const short8*)(hrow + lane15 * 136 + kc2 * 32 + laneq * 8);
      const ushort_t* wp = w2s + ((size_t)((hc * 4 + kc2) * 16) * 64 + lane) * 8;
      #pragma unroll
      for (int nb = 0; nb < 16; ++nb) {
        short8 b = *(const short8*)(wp + (size_t)nb * 64 * 8);
        c2[nb] = __builtin_amdgcn_mfma_f32_16x16x32_bf16(a2, b, c2[nb], 0, 0, 0);
      }
    }
  }
  // ---- epilogue: + b2 + residual x, write in-place
  #pragma unroll
  for (int nb = 0; nb < 16; ++nb) {
    int col = nb * 16 + lane15;
    float bias = b2[col];
    #pragma unroll
    for (int i = 0; i < 4; ++i) {
      size_t idx = (row0 + w * 16 + laneq * 4 + i) * 256 + col;
      float val = c2[nb][i] + bias + bf2f(xbuf[idx]);
      xbuf[idx] = f2bf(val);
    }
  }
}

// ============ attention: per (b,h), 32 q-rows per block ============
__global__ __launch_bounds__(256) void k_attn(
    const ushort_t* __restrict__ Qb, const ushort_t* __restrict__ Kb,
    const ushort_t* __restrict__ Vb, const int* __restrict__ tq,
    const int* __restrict__ tk, const int* __restrict__ pad_q,
    const int* __restrict__ pad_k, ushort_t* __restrict__ aout)
{
  __shared__ ushort_t KtL[64 * 130];  // [d][k] bf16
  __shared__ float Vl[128 * 64];      // [k][d] fp32
  __shared__ int   tkL[128];
  __shared__ float qrL[4][128];
  __shared__ float pL[4][256];

  const int h = blockIdx.y, b = blockIdx.z;
  const int tid = threadIdx.x;
  const int lane = tid & 63, w = tid >> 6;
  for (int i = tid; i < cLK * cDH; i += 256) {
    int k = i >> 6, d = i & 63;
    size_t src = (size_t)(k * cB + b) * 256 + h * 64 + d;
    KtL[d * 130 + k] = Kb[src];
    Vl[k * 64 + d] = bf2f(Vb[src]);
  }
  if (tid < 128) tkL[tid] = tk[tid * cB + b];
  __syncthreads();
  const int pk = pad_k[b];
  const int pq = pad_q[b] * cHW;

  for (int pr = 0; pr < 4; ++pr) {
    int q0 = blockIdx.x * 32 + w * 8 + pr * 2;
    if (q0 >= cLQ) continue;                  // wave-uniform
    int q1 = q0 + 1;
    bool has1 = (q1 < cLQ);
    int q1c = has1 ? q1 : q0;
    qrL[w][lane]      = bf2f(Qb[(size_t)(q0 * cB + b) * 256 + h * 64 + lane]);
    qrL[w][64 + lane] = bf2f(Qb[(size_t)(q1c * cB + b) * 256 + h * 64 + lane]);
    float s00 = 0.f, s01 = 0.f, s10 = 0.f, s11 = 0.f;
    #pragma unroll 8
    for (int d = 0; d < 64; ++d) {
      float k0 = bf2f(KtL[d * 130 + lane]);
      float k1 = bf2f(KtL[d * 130 + 64 + lane]);
      float q0v = qrL[w][d];
      float q1v = qrL[w][64 + d];
      s00 = fmaf(q0v, k0, s00); s01 = fmaf(q0v, k1, s01);
      s10 = fmaf(q1v, k0, s10); s11 = fmaf(q1v, k1, s11);
    }
    int t0 = tq[(q0 / cHW) * cB + b];
    int t1 = tq[(q1c / cHW) * cB + b];
    bool qa0 = (q0 < pq), qa1 = (q1c < pq);
    int tk0 = tkL[lane], tk1 = tkL[64 + lane];
    bool k0ok = (lane < pk), k1ok = (64 + lane < pk);
    s00 = (qa0 && tk0 <= t0 && k0ok) ? s00 * 0.125f : -1e9f;
    s01 = (qa0 && tk1 <= t0 && k1ok) ? s01 * 0.125f : -1e9f;
    s10 = (qa1 && tk0 <= t1 && k0ok) ? s10 * 0.125f : -1e9f;
    s11 = (qa1 && tk1 <= t1 && k1ok) ? s11 * 0.125f : -1e9f;
    float m0 = fmaxf(s00, s01), m1 = fmaxf(s10, s11);
    #pragma unroll
    for (int off = 32; off >= 1; off >>= 1) {
      m0 = fmaxf(m0, __shfl_xor(m0, off, 64));
      m1 = fmaxf(m1, __shfl_xor(m1, off, 64));
    }
    float p00 = __expf(s00 - m0), p01 = __expf(s01 - m0);
    float p10 = __expf(s10 - m1), p11 = __expf(s11 - m1);
    float l0 = p00 + p01, l1 = p10 + p11;
    #pragma unroll
    for (int off = 32; off >= 1; off >>= 1) {
      l0 += __shfl_xor(l0, off, 64);
      l1 += __shfl_xor(l1, off, 64);
    }
    float i0 = 1.0f / l0, i1 = 1.0f / l1;
    pL[w][lane]       = p00 * i0;
    pL[w][64 + lane]  = p01 * i0;
    pL[w][128 + lane] = p10 * i1;
    pL[w][192 + lane] = p11 * i1;
    float o0 = 0.f, o1 = 0.f;
    #pragma unroll 8
    for (int k = 0; k < 128; ++k) {
      float vv = Vl[k * 64 + lane];
      o0 = fmaf(pL[w][k], vv, o0);
      o1 = fmaf(pL[w][128 + k], vv, o1);
    }
    aout[((size_t)q0 * cB + b) * cC + h * cDH + lane] = f2bf(o0);
    if (has1) aout[((size_t)q1 * cB + b) * cC + h * cDH + lane] = f2bf(o1);
  }
}

// ============ table/hand heads + upsample scatter ============
__global__ __launch_bounds__(256) void k_th(
    const ushort_t* __restrict__ x2, const float* __restrict__ tw,
    const float* __restrict__ tb, const float* __restrict__ hwgt,
    const float* __restrict__ hb, float* __restrict__ out)
{
  int x = blockIdx.x;                 // s*584 + hw*2 + half
  int s = x / 584;
  int rem = x % 584;
  int hw = rem >> 1, half = rem & 1;
  int j = threadIdx.x & 31, rr = threadIdx.x >> 5;
  int b = half * 8 + rr;
  const float* W;
  const float* Bi;
  if (hw < 256) { W = tw; Bi = tb; } else { W = hwgt; Bi = hb; }
  const ushort_t* row = x2 + ((size_t)(s * cHW + hw) * cB + b) * cC;
  float acc = Bi[j];
  for (int c = 0; c < cC; c += 4) {
    uint2 hv = *(const uint2*)(row + c);
    acc = fmaf(bf2f((ushort_t)(hv.x & 0xffff)), W[(c + 0) * 32 + j], acc);
    acc = fmaf(bf2f((ushort_t)(hv.x >> 16)),   W[(c + 1) * 32 + j], acc);
    acc = fmaf(bf2f((ushort_t)(hv.y & 0xffff)), W[(c + 2) * 32 + j], acc);
    acc = fmaf(bf2f((ushort_t)(hv.y >> 16)),   W[(c + 3) * 32 + j], acc);
  }
  int uh = j >> 3, uw = (j >> 1) & 3, uc = j & 1;
  size_t idx;
  if (hw < 256) {
    int th = hw >> 4, twi = hw & 15;
    idx = TX_OFF + ((((size_t)(s * cB + b)) * 2 + uc) * 64 + (th * 4 + uh)) * 64 + (twi * 4 + uw);
  } else {
    int h2 = hw - 256;
    int hh = h2 / 6, ww = h2 % 6;
    idx = HX_OFF + ((((size_t)(s * cB + b)) * 2 + uc) * 24 + (hh * 4 + uh)) * 24 + (ww * 4 + uw);
  }
  out[idx] = acc;
}

// ============ gx heads: mode / shape / color ============
__global__ __launch_bounds__(128) void k_gx(
    const ushort_t* __restrict__ x2,
    const float* __restrict__ mw, const float* __restrict__ mbi,
    const float* __restrict__ sw, const float* __restrict__ sbi,
    const float* __restrict__ cw, const float* __restrict__ cbi,
    float* __restrict__ out)
{
  int sb = blockIdx.x;              // s*16 + b
  int s = sb >> 4, b = sb & 15;
  __shared__ float rowL[256];
  const ushort_t* row = x2 + ((size_t)(s * cHW + 292) * cB + b) * cC;
  for (int i = threadIdx.x; i < 256; i += 128) rowL[i] = bf2f(row[i]);
  __syncthreads();
  int j = threadIdx.x;
  if (j < 100) {
    const float* W;
    const float* Bi;
    int jj, M;
    size_t off;
    if (j < 20)      { W = mw; Bi = mbi; jj = j;      M = 20; off = 0;     }
    else if (j < 84) { W = sw; Bi = sbi; jj = j - 20; M = 64; off = 5120;  }
    else             { W = cw; Bi = cbi; jj = j - 84; M = 16; off = 21504; }
    float acc = Bi[jj];
    for (int c = 0; c < 256; ++c) acc = fmaf(rowL[c], W[c * M + jj], acc);
    out[off + (size_t)sb * M + jj] = acc;
  }
}

extern "C" void kernel_launch(void* const* d_in, const int* in_sizes, int n_in,
                              void* d_out, int out_size, void* d_ws, size_t ws_size,
                              hipStream_t stream)
{
  const int*   tq       = (const int*)d_in[0];
  const int*   pad_q    = (const int*)d_in[1];
  const float* xk       = (const float*)d_in[2];
  const int*   tk       = (const int*)d_in[3];
  const int*   pad_k    = (const int*)d_in[4];
  const float* spatial  = (const float*)d_in[8];
  const float* temporal = (const float*)d_in[9];
  const float* ln1_g    = (const float*)d_in[10];
  const float* ln1_b    = (const float*)d_in[11];
  const float* wq       = (const float*)d_in[12];
  const float* bq       = (const float*)d_in[13];
  const float* wk       = (const float*)d_in[14];
  const float* bk       = (const float*)d_in[15];
  const float* wv       = (const float*)d_in[16];
  const float* bv       = (const float*)d_in[17];
  const float* wo       = (const float*)d_in[18];
  const float* bo       = (const float*)d_in[19];
  const float* ln2_g    = (const float*)d_in[20];
  const float* ln2_b    = (const float*)d_in[21];
  const float* w1       = (const float*)d_in[22];
  const float* b1       = (const float*)d_in[23];
  const float* w2       = (const float*)d_in[24];
  const float* b2       = (const float*)d_in[25];
  const float* table_w  = (const float*)d_in[26];
  const float* table_b  = (const float*)d_in[27];
  const float* hand_w   = (const float*)d_in[28];
  const float* hand_b   = (const float*)d_in[29];
  const float* mode_w   = (const float*)d_in[30];
  const float* mode_b   = (const float*)d_in[31];
  const float* shape_w  = (const float*)d_in[32];
  const float* shape_b  = (const float*)d_in[33];
  const float* color_w  = (const float*)d_in[34];
  const float* color_b  = (const float*)d_in[35];
  float* out = (float*)d_out;

  // Workspace layout (~82 MB)
  char* ws = (char*)d_ws;
  const size_t NB2 = (size_t)cN * cC * sizeof(ushort_t);       // 38,404,096
  ushort_t* buf1 = (ushort_t*)ws;                              // qn -> a -> xln
  ushort_t* buf2 = (ushort_t*)(ws + NB2);                      // Q -> x -> x2 (in-place)
  char* p = ws + 2 * NB2;
  ushort_t* Kb  = (ushort_t*)p;  p += (size_t)cLK * cB * 256 * 2;   // 1 MB
  ushort_t* Vb  = (ushort_t*)p;  p += (size_t)cLK * cB * 256 * 2;   // 1 MB
  ushort_t* xkb = (ushort_t*)p;  p += (size_t)cLK * cB * 256 * 2;   // 1 MB
  ushort_t* wqs = (ushort_t*)p;  p += 256 * 256 * 2;
  ushort_t* wks = (ushort_t*)p;  p += 256 * 256 * 2;
  ushort_t* wvs = (ushort_t*)p;  p += 256 * 256 * 2;
  ushort_t* wos = (ushort_t*)p;  p += 256 * 256 * 2;
  ushort_t* w1s = (ushort_t*)p;  p += 256 * 1024 * 2;
  ushort_t* w2s = (ushort_t*)p;  p += 1024 * 256 * 2;

  // weight prep
  k_cvt<<<(cLK * cB * 256 + 255) / 256, 256, 0, stream>>>(xk, xkb, cLK * cB * 256);
  k_swz<<<32, 256, 0, stream>>>(wq, wqs, 256);
  k_swz<<<32, 256, 0, stream>>>(wk, wks, 256);
  k_swz<<<32, 256, 0, stream>>>(wv, wvs, 256);
  k_swz<<<32, 256, 0, stream>>>(wo, wos, 256);
  k_swz<<<128, 256, 0, stream>>>(w1, w1s, 1024);
  k_swz<<<128, 256, 0, stream>>>(w2, w2s, 256);

  // pipeline
  k_qn<<<cN, 256, 0, stream>>>(tq, spatial, temporal, ln1_g, ln1_b, buf1);
  k_kv<<<dim3(32, 2), 256, 0, stream>>>(xkb, wks, wvs, bk, bv, Kb, Vb);
  k_qproj<<<cN / 64, 256, 0, stream>>>(buf1, wqs, bq, buf2);
  k_attn<<<dim3((cLQ + 31) / 32, cH, cB), 256, 0, stream>>>(buf2, Kb, Vb, tq, tk,
                                                            pad_q, pad_k, buf1);
  k_wo<<<cN / 64, 256, 0, stream>>>(buf1, wos, bo, tq, spatial, temporal, buf2);
  k_ln<<<cN, 256, 0, stream>>>(buf2, ln2_g, ln2_b, buf1);
  k_ffn<<<cN / 64, 256, 0, stream>>>(buf1, w1s, b1, w2s, b2, buf2);
  k_th<<<cS * 292 * 2, 256, 0, stream>>>(buf2, table_w, table_b, hand_w, hand_b, out);
  k_gx<<<cS * cB, 128, 0, stream>>>(buf2, mode_w, mode_b, shape_w, shape_b,
                                    color_w, color_b, out);
}

// Round 4
// 1022.600 us; speedup vs baseline: 2.6540x; 1.5082x over previous
//
#include <hip/hip_runtime.h>
#include <hip/hip_bf16.h>

namespace {
constexpr int cS = 16, cB = 16, cC = 256, cH = 4, cDH = 64, cHW = 293;
constexpr int cLQ = cS * cHW;      // 4688
constexpr int cLK = 128;
constexpr int cN  = cLQ * cB;      // 75008
constexpr size_t TX_OFF = 25600;         // 5120 + 16384 + 4096
constexpr size_t HX_OFF = 2122752;       // TX_OFF + 16*16*2*64*64
}

typedef unsigned short ushort_t;
typedef unsigned int uint_t;
typedef __attribute__((ext_vector_type(8))) short short8;    // 8 bf16 (4 VGPRs)
typedef __attribute__((ext_vector_type(4))) float f32x4;     // MFMA C/D frag

__device__ __forceinline__ float bf2f(ushort_t u) {
  return __uint_as_float(((uint_t)u) << 16);
}
__device__ __forceinline__ ushort_t f2bf(float f) {
  __hip_bfloat16 h = __float2bfloat16(f);
  return *(ushort_t*)&h;
}

// SWZ frag-linear activation layout for a [rows][256] matrix:
// element (r, c) lives at ((r>>4)*8 + (c>>5))*512 + ((c>>3)&3)*128 + (r&15)*8 + (c&7)
// so a wave's A-frag (m15=lane&15, k=(lane>>4)*8+j) for (row-tile rt, k-chunk kc)
// is a contiguous 1KB block at ((rt*8+kc)*64 + lane)*8.
__device__ __forceinline__ size_t swz(int r, int c) {
  return (((size_t)(r >> 4) * 8 + (c >> 5)) * 64 + ((c >> 3) & 3) * 16 + (r & 15)) * 8 + (c & 7);
}

// ============ weight swizzle: W[K][N] fp32 -> B-frag order bf16 ============
// slot (kc, nb): lane holds 8 elems W[kc*32 + (lane>>4)*8 + j][nb*16 + (lane&15)]
__global__ __launch_bounds__(256) void k_swz(
    const float* __restrict__ W, ushort_t* __restrict__ Ws, int N)
{
  int slot = blockIdx.x * 256 + threadIdx.x;
  int lane = slot & 63;
  int fr   = slot >> 6;            // kc*(N/16) + nb
  int NB   = N >> 4;
  int nb   = fr % NB, kc = fr / NB;
  int n    = nb * 16 + (lane & 15);
  int k0   = kc * 32 + (lane >> 4) * 8;
  ushort_t tmp[8];
  #pragma unroll
  for (int i = 0; i < 8; ++i) tmp[i] = f2bf(W[(size_t)(k0 + i) * N + n]);
  *(uint4*)&Ws[(size_t)slot * 8] = *(uint4*)tmp;
}

// ============ xk fp32 row-major -> SWZ bf16 ============
__global__ __launch_bounds__(256) void k_cvt_swz(
    const float* __restrict__ src, ushort_t* __restrict__ dst)
{
  int i4 = blockIdx.x * 256 + threadIdx.x;      // one thread per 4 elems
  int r = i4 >> 6;
  int c0 = (i4 & 63) * 4;
  float4 v = *(const float4*)(src + (size_t)r * 256 + c0);
  ushort_t o[4] = {f2bf(v.x), f2bf(v.y), f2bf(v.z), f2bf(v.w)};
  *(uint2*)&dst[swz(r, c0)] = *(uint2*)o;
}

// ============ xq build + LayerNorm1 -> qn (SWZ bf16), wave per row ============
__global__ __launch_bounds__(256) void k_qn(
    const int* __restrict__ tq, const float* __restrict__ spatial,
    const float* __restrict__ temporal, const float* __restrict__ g,
    const float* __restrict__ bt, ushort_t* __restrict__ qn)
{
  int w = threadIdx.x >> 6, lane = threadIdx.x & 63;
  int r = blockIdx.x * 4 + w;          // r = q*16 + b
  int b = r & 15, q = r >> 4;
  int s = q / cHW, hw = q % cHW;
  int t = tq[s * cB + b];
  int c0 = lane * 4;
  float4 tv = *(const float4*)(temporal + (size_t)t * cC + c0);
  float4 sv = *(const float4*)(spatial + (size_t)hw * cC + c0);
  float v0 = tv.x + sv.x, v1 = tv.y + sv.y, v2 = tv.z + sv.z, v3 = tv.w + sv.w;
  float sum = v0 + v1 + v2 + v3;
  float sum2 = v0 * v0 + v1 * v1 + v2 * v2 + v3 * v3;
  #pragma unroll
  for (int off = 32; off >= 1; off >>= 1) {
    sum  += __shfl_xor(sum,  off, 64);
    sum2 += __shfl_xor(sum2, off, 64);
  }
  float mean = sum * (1.0f / cC);
  float var  = sum2 * (1.0f / cC) - mean * mean;
  float inv  = rsqrtf(var + 1e-5f);
  float4 g4 = *(const float4*)(g + c0);
  float4 b4 = *(const float4*)(bt + c0);
  ushort_t o[4] = {f2bf((v0 - mean) * inv * g4.x + b4.x),
                   f2bf((v1 - mean) * inv * g4.y + b4.y),
                   f2bf((v2 - mean) * inv * g4.z + b4.z),
                   f2bf((v3 - mean) * inv * g4.w + b4.w)};
  *(uint2*)&qn[swz(r, c0)] = *(uint2*)o;
}

// ============ LayerNorm: x (row-major bf16) -> xln (SWZ bf16), wave per row ============
__global__ __launch_bounds__(256) void k_ln(
    const ushort_t* __restrict__ src, const float* __restrict__ g,
    const float* __restrict__ bt, ushort_t* __restrict__ dst)
{
  int w = threadIdx.x >> 6, lane = threadIdx.x & 63;
  int r = blockIdx.x * 4 + w;
  int c0 = lane * 4;
  uint2 hv = *(const uint2*)(src + (size_t)r * cC + c0);
  float v0 = bf2f((ushort_t)(hv.x & 0xffff)), v1 = bf2f((ushort_t)(hv.x >> 16));
  float v2 = bf2f((ushort_t)(hv.y & 0xffff)), v3 = bf2f((ushort_t)(hv.y >> 16));
  float sum = v0 + v1 + v2 + v3;
  float sum2 = v0 * v0 + v1 * v1 + v2 * v2 + v3 * v3;
  #pragma unroll
  for (int off = 32; off >= 1; off >>= 1) {
    sum  += __shfl_xor(sum,  off, 64);
    sum2 += __shfl_xor(sum2, off, 64);
  }
  float mean = sum * (1.0f / cC);
  float var  = sum2 * (1.0f / cC) - mean * mean;
  float inv  = rsqrtf(var + 1e-5f);
  float4 g4 = *(const float4*)(g + c0);
  float4 b4 = *(const float4*)(bt + c0);
  ushort_t o[4] = {f2bf((v0 - mean) * inv * g4.x + b4.x),
                   f2bf((v1 - mean) * inv * g4.y + b4.y),
                   f2bf((v2 - mean) * inv * g4.z + b4.z),
                   f2bf((v3 - mean) * inv * g4.w + b4.w)};
  *(uint2*)&dst[swz(r, c0)] = *(uint2*)o;
}

// ============ core GEMM: 64 rows x 256 cols, K=256, no LDS, N-split waves ============
__device__ __forceinline__ void gemm_k256(
    const ushort_t* __restrict__ A, const ushort_t* __restrict__ Ws,
    int rt0, int slot0, int NB, int lane, f32x4 c[4][4])
{
  #pragma unroll 2
  for (int kc = 0; kc < 8; ++kc) {
    short8 a[4];
    #pragma unroll
    for (int mf = 0; mf < 4; ++mf)
      a[mf] = *(const short8*)(A + (((size_t)(rt0 + mf) * 8 + kc) * 64 + lane) * 8);
    #pragma unroll
    for (int nb = 0; nb < 4; ++nb) {
      short8 b = *(const short8*)(Ws + (((size_t)kc * NB + slot0 + nb) * 64 + lane) * 8);
      #pragma unroll
      for (int mf = 0; mf < 4; ++mf)
        c[mf][nb] = __builtin_amdgcn_mfma_f32_16x16x32_bf16(a[mf], b, c[mf][nb], 0, 0, 0);
    }
  }
}

// ============ Q projection: qn_swz @ wq + bq -> Q row-major bf16 ============
__global__ __launch_bounds__(256) void k_qproj(
    const ushort_t* __restrict__ A, const ushort_t* __restrict__ Ws,
    const float* __restrict__ Bi, ushort_t* __restrict__ Out)
{
  const int lane = threadIdx.x & 63, w = threadIdx.x >> 6;
  const int rt0 = blockIdx.x * 4, row0 = blockIdx.x * 64;
  f32x4 z = {0.f, 0.f, 0.f, 0.f};
  f32x4 c[4][4];
  #pragma unroll
  for (int mf = 0; mf < 4; ++mf)
    #pragma unroll
    for (int nb = 0; nb < 4; ++nb) c[mf][nb] = z;
  gemm_k256(A, Ws, rt0, w * 4, 16, lane, c);
  const int lane15 = lane & 15, kq = lane >> 4;
  #pragma unroll
  for (int nb = 0; nb < 4; ++nb) {
    int col = w * 64 + nb * 16 + lane15;
    float bias = Bi[col];
    #pragma unroll
    for (int mf = 0; mf < 4; ++mf)
      #pragma unroll
      for (int i = 0; i < 4; ++i) {
        int row = row0 + mf * 16 + kq * 4 + i;
        Out[(size_t)row * 256 + col] = f2bf(c[mf][nb][i] + bias);
      }
  }
}

// ============ K/V projections ============
__global__ __launch_bounds__(256) void k_kv(
    const ushort_t* __restrict__ xkb, const ushort_t* __restrict__ wks,
    const ushort_t* __restrict__ wvs, const float* __restrict__ bk,
    const float* __restrict__ bv, ushort_t* __restrict__ Kb,
    ushort_t* __restrict__ Vb)
{
  const ushort_t* Ws = blockIdx.y ? wvs : wks;
  const float* Bi = blockIdx.y ? bv : bk;
  ushort_t* Out = blockIdx.y ? Vb : Kb;
  const int lane = threadIdx.x & 63, w = threadIdx.x >> 6;
  const int rt0 = blockIdx.x * 4, row0 = blockIdx.x * 64;
  f32x4 z = {0.f, 0.f, 0.f, 0.f};
  f32x4 c[4][4];
  #pragma unroll
  for (int mf = 0; mf < 4; ++mf)
    #pragma unroll
    for (int nb = 0; nb < 4; ++nb) c[mf][nb] = z;
  gemm_k256(xkb, Ws, rt0, w * 4, 16, lane, c);
  const int lane15 = lane & 15, kq = lane >> 4;
  #pragma unroll
  for (int nb = 0; nb < 4; ++nb) {
    int col = w * 64 + nb * 16 + lane15;
    float bias = Bi[col];
    #pragma unroll
    for (int mf = 0; mf < 4; ++mf)
      #pragma unroll
      for (int i = 0; i < 4; ++i) {
        int row = row0 + mf * 16 + kq * 4 + i;
        Out[(size_t)row * 256 + col] = f2bf(c[mf][nb][i] + bias);
      }
  }
}

// ============ wo projection + recomputed-xq residual -> x row-major bf16 ============
__global__ __launch_bounds__(256) void k_wo(
    const ushort_t* __restrict__ A, const ushort_t* __restrict__ Ws,
    const float* __restrict__ Bi, const int* __restrict__ tq,
    const float* __restrict__ spatial, const float* __restrict__ temporal,
    ushort_t* __restrict__ Out)
{
  const int lane = threadIdx.x & 63, w = threadIdx.x >> 6;
  const int rt0 = blockIdx.x * 4, row0 = blockIdx.x * 64;
  f32x4 z = {0.f, 0.f, 0.f, 0.f};
  f32x4 c[4][4];
  #pragma unroll
  for (int mf = 0; mf < 4; ++mf)
    #pragma unroll
    for (int nb = 0; nb < 4; ++nb) c[mf][nb] = z;
  gemm_k256(A, Ws, rt0, w * 4, 16, lane, c);
  const int lane15 = lane & 15, kq = lane >> 4;
  // rows handled by this lane: row = row0 + mf*16 + kq*4 + i ; b = kq*4+i ; q = rt0+mf
  int tt[4][4], hws[4];
  #pragma unroll
  for (int mf = 0; mf < 4; ++mf) {
    int q = rt0 + mf;
    int s = q / cHW;
    hws[mf] = q % cHW;
    #pragma unroll
    for (int i = 0; i < 4; ++i) tt[mf][i] = tq[s * cB + kq * 4 + i];
  }
  #pragma unroll
  for (int nb = 0; nb < 4; ++nb) {
    int col = w * 64 + nb * 16 + lane15;
    float bias = Bi[col];
    #pragma unroll
    for (int mf = 0; mf < 4; ++mf) {
      float sp = spatial[(size_t)hws[mf] * cC + col];
      #pragma unroll
      for (int i = 0; i < 4; ++i) {
        int row = row0 + mf * 16 + kq * 4 + i;
        float xq = temporal[(size_t)tt[mf][i] * cC + col] + sp;
        Out[(size_t)row * 256 + col] = f2bf(c[mf][nb][i] + bias + xq);
      }
    }
  }
}

// ============ fused FFN: xln_swz @ w1 -> gelu -> @ w2 + resid(x) -> x2 (in-place) ====
// Block: 64 rows, 4 waves. Wave w owns output cols [w*64, w*64+64).
// hc loop: 4 chunks of 256 h-cols; h chunk lives in 32KB LDS frag buffer.
__global__ __launch_bounds__(256) void k_ffn(
    const ushort_t* __restrict__ xln, const ushort_t* __restrict__ w1s,
    const float* __restrict__ b1, const ushort_t* __restrict__ w2s,
    const float* __restrict__ b2, ushort_t* __restrict__ xbuf)
{
  __shared__ ushort_t hL[8 * 4 * 64 * 8];    // [kc2][mf][lane][8] = 32 KB
  const int lane = threadIdx.x & 63, w = threadIdx.x >> 6;
  const int lane15 = lane & 15, kq = lane >> 4;
  const int rt0 = blockIdx.x * 4, row0 = blockIdx.x * 64;
  f32x4 z = {0.f, 0.f, 0.f, 0.f};
  f32x4 c2[4][4];
  #pragma unroll
  for (int mf = 0; mf < 4; ++mf)
    #pragma unroll
    for (int nb = 0; nb < 4; ++nb) c2[mf][nb] = z;

  for (int hc = 0; hc < 4; ++hc) {
    // ---- FFN1: c1[4][4] = A(64x256) @ w1[:, hc*256 + w*64 ..+64)
    f32x4 c1[4][4];
    #pragma unroll
    for (int mf = 0; mf < 4; ++mf)
      #pragma unroll
      for (int nb = 0; nb < 4; ++nb) c1[mf][nb] = z;
    gemm_k256(xln, w1s, rt0, hc * 16 + w * 4, 64, lane, c1);
    __syncthreads();   // prior iteration's hL reads complete
    // ---- GELU + scatter into hL frag layout
    #pragma unroll
    for (int nb = 0; nb < 4; ++nb) {
      float bias = b1[hc * 256 + w * 64 + nb * 16 + lane15];
      int k2l = w * 64 + nb * 16 + lane15;
      int kc2l = k2l >> 5, kq2 = (k2l >> 3) & 3, j2 = k2l & 7;
      #pragma unroll
      for (int mf = 0; mf < 4; ++mf)
        #pragma unroll
        for (int i = 0; i < 4; ++i) {
          float xx = c1[mf][nb][i] + bias;
          float u = 0.7978845608028654f * (xx + 0.044715f * xx * xx * xx);
          u = fminf(fmaxf(u, -15.f), 15.f);
          float e = __expf(2.f * u);
          float t = (e - 1.f) / (e + 1.f);
          hL[(((kc2l * 4 + mf) * 64) + kq2 * 16 + kq * 4 + i) * 8 + j2] =
              f2bf(0.5f * xx * (1.f + t));
        }
    }
    __syncthreads();
    // ---- FFN2 accumulate: c2 += h(64x256) @ w2[hc*256.., w*64..+64)
    #pragma unroll 2
    for (int kc2 = 0; kc2 < 8; ++kc2) {
      short8 a2[4];
      #pragma unroll
      for (int mf = 0; mf < 4; ++mf)
        a2[mf] = *(const short8*)&hL[((kc2 * 4 + mf) * 64 + lane) * 8];
      #pragma unroll
      for (int nb = 0; nb < 4; ++nb) {
        short8 b = *(const short8*)(w2s +
            (((size_t)(hc * 8 + kc2) * 16 + w * 4 + nb) * 64 + lane) * 8);
        #pragma unroll
        for (int mf = 0; mf < 4; ++mf)
          c2[mf][nb] = __builtin_amdgcn_mfma_f32_16x16x32_bf16(a2[mf], b, c2[mf][nb], 0, 0, 0);
      }
    }
  }
  // ---- epilogue: + b2 + residual x (row-major), write x2 in-place
  #pragma unroll
  for (int nb = 0; nb < 4; ++nb) {
    int col = w * 64 + nb * 16 + lane15;
    float bias = b2[col];
    #pragma unroll
    for (int mf = 0; mf < 4; ++mf)
      #pragma unroll
      for (int i = 0; i < 4; ++i) {
        size_t idx = (size_t)(row0 + mf * 16 + kq * 4 + i) * 256 + col;
        float val = c2[mf][nb][i] + bias + bf2f(xbuf[idx]);
        xbuf[idx] = f2bf(val);
      }
  }
}

// ============ attention: per (b,h), 32 q-rows per block; out a in SWZ ============
__global__ __launch_bounds__(256) void k_attn(
    const ushort_t* __restrict__ Qb, const ushort_t* __restrict__ Kb,
    const ushort_t* __restrict__ Vb, const int* __restrict__ tq,
    const int* __restrict__ tk, const int* __restrict__ pad_q,
    const int* __restrict__ pad_k, ushort_t* __restrict__ aout)
{
  __shared__ ushort_t KtL[64 * 130];  // [d][k] bf16
  __shared__ float Vl[128 * 64];      // [k][d] fp32
  __shared__ int   tkL[128];
  __shared__ float qrL[4][128];
  __shared__ float pL[4][256];

  const int h = blockIdx.y, b = blockIdx.z;
  const int tid = threadIdx.x;
  const int lane = tid & 63, w = tid >> 6;
  for (int i = tid; i < cLK * cDH; i += 256) {
    int k = i >> 6, d = i & 63;
    size_t src = (size_t)(k * cB + b) * 256 + h * 64 + d;
    KtL[d * 130 + k] = Kb[src];
    Vl[k * 64 + d] = bf2f(Vb[src]);
  }
  if (tid < 128) tkL[tid] = tk[tid * cB + b];
  __syncthreads();
  const int pk = pad_k[b];
  const int pq = pad_q[b] * cHW;
  // SWZ store pieces for col c = h*64 + lane:
  const int kcS = h * 2 + (lane >> 5);
  const int kqS = (lane >> 3) & 3;
  const int jS = lane & 7;

  for (int pr = 0; pr < 4; ++pr) {
    int q0 = blockIdx.x * 32 + w * 8 + pr * 2;
    if (q0 >= cLQ) continue;                  // wave-uniform
    int q1 = q0 + 1;
    bool has1 = (q1 < cLQ);
    int q1c = has1 ? q1 : q0;
    qrL[w][lane]      = bf2f(Qb[(size_t)(q0 * cB + b) * 256 + h * 64 + lane]);
    qrL[w][64 + lane] = bf2f(Qb[(size_t)(q1c * cB + b) * 256 + h * 64 + lane]);
    float s00 = 0.f, s01 = 0.f, s10 = 0.f, s11 = 0.f;
    #pragma unroll 8
    for (int d = 0; d < 64; ++d) {
      float k0 = bf2f(KtL[d * 130 + lane]);
      float k1 = bf2f(KtL[d * 130 + 64 + lane]);
      float q0v = qrL[w][d];
      float q1v = qrL[w][64 + d];
      s00 = fmaf(q0v, k0, s00); s01 = fmaf(q0v, k1, s01);
      s10 = fmaf(q1v, k0, s10); s11 = fmaf(q1v, k1, s11);
    }
    int t0 = tq[(q0 / cHW) * cB + b];
    int t1 = tq[(q1c / cHW) * cB + b];
    bool qa0 = (q0 < pq), qa1 = (q1c < pq);
    int tk0 = tkL[lane], tk1 = tkL[64 + lane];
    bool k0ok = (lane < pk), k1ok = (64 + lane < pk);
    s00 = (qa0 && tk0 <= t0 && k0ok) ? s00 * 0.125f : -1e9f;
    s01 = (qa0 && tk1 <= t0 && k1ok) ? s01 * 0.125f : -1e9f;
    s10 = (qa1 && tk0 <= t1 && k0ok) ? s10 * 0.125f : -1e9f;
    s11 = (qa1 && tk1 <= t1 && k1ok) ? s11 * 0.125f : -1e9f;
    float m0 = fmaxf(s00, s01), m1 = fmaxf(s10, s11);
    #pragma unroll
    for (int off = 32; off >= 1; off >>= 1) {
      m0 = fmaxf(m0, __shfl_xor(m0, off, 64));
      m1 = fmaxf(m1, __shfl_xor(m1, off, 64));
    }
    float p00 = __expf(s00 - m0), p01 = __expf(s01 - m0);
    float p10 = __expf(s10 - m1), p11 = __expf(s11 - m1);
    float l0 = p00 + p01, l1 = p10 + p11;
    #pragma unroll
    for (int off = 32; off >= 1; off >>= 1) {
      l0 += __shfl_xor(l0, off, 64);
      l1 += __shfl_xor(l1, off, 64);
    }
    float i0 = 1.0f / l0, i1 = 1.0f / l1;
    pL[w][lane]       = p00 * i0;
    pL[w][64 + lane]  = p01 * i0;
    pL[w][128 + lane] = p10 * i1;
    pL[w][192 + lane] = p11 * i1;
    float o0 = 0.f, o1 = 0.f;
    #pragma unroll 8
    for (int k = 0; k < 128; ++k) {
      float vv = Vl[k * 64 + lane];
      o0 = fmaf(pL[w][k], vv, o0);
      o1 = fmaf(pL[w][128 + k], vv, o1);
    }
    // SWZ stores: row r = q*16 + b  ->  rt = q, m15 = b
    aout[(((size_t)q0 * 8 + kcS) * 64 + kqS * 16 + b) * 8 + jS] = f2bf(o0);
    if (has1)
      aout[(((size_t)q1 * 8 + kcS) * 64 + kqS * 16 + b) * 8 + jS] = f2bf(o1);
  }
}

// ============ table/hand heads + upsample scatter ============
__global__ __launch_bounds__(256) void k_th(
    const ushort_t* __restrict__ x2, const float* __restrict__ tw,
    const float* __restrict__ tb, const float* __restrict__ hwgt,
    const float* __restrict__ hb, float* __restrict__ out)
{
  int x = blockIdx.x;                 // s*584 + hw*2 + half
  int s = x / 584;
  int rem = x % 584;
  int hw = rem >> 1, half = rem & 1;
  int j = threadIdx.x & 31, rr = threadIdx.x >> 5;
  int b = half * 8 + rr;
  const float* W;
  const float* Bi;
  if (hw < 256) { W = tw; Bi = tb; } else { W = hwgt; Bi = hb; }
  const ushort_t* row = x2 + ((size_t)(s * cHW + hw) * cB + b) * cC;
  float acc = Bi[j];
  for (int c = 0; c < cC; c += 4) {
    uint2 hv = *(const uint2*)(row + c);
    acc = fmaf(bf2f((ushort_t)(hv.x & 0xffff)), W[(c + 0) * 32 + j], acc);
    acc = fmaf(bf2f((ushort_t)(hv.x >> 16)),   W[(c + 1) * 32 + j], acc);
    acc = fmaf(bf2f((ushort_t)(hv.y & 0xffff)), W[(c + 2) * 32 + j], acc);
    acc = fmaf(bf2f((ushort_t)(hv.y >> 16)),   W[(c + 3) * 32 + j], acc);
  }
  int uh = j >> 3, uw = (j >> 1) & 3, uc = j & 1;
  size_t idx;
  if (hw < 256) {
    int th = hw >> 4, twi = hw & 15;
    idx = TX_OFF + ((((size_t)(s * cB + b)) * 2 + uc) * 64 + (th * 4 + uh)) * 64 + (twi * 4 + uw);
  } else {
    int h2 = hw - 256;
    int hh = h2 / 6, ww = h2 % 6;
    idx = HX_OFF + ((((size_t)(s * cB + b)) * 2 + uc) * 24 + (hh * 4 + uh)) * 24 + (ww * 4 + uw);
  }
  out[idx] = acc;
}

// ============ gx heads: mode / shape / color ============
__global__ __launch_bounds__(128) void k_gx(
    const ushort_t* __restrict__ x2,
    const float* __restrict__ mw, const float* __restrict__ mbi,
    const float* __restrict__ sw, const float* __restrict__ sbi,
    const float* __restrict__ cw, const float* __restrict__ cbi,
    float* __restrict__ out)
{
  int sb = blockIdx.x;              // s*16 + b
  int s = sb >> 4, b = sb & 15;
  __shared__ float rowL[256];
  const ushort_t* row = x2 + ((size_t)(s * cHW + 292) * cB + b) * cC;
  for (int i = threadIdx.x; i < 256; i += 128) rowL[i] = bf2f(row[i]);
  __syncthreads();
  int j = threadIdx.x;
  if (j < 100) {
    const float* W;
    const float* Bi;
    int jj, M;
    size_t off;
    if (j < 20)      { W = mw; Bi = mbi; jj = j;      M = 20; off = 0;     }
    else if (j < 84) { W = sw; Bi = sbi; jj = j - 20; M = 64; off = 5120;  }
    else             { W = cw; Bi = cbi; jj = j - 84; M = 16; off = 21504; }
    float acc = Bi[jj];
    for (int c = 0; c < 256; ++c) acc = fmaf(rowL[c], W[c * M + jj], acc);
    out[off + (size_t)sb * M + jj] = acc;
  }
}

extern "C" void kernel_launch(void* const* d_in, const int* in_sizes, int n_in,
                              void* d_out, int out_size, void* d_ws, size_t ws_size,
                              hipStream_t stream)
{
  const int*   tq       = (const int*)d_in[0];
  const int*   pad_q    = (const int*)d_in[1];
  const float* xk       = (const float*)d_in[2];
  const int*   tk       = (const int*)d_in[3];
  const int*   pad_k    = (const int*)d_in[4];
  const float* spatial  = (const float*)d_in[8];
  const float* temporal = (const float*)d_in[9];
  const float* ln1_g    = (const float*)d_in[10];
  const float* ln1_b    = (const float*)d_in[11];
  const float* wq       = (const float*)d_in[12];
  const float* bq       = (const float*)d_in[13];
  const float* wk       = (const float*)d_in[14];
  const float* bk       = (const float*)d_in[15];
  const float* wv       = (const float*)d_in[16];
  const float* bv       = (const float*)d_in[17];
  const float* wo       = (const float*)d_in[18];
  const float* bo       = (const float*)d_in[19];
  const float* ln2_g    = (const float*)d_in[20];
  const float* ln2_b    = (const float*)d_in[21];
  const float* w1       = (const float*)d_in[22];
  const float* b1       = (const float*)d_in[23];
  const float* w2       = (const float*)d_in[24];
  const float* b2       = (const float*)d_in[25];
  const float* table_w  = (const float*)d_in[26];
  const float* table_b  = (const float*)d_in[27];
  const float* hand_w   = (const float*)d_in[28];
  const float* hand_b   = (const float*)d_in[29];
  const float* mode_w   = (const float*)d_in[30];
  const float* mode_b   = (const float*)d_in[31];
  const float* shape_w  = (const float*)d_in[32];
  const float* shape_b  = (const float*)d_in[33];
  const float* color_w  = (const float*)d_in[34];
  const float* color_b  = (const float*)d_in[35];
  float* out = (float*)d_out;

  // Workspace layout (~82 MB)
  char* ws = (char*)d_ws;
  const size_t NB2 = (size_t)cN * cC * sizeof(ushort_t);       // 38,404,096
  ushort_t* buf1 = (ushort_t*)ws;                              // qn_swz -> a_swz -> xln_swz
  ushort_t* buf2 = (ushort_t*)(ws + NB2);                      // Q -> x -> x2 (in-place)
  char* p = ws + 2 * NB2;
  ushort_t* Kb  = (ushort_t*)p;  p += (size_t)cLK * cB * 256 * 2;   // 1 MB
  ushort_t* Vb  = (ushort_t*)p;  p += (size_t)cLK * cB * 256 * 2;   // 1 MB
  ushort_t* xkb = (ushort_t*)p;  p += (size_t)cLK * cB * 256 * 2;   // 1 MB (SWZ)
  ushort_t* wqs = (ushort_t*)p;  p += 256 * 256 * 2;
  ushort_t* wks = (ushort_t*)p;  p += 256 * 256 * 2;
  ushort_t* wvs = (ushort_t*)p;  p += 256 * 256 * 2;
  ushort_t* wos = (ushort_t*)p;  p += 256 * 256 * 2;
  ushort_t* w1s = (ushort_t*)p;  p += 256 * 1024 * 2;
  ushort_t* w2s = (ushort_t*)p;  p += 1024 * 256 * 2;

  // weight / input prep
  k_cvt_swz<<<cLK * cB * 256 / 4 / 256, 256, 0, stream>>>(xk, xkb);
  k_swz<<<32, 256, 0, stream>>>(wq, wqs, 256);
  k_swz<<<32, 256, 0, stream>>>(wk, wks, 256);
  k_swz<<<32, 256, 0, stream>>>(wv, wvs, 256);
  k_swz<<<32, 256, 0, stream>>>(wo, wos, 256);
  k_swz<<<128, 256, 0, stream>>>(w1, w1s, 1024);
  k_swz<<<128, 256, 0, stream>>>(w2, w2s, 256);

  // pipeline
  k_qn<<<cN / 4, 256, 0, stream>>>(tq, spatial, temporal, ln1_g, ln1_b, buf1);
  k_kv<<<dim3(32, 2), 256, 0, stream>>>(xkb, wks, wvs, bk, bv, Kb, Vb);
  k_qproj<<<cN / 64, 256, 0, stream>>>(buf1, wqs, bq, buf2);
  k_attn<<<dim3((cLQ + 31) / 32, cH, cB), 256, 0, stream>>>(buf2, Kb, Vb, tq, tk,
                                                            pad_q, pad_k, buf1);
  k_wo<<<cN / 64, 256, 0, stream>>>(buf1, wos, bo, tq, spatial, temporal, buf2);
  k_ln<<<cN / 4, 256, 0, stream>>>(buf2, ln2_g, ln2_b, buf1);
  k_ffn<<<cN / 64, 256, 0, stream>>>(buf1, w1s, b1, w2s, b2, buf2);
  k_th<<<cS * 292 * 2, 256, 0, stream>>>(buf2, table_w, table_b, hand_w, hand_b, out);
  k_gx<<<cS * cB, 128, 0, stream>>>(buf2, mode_w, mode_b, shape_w, shape_b,
                                    color_w, color_b, out);
}

// Round 5
// 677.063 us; speedup vs baseline: 4.0084x; 1.5103x over previous
//
#include <hip/hip_runtime.h>
#include <hip/hip_bf16.h>

namespace {
constexpr int cS = 16, cB = 16, cC = 256, cH = 4, cDH = 64, cHW = 293;
constexpr int cLQ = cS * cHW;      // 4688
constexpr int cLK = 128;
constexpr int cN  = cLQ * cC;      // placeholder avoid unused warn
constexpr int cNN = cLQ * cB;      // 75008
constexpr size_t TX_OFF = 25600;         // 5120 + 16384 + 4096
constexpr size_t HX_OFF = 2122752;       // TX_OFF + 16*16*2*64*64
}

typedef unsigned short ushort_t;
typedef unsigned int uint_t;
typedef __attribute__((ext_vector_type(8))) short short8;    // 8 bf16 (4 VGPRs)
typedef __attribute__((ext_vector_type(4))) float f32x4;     // MFMA C/D frag

__device__ __forceinline__ float bf2f(ushort_t u) {
  return __uint_as_float(((uint_t)u) << 16);
}
__device__ __forceinline__ ushort_t f2bf(float f) {
  __hip_bfloat16 h = __float2bfloat16(f);
  return *(ushort_t*)&h;
}

// SWZ frag-linear activation layout for a [rows][256] matrix:
// element (r, c) lives at ((r>>4)*8 + (c>>5))*512 + ((c>>3)&3)*128 + (r&15)*8 + (c&7)
__device__ __forceinline__ size_t swz(int r, int c) {
  return (((size_t)(r >> 4) * 8 + (c >> 5)) * 64 + ((c >> 3) & 3) * 16 + (r & 15)) * 8 + (c & 7);
}

// ============ weight swizzle: W[K][N] fp32 -> B-frag order bf16 ============
__global__ __launch_bounds__(256) void k_swz(
    const float* __restrict__ W, ushort_t* __restrict__ Ws, int N)
{
  int slot = blockIdx.x * 256 + threadIdx.x;
  int lane = slot & 63;
  int fr   = slot >> 6;            // kc*(N/16) + nb
  int NB   = N >> 4;
  int nb   = fr % NB, kc = fr / NB;
  int n    = nb * 16 + (lane & 15);
  int k0   = kc * 32 + (lane >> 4) * 8;
  ushort_t tmp[8];
  #pragma unroll
  for (int i = 0; i < 8; ++i) tmp[i] = f2bf(W[(size_t)(k0 + i) * N + n]);
  *(uint4*)&Ws[(size_t)slot * 8] = *(uint4*)tmp;
}

// ============ xk fp32 row-major -> SWZ bf16 ============
__global__ __launch_bounds__(256) void k_cvt_swz(
    const float* __restrict__ src, ushort_t* __restrict__ dst)
{
  int i4 = blockIdx.x * 256 + threadIdx.x;      // one thread per 4 elems
  int r = i4 >> 6;
  int c0 = (i4 & 63) * 4;
  float4 v = *(const float4*)(src + (size_t)r * 256 + c0);
  ushort_t o[4] = {f2bf(v.x), f2bf(v.y), f2bf(v.z), f2bf(v.w)};
  *(uint2*)&dst[swz(r, c0)] = *(uint2*)o;
}

// ============ xq build + LayerNorm1 -> qn (SWZ bf16), wave per row ============
__global__ __launch_bounds__(256) void k_qn(
    const int* __restrict__ tq, const float* __restrict__ spatial,
    const float* __restrict__ temporal, const float* __restrict__ g,
    const float* __restrict__ bt, ushort_t* __restrict__ qn)
{
  int w = threadIdx.x >> 6, lane = threadIdx.x & 63;
  int r = blockIdx.x * 4 + w;          // r = q*16 + b
  int b = r & 15, q = r >> 4;
  int s = q / cHW, hw = q % cHW;
  int t = tq[s * cB + b];
  int c0 = lane * 4;
  float4 tv = *(const float4*)(temporal + (size_t)t * cC + c0);
  float4 sv = *(const float4*)(spatial + (size_t)hw * cC + c0);
  float v0 = tv.x + sv.x, v1 = tv.y + sv.y, v2 = tv.z + sv.z, v3 = tv.w + sv.w;
  float sum = v0 + v1 + v2 + v3;
  float sum2 = v0 * v0 + v1 * v1 + v2 * v2 + v3 * v3;
  #pragma unroll
  for (int off = 32; off >= 1; off >>= 1) {
    sum  += __shfl_xor(sum,  off, 64);
    sum2 += __shfl_xor(sum2, off, 64);
  }
  float mean = sum * (1.0f / cC);
  float var  = sum2 * (1.0f / cC) - mean * mean;
  float inv  = rsqrtf(var + 1e-5f);
  float4 g4 = *(const float4*)(g + c0);
  float4 b4 = *(const float4*)(bt + c0);
  ushort_t o[4] = {f2bf((v0 - mean) * inv * g4.x + b4.x),
                   f2bf((v1 - mean) * inv * g4.y + b4.y),
                   f2bf((v2 - mean) * inv * g4.z + b4.z),
                   f2bf((v3 - mean) * inv * g4.w + b4.w)};
  *(uint2*)&qn[swz(r, c0)] = *(uint2*)o;
}

// ============ LayerNorm: x (row-major bf16) -> xln (SWZ bf16), wave per row ============
__global__ __launch_bounds__(256) void k_ln(
    const ushort_t* __restrict__ src, const float* __restrict__ g,
    const float* __restrict__ bt, ushort_t* __restrict__ dst)
{
  int w = threadIdx.x >> 6, lane = threadIdx.x & 63;
  int r = blockIdx.x * 4 + w;
  int c0 = lane * 4;
  uint2 hv = *(const uint2*)(src + (size_t)r * cC + c0);
  float v0 = bf2f((ushort_t)(hv.x & 0xffff)), v1 = bf2f((ushort_t)(hv.x >> 16));
  float v2 = bf2f((ushort_t)(hv.y & 0xffff)), v3 = bf2f((ushort_t)(hv.y >> 16));
  float sum = v0 + v1 + v2 + v3;
  float sum2 = v0 * v0 + v1 * v1 + v2 * v2 + v3 * v3;
  #pragma unroll
  for (int off = 32; off >= 1; off >>= 1) {
    sum  += __shfl_xor(sum,  off, 64);
    sum2 += __shfl_xor(sum2, off, 64);
  }
  float mean = sum * (1.0f / cC);
  float var  = sum2 * (1.0f / cC) - mean * mean;
  float inv  = rsqrtf(var + 1e-5f);
  float4 g4 = *(const float4*)(g + c0);
  float4 b4 = *(const float4*)(bt + c0);
  ushort_t o[4] = {f2bf((v0 - mean) * inv * g4.x + b4.x),
                   f2bf((v1 - mean) * inv * g4.y + b4.y),
                   f2bf((v2 - mean) * inv * g4.z + b4.z),
                   f2bf((v3 - mean) * inv * g4.w + b4.w)};
  *(uint2*)&dst[swz(r, c0)] = *(uint2*)o;
}

// ============ core GEMM: 64 rows x 256 cols, K=256, no LDS, N-split waves ============
__device__ __forceinline__ void gemm_k256(
    const ushort_t* __restrict__ A, const ushort_t* __restrict__ Ws,
    int rt0, int slot0, int NB, int lane, f32x4 c[4][4])
{
  #pragma unroll 2
  for (int kc = 0; kc < 8; ++kc) {
    short8 a[4];
    #pragma unroll
    for (int mf = 0; mf < 4; ++mf)
      a[mf] = *(const short8*)(A + (((size_t)(rt0 + mf) * 8 + kc) * 64 + lane) * 8);
    #pragma unroll
    for (int nb = 0; nb < 4; ++nb) {
      short8 b = *(const short8*)(Ws + (((size_t)kc * NB + slot0 + nb) * 64 + lane) * 8);
      #pragma unroll
      for (int mf = 0; mf < 4; ++mf)
        c[mf][nb] = __builtin_amdgcn_mfma_f32_16x16x32_bf16(a[mf], b, c[mf][nb], 0, 0, 0);
    }
  }
}

// ============ Q projection: qn_swz @ wq + bq -> Q row-major bf16 ============
__global__ __launch_bounds__(256) void k_qproj(
    const ushort_t* __restrict__ A, const ushort_t* __restrict__ Ws,
    const float* __restrict__ Bi, ushort_t* __restrict__ Out)
{
  const int lane = threadIdx.x & 63, w = threadIdx.x >> 6;
  const int rt0 = blockIdx.x * 4, row0 = blockIdx.x * 64;
  f32x4 z = {0.f, 0.f, 0.f, 0.f};
  f32x4 c[4][4];
  #pragma unroll
  for (int mf = 0; mf < 4; ++mf)
    #pragma unroll
    for (int nb = 0; nb < 4; ++nb) c[mf][nb] = z;
  gemm_k256(A, Ws, rt0, w * 4, 16, lane, c);
  const int lane15 = lane & 15, kq = lane >> 4;
  #pragma unroll
  for (int nb = 0; nb < 4; ++nb) {
    int col = w * 64 + nb * 16 + lane15;
    float bias = Bi[col];
    #pragma unroll
    for (int mf = 0; mf < 4; ++mf)
      #pragma unroll
      for (int i = 0; i < 4; ++i) {
        int row = row0 + mf * 16 + kq * 4 + i;
        Out[(size_t)row * 256 + col] = f2bf(c[mf][nb][i] + bias);
      }
  }
}

// ============ K/V projections ============
__global__ __launch_bounds__(256) void k_kv(
    const ushort_t* __restrict__ xkb, const ushort_t* __restrict__ wks,
    const ushort_t* __restrict__ wvs, const float* __restrict__ bk,
    const float* __restrict__ bv, ushort_t* __restrict__ Kb,
    ushort_t* __restrict__ Vb)
{
  const ushort_t* Ws = blockIdx.y ? wvs : wks;
  const float* Bi = blockIdx.y ? bv : bk;
  ushort_t* Out = blockIdx.y ? Vb : Kb;
  const int lane = threadIdx.x & 63, w = threadIdx.x >> 6;
  const int rt0 = blockIdx.x * 4, row0 = blockIdx.x * 64;
  f32x4 z = {0.f, 0.f, 0.f, 0.f};
  f32x4 c[4][4];
  #pragma unroll
  for (int mf = 0; mf < 4; ++mf)
    #pragma unroll
    for (int nb = 0; nb < 4; ++nb) c[mf][nb] = z;
  gemm_k256(xkb, Ws, rt0, w * 4, 16, lane, c);
  const int lane15 = lane & 15, kq = lane >> 4;
  #pragma unroll
  for (int nb = 0; nb < 4; ++nb) {
    int col = w * 64 + nb * 16 + lane15;
    float bias = Bi[col];
    #pragma unroll
    for (int mf = 0; mf < 4; ++mf)
      #pragma unroll
      for (int i = 0; i < 4; ++i) {
        int row = row0 + mf * 16 + kq * 4 + i;
        Out[(size_t)row * 256 + col] = f2bf(c[mf][nb][i] + bias);
      }
  }
}

// ============ wo projection + recomputed-xq residual -> x row-major bf16 ============
__global__ __launch_bounds__(256) void k_wo(
    const ushort_t* __restrict__ A, const ushort_t* __restrict__ Ws,
    const float* __restrict__ Bi, const int* __restrict__ tq,
    const float* __restrict__ spatial, const float* __restrict__ temporal,
    ushort_t* __restrict__ Out)
{
  const int lane = threadIdx.x & 63, w = threadIdx.x >> 6;
  const int rt0 = blockIdx.x * 4, row0 = blockIdx.x * 64;
  f32x4 z = {0.f, 0.f, 0.f, 0.f};
  f32x4 c[4][4];
  #pragma unroll
  for (int mf = 0; mf < 4; ++mf)
    #pragma unroll
    for (int nb = 0; nb < 4; ++nb) c[mf][nb] = z;
  gemm_k256(A, Ws, rt0, w * 4, 16, lane, c);
  const int lane15 = lane & 15, kq = lane >> 4;
  int tt[4][4], hws[4];
  #pragma unroll
  for (int mf = 0; mf < 4; ++mf) {
    int q = rt0 + mf;
    int s = q / cHW;
    hws[mf] = q % cHW;
    #pragma unroll
    for (int i = 0; i < 4; ++i) tt[mf][i] = tq[s * cB + kq * 4 + i];
  }
  #pragma unroll
  for (int nb = 0; nb < 4; ++nb) {
    int col = w * 64 + nb * 16 + lane15;
    float bias = Bi[col];
    #pragma unroll
    for (int mf = 0; mf < 4; ++mf) {
      float sp = spatial[(size_t)hws[mf] * cC + col];
      #pragma unroll
      for (int i = 0; i < 4; ++i) {
        int row = row0 + mf * 16 + kq * 4 + i;
        float xq = temporal[(size_t)tt[mf][i] * cC + col] + sp;
        Out[(size_t)row * 256 + col] = f2bf(c[mf][nb][i] + bias + xq);
      }
    }
  }
}

// ============ fused FFN (unchanged from R4) ============
__global__ __launch_bounds__(256) void k_ffn(
    const ushort_t* __restrict__ xln, const ushort_t* __restrict__ w1s,
    const float* __restrict__ b1, const ushort_t* __restrict__ w2s,
    const float* __restrict__ b2, ushort_t* __restrict__ xbuf)
{
  __shared__ ushort_t hL[8 * 4 * 64 * 8];    // 32 KB
  const int lane = threadIdx.x & 63, w = threadIdx.x >> 6;
  const int lane15 = lane & 15, kq = lane >> 4;
  const int rt0 = blockIdx.x * 4, row0 = blockIdx.x * 64;
  f32x4 z = {0.f, 0.f, 0.f, 0.f};
  f32x4 c2[4][4];
  #pragma unroll
  for (int mf = 0; mf < 4; ++mf)
    #pragma unroll
    for (int nb = 0; nb < 4; ++nb) c2[mf][nb] = z;

  for (int hc = 0; hc < 4; ++hc) {
    f32x4 c1[4][4];
    #pragma unroll
    for (int mf = 0; mf < 4; ++mf)
      #pragma unroll
      for (int nb = 0; nb < 4; ++nb) c1[mf][nb] = z;
    gemm_k256(xln, w1s, rt0, hc * 16 + w * 4, 64, lane, c1);
    __syncthreads();
    #pragma unroll
    for (int nb = 0; nb < 4; ++nb) {
      float bias = b1[hc * 256 + w * 64 + nb * 16 + lane15];
      int k2l = w * 64 + nb * 16 + lane15;
      int kc2l = k2l >> 5, kq2 = (k2l >> 3) & 3, j2 = k2l & 7;
      #pragma unroll
      for (int mf = 0; mf < 4; ++mf)
        #pragma unroll
        for (int i = 0; i < 4; ++i) {
          float xx = c1[mf][nb][i] + bias;
          float u = 0.7978845608028654f * (xx + 0.044715f * xx * xx * xx);
          u = fminf(fmaxf(u, -15.f), 15.f);
          float e = __expf(2.f * u);
          float t = (e - 1.f) / (e + 1.f);
          hL[(((kc2l * 4 + mf) * 64) + kq2 * 16 + kq * 4 + i) * 8 + j2] =
              f2bf(0.5f * xx * (1.f + t));
        }
    }
    __syncthreads();
    #pragma unroll 2
    for (int kc2 = 0; kc2 < 8; ++kc2) {
      short8 a2[4];
      #pragma unroll
      for (int mf = 0; mf < 4; ++mf)
        a2[mf] = *(const short8*)&hL[((kc2 * 4 + mf) * 64 + lane) * 8];
      #pragma unroll
      for (int nb = 0; nb < 4; ++nb) {
        short8 b = *(const short8*)(w2s +
            (((size_t)(hc * 8 + kc2) * 16 + w * 4 + nb) * 64 + lane) * 8);
        #pragma unroll
        for (int mf = 0; mf < 4; ++mf)
          c2[mf][nb] = __builtin_amdgcn_mfma_f32_16x16x32_bf16(a2[mf], b, c2[mf][nb], 0, 0, 0);
      }
    }
  }
  #pragma unroll
  for (int nb = 0; nb < 4; ++nb) {
    int col = w * 64 + nb * 16 + lane15;
    float bias = b2[col];
    #pragma unroll
    for (int mf = 0; mf < 4; ++mf)
      #pragma unroll
      for (int i = 0; i < 4; ++i) {
        size_t idx = (size_t)(row0 + mf * 16 + kq * 4 + i) * 256 + col;
        float val = c2[mf][nb][i] + bias + bf2f(xbuf[idx]);
        xbuf[idx] = f2bf(val);
      }
  }
}

// ============ MFMA attention: per (b,h), 16 q-tiles (of 16 rows) per block ============
// LDS: KL 128x72 (18432B) + VtL 64x136 (17408B) + pL 4x16x136 (17408B) + tk (512B) = 53760B
__global__ __launch_bounds__(256) void k_attn(
    const ushort_t* __restrict__ Qb, const ushort_t* __restrict__ Kb,
    const ushort_t* __restrict__ Vb, const int* __restrict__ tq,
    const int* __restrict__ tk, const int* __restrict__ pad_q,
    const int* __restrict__ pad_k, ushort_t* __restrict__ aout)
{
  __shared__ ushort_t KL[128 * 72];     // [k][d], pad 72
  __shared__ ushort_t VtL[64 * 136];    // [d][k], pad 136
  __shared__ ushort_t pL[4][16 * 136];  // per-wave P tile [m][k], pad 136
  __shared__ int tkL[128];

  const int h = blockIdx.y, b = blockIdx.z;
  const int tid = threadIdx.x, lane = tid & 63, w = tid >> 6;
  const int m15 = lane & 15, quad = lane >> 4;

  for (int i = tid; i < 128 * 64; i += 256) {
    int k = i >> 6, d = i & 63;
    size_t src = (size_t)(k * cB + b) * 256 + h * 64 + d;
    ushort_t kv = Kb[src];
    ushort_t vv = Vb[src];
    KL[k * 72 + d] = kv;
    VtL[d * 136 + k] = vv;
  }
  if (tid < 128) tkL[tid] = tk[tid * cB + b];
  __syncthreads();
  const int pk = pad_k[b];
  const int pq = pad_q[b] * cHW;
  ushort_t* pRow = pL[w];
  const f32x4 z = {0.f, 0.f, 0.f, 0.f};

  for (int pr = 0; pr < 4; ++pr) {
    int qt = blockIdx.x * 16 + pr * 4 + w;
    if (qt >= 293) break;                       // wave-uniform
    // ---- Q A-frags (2 k-chunks of 32 over d)
    const ushort_t* qrow =
        Qb + ((size_t)((qt * 16 + m15) * cB + b)) * 256 + h * 64 + quad * 8;
    short8 qa0 = *(const short8*)(qrow);
    short8 qa1 = *(const short8*)(qrow + 32);
    // ---- scores S = Q @ K^T : 8 n-frags of 16 k-indices
    f32x4 s[8];
    #pragma unroll
    for (int nf = 0; nf < 8; ++nf) {
      const ushort_t* kp = KL + (nf * 16 + m15) * 72 + quad * 8;
      short8 b0 = *(const short8*)(kp);
      short8 b1 = *(const short8*)(kp + 32);
      s[nf] = __builtin_amdgcn_mfma_f32_16x16x32_bf16(qa0, b0, z, 0, 0, 0);
      s[nf] = __builtin_amdgcn_mfma_f32_16x16x32_bf16(qa1, b1, s[nf], 0, 0, 0);
    }
    // ---- per-row params: row r = quad*4+i, q_global = qt*16 + r
    int tqv[4], qok[4];
    #pragma unroll
    for (int i = 0; i < 4; ++i) {
      int qg = qt * 16 + quad * 4 + i;
      int sидx = (qg * 3579) >> 20;            // exact q/293 for q<14768
      tqv[i] = tq[sидx * cB + b];
      qok[i] = (qg < pq);
    }
    // ---- mask + scale
    #pragma unroll
    for (int nf = 0; nf < 8; ++nf) {
      int kidx = nf * 16 + m15;
      int tkc = tkL[kidx];
      bool kok = (kidx < pk);
      #pragma unroll
      for (int i = 0; i < 4; ++i) {
        bool ok = kok && qok[i] && (tkc <= tqv[i]);
        s[nf][i] = ok ? s[nf][i] * 0.125f : -1e9f;
      }
    }
    // ---- softmax: row max & sum across 16-lane col group
    float mx[4], l[4];
    #pragma unroll
    for (int i = 0; i < 4; ++i) {
      float m = s[0][i];
      #pragma unroll
      for (int nf = 1; nf < 8; ++nf) m = fmaxf(m, s[nf][i]);
      #pragma unroll
      for (int off = 8; off >= 1; off >>= 1) m = fmaxf(m, __shfl_xor(m, off, 64));
      mx[i] = m;
    }
    #pragma unroll
    for (int i = 0; i < 4; ++i) l[i] = 0.f;
    #pragma unroll
    for (int nf = 0; nf < 8; ++nf)
      #pragma unroll
      for (int i = 0; i < 4; ++i) {
        float p = __expf(s[nf][i] - mx[i]);
        s[nf][i] = p;
        l[i] += p;
      }
    #pragma unroll
    for (int i = 0; i < 4; ++i) {
      float t = l[i];
      #pragma unroll
      for (int off = 8; off >= 1; off >>= 1) t += __shfl_xor(t, off, 64);
      l[i] = 1.0f / t;
    }
    // ---- P (unnormalized, bf16) -> per-wave LDS tile [m][136]
    #pragma unroll
    for (int nf = 0; nf < 8; ++nf)
      #pragma unroll
      for (int i = 0; i < 4; ++i)
        pRow[(quad * 4 + i) * 136 + nf * 16 + m15] = f2bf(s[nf][i]);
    // ---- O = P @ V : 4 k-chunks x 4 n-frags (d)
    f32x4 o[4];
    #pragma unroll
    for (int nf = 0; nf < 4; ++nf) o[nf] = z;
    #pragma unroll
    for (int kc = 0; kc < 4; ++kc) {
      short8 pa = *(const short8*)(pRow + m15 * 136 + kc * 32 + quad * 8);
      #pragma unroll
      for (int nf = 0; nf < 4; ++nf) {
        short8 vb = *(const short8*)(VtL + (nf * 16 + m15) * 136 + kc * 32 + quad * 8);
        o[nf] = __builtin_amdgcn_mfma_f32_16x16x32_bf16(pa, vb, o[nf], 0, 0, 0);
      }
    }
    // ---- epilogue: normalize, store to aout in SWZ layout
    #pragma unroll
    for (int nf = 0; nf < 4; ++nf) {
      int c = h * 64 + nf * 16 + m15;
      size_t base = ((size_t)0 * 8 + (c >> 5)) * 64 + ((c >> 3) & 3) * 16 + b;
      int cj = c & 7;
      #pragma unroll
      for (int i = 0; i < 4; ++i) {
        int qg = qt * 16 + quad * 4 + i;
        aout[(((size_t)qg * 8) * 64 + base) * 8 + cj] = f2bf(o[nf][i] * l[i]);
      }
    }
  }
}

// ============ table/hand heads + upsample scatter ============
__global__ __launch_bounds__(256) void k_th(
    const ushort_t* __restrict__ x2, const float* __restrict__ tw,
    const float* __restrict__ tb, const float* __restrict__ hwgt,
    const float* __restrict__ hb, float* __restrict__ out)
{
  int x = blockIdx.x;                 // s*584 + hw*2 + half
  int s = x / 584;
  int rem = x % 584;
  int hw = rem >> 1, half = rem & 1;
  int j = threadIdx.x & 31, rr = threadIdx.x >> 5;
  int b = half * 8 + rr;
  const float* W;
  const float* Bi;
  if (hw < 256) { W = tw; Bi = tb; } else { W = hwgt; Bi = hb; }
  const ushort_t* row = x2 + ((size_t)(s * cHW + hw) * cB + b) * cC;
  float acc = Bi[j];
  for (int c = 0; c < cC; c += 4) {
    uint2 hv = *(const uint2*)(row + c);
    acc = fmaf(bf2f((ushort_t)(hv.x & 0xffff)), W[(c + 0) * 32 + j], acc);
    acc = fmaf(bf2f((ushort_t)(hv.x >> 16)),   W[(c + 1) * 32 + j], acc);
    acc = fmaf(bf2f((ushort_t)(hv.y & 0xffff)), W[(c + 2) * 32 + j], acc);
    acc = fmaf(bf2f((ushort_t)(hv.y >> 16)),   W[(c + 3) * 32 + j], acc);
  }
  int uh = j >> 3, uw = (j >> 1) & 3, uc = j & 1;
  size_t idx;
  if (hw < 256) {
    int th = hw >> 4, twi = hw & 15;
    idx = TX_OFF + ((((size_t)(s * cB + b)) * 2 + uc) * 64 + (th * 4 + uh)) * 64 + (twi * 4 + uw);
  } else {
    int h2 = hw - 256;
    int hh = h2 / 6, ww = h2 % 6;
    idx = HX_OFF + ((((size_t)(s * cB + b)) * 2 + uc) * 24 + (hh * 4 + uh)) * 24 + (ww * 4 + uw);
  }
  out[idx] = acc;
}

// ============ gx heads: mode / shape / color ============
__global__ __launch_bounds__(128) void k_gx(
    const ushort_t* __restrict__ x2,
    const float* __restrict__ mw, const float* __restrict__ mbi,
    const float* __restrict__ sw, const float* __restrict__ sbi,
    const float* __restrict__ cw, const float* __restrict__ cbi,
    float* __restrict__ out)
{
  int sb = blockIdx.x;              // s*16 + b
  int s = sb >> 4, b = sb & 15;
  __shared__ float rowL[256];
  const ushort_t* row = x2 + ((size_t)(s * cHW + 292) * cB + b) * cC;
  for (int i = threadIdx.x; i < 256; i += 128) rowL[i] = bf2f(row[i]);
  __syncthreads();
  int j = threadIdx.x;
  if (j < 100) {
    const float* W;
    const float* Bi;
    int jj, M;
    size_t off;
    if (j < 20)      { W = mw; Bi = mbi; jj = j;      M = 20; off = 0;     }
    else if (j < 84) { W = sw; Bi = sbi; jj = j - 20; M = 64; off = 5120;  }
    else             { W = cw; Bi = cbi; jj = j - 84; M = 16; off = 21504; }
    float acc = Bi[jj];
    for (int c = 0; c < 256; ++c) acc = fmaf(rowL[c], W[c * M + jj], acc);
    out[off + (size_t)sb * M + jj] = acc;
  }
}

extern "C" void kernel_launch(void* const* d_in, const int* in_sizes, int n_in,
                              void* d_out, int out_size, void* d_ws, size_t ws_size,
                              hipStream_t stream)
{
  const int*   tq       = (const int*)d_in[0];
  const int*   pad_q    = (const int*)d_in[1];
  const float* xk       = (const float*)d_in[2];
  const int*   tk       = (const int*)d_in[3];
  const int*   pad_k    = (const int*)d_in[4];
  const float* spatial  = (const float*)d_in[8];
  const float* temporal = (const float*)d_in[9];
  const float* ln1_g    = (const float*)d_in[10];
  const float* ln1_b    = (const float*)d_in[11];
  const float* wq       = (const float*)d_in[12];
  const float* bq       = (const float*)d_in[13];
  const float* wk       = (const float*)d_in[14];
  const float* bk       = (const float*)d_in[15];
  const float* wv       = (const float*)d_in[16];
  const float* bv       = (const float*)d_in[17];
  const float* wo       = (const float*)d_in[18];
  const float* bo       = (const float*)d_in[19];
  const float* ln2_g    = (const float*)d_in[20];
  const float* ln2_b    = (const float*)d_in[21];
  const float* w1       = (const float*)d_in[22];
  const float* b1       = (const float*)d_in[23];
  const float* w2       = (const float*)d_in[24];
  const float* b2       = (const float*)d_in[25];
  const float* table_w  = (const float*)d_in[26];
  const float* table_b  = (const float*)d_in[27];
  const float* hand_w   = (const float*)d_in[28];
  const float* hand_b   = (const float*)d_in[29];
  const float* mode_w   = (const float*)d_in[30];
  const float* mode_b   = (const float*)d_in[31];
  const float* shape_w  = (const float*)d_in[32];
  const float* shape_b  = (const float*)d_in[33];
  const float* color_w  = (const float*)d_in[34];
  const float* color_b  = (const float*)d_in[35];
  float* out = (float*)d_out;

  // Workspace layout (~82 MB)
  char* ws = (char*)d_ws;
  const size_t NB2 = (size_t)cNN * cC * sizeof(ushort_t);      // 38,404,096
  ushort_t* buf1 = (ushort_t*)ws;                              // qn_swz -> a_swz -> xln_swz
  ushort_t* buf2 = (ushort_t*)(ws + NB2);                      // Q -> x -> x2 (in-place)
  char* p = ws + 2 * NB2;
  ushort_t* Kb  = (ushort_t*)p;  p += (size_t)cLK * cB * 256 * 2;   // 1 MB
  ushort_t* Vb  = (ushort_t*)p;  p += (size_t)cLK * cB * 256 * 2;   // 1 MB
  ushort_t* xkb = (ushort_t*)p;  p += (size_t)cLK * cB * 256 * 2;   // 1 MB (SWZ)
  ushort_t* wqs = (ushort_t*)p;  p += 256 * 256 * 2;
  ushort_t* wks = (ushort_t*)p;  p += 256 * 256 * 2;
  ushort_t* wvs = (ushort_t*)p;  p += 256 * 256 * 2;
  ushort_t* wos = (ushort_t*)p;  p += 256 * 256 * 2;
  ushort_t* w1s = (ushort_t*)p;  p += 256 * 1024 * 2;
  ushort_t* w2s = (ushort_t*)p;  p += 1024 * 256 * 2;

  // weight / input prep
  k_cvt_swz<<<cLK * cB * 256 / 4 / 256, 256, 0, stream>>>(xk, xkb);
  k_swz<<<32, 256, 0, stream>>>(wq, wqs, 256);
  k_swz<<<32, 256, 0, stream>>>(wk, wks, 256);
  k_swz<<<32, 256, 0, stream>>>(wv, wvs, 256);
  k_swz<<<32, 256, 0, stream>>>(wo, wos, 256);
  k_swz<<<128, 256, 0, stream>>>(w1, w1s, 1024);
  k_swz<<<128, 256, 0, stream>>>(w2, w2s, 256);

  // pipeline
  k_qn<<<cNN / 4, 256, 0, stream>>>(tq, spatial, temporal, ln1_g, ln1_b, buf1);
  k_kv<<<dim3(32, 2), 256, 0, stream>>>(xkb, wks, wvs, bk, bv, Kb, Vb);
  k_qproj<<<cNN / 64, 256, 0, stream>>>(buf1, wqs, bq, buf2);
  k_attn<<<dim3(19, cH, cB), 256, 0, stream>>>(buf2, Kb, Vb, tq, tk,
                                               pad_q, pad_k, buf1);
  k_wo<<<cNN / 64, 256, 0, stream>>>(buf1, wos, bo, tq, spatial, temporal, buf2);
  k_ln<<<cNN / 4, 256, 0, stream>>>(buf2, ln2_g, ln2_b, buf1);
  k_ffn<<<cNN / 64, 256, 0, stream>>>(buf1, w1s, b1, w2s, b2, buf2);
  k_th<<<cS * 292 * 2, 256, 0, stream>>>(buf2, table_w, table_b, hand_w, hand_b, out);
  k_gx<<<cS * cB, 128, 0, stream>>>(buf2, mode_w, mode_b, shape_w, shape_b,
                                    color_w, color_b, out);
}

// Round 6
// 672.141 us; speedup vs baseline: 4.0378x; 1.0073x over previous
//
#include <hip/hip_runtime.h>
#include <hip/hip_bf16.h>

namespace {
constexpr int cS = 16, cB = 16, cC = 256, cH = 4, cDH = 64, cHW = 293;
constexpr int cLQ = cS * cHW;      // 4688
constexpr int cLK = 128;
constexpr int cNN = cLQ * cB;      // 75008
constexpr size_t TX_OFF = 25600;         // 5120 + 16384 + 4096
constexpr size_t HX_OFF = 2122752;       // TX_OFF + 16*16*2*64*64
}

typedef unsigned short ushort_t;
typedef unsigned int uint_t;
typedef __attribute__((ext_vector_type(8))) short short8;    // 8 bf16 (4 VGPRs)
typedef __attribute__((ext_vector_type(4))) float f32x4;     // MFMA C/D frag

__device__ __forceinline__ float bf2f(ushort_t u) {
  return __uint_as_float(((uint_t)u) << 16);
}
__device__ __forceinline__ ushort_t f2bf(float f) {
  __hip_bfloat16 h = __float2bfloat16(f);
  return *(ushort_t*)&h;
}

// SWZ frag-linear activation layout for a [rows][256] matrix:
// element (r, c) -> ((r>>4)*8 + (c>>5))*512 + ((c>>3)&3)*128 + (r&15)*8 + (c&7)
__device__ __forceinline__ size_t swz(int r, int c) {
  return (((size_t)(r >> 4) * 8 + (c >> 5)) * 64 + ((c >> 3) & 3) * 16 + (r & 15)) * 8 + (c & 7);
}

// ============ merged prep: xk cvt+swz, 6 weight swizzles ============
__global__ __launch_bounds__(256) void k_prep(
    const float* __restrict__ xk, ushort_t* __restrict__ xkb,
    const float* __restrict__ wq, ushort_t* __restrict__ wqs,
    const float* __restrict__ wk, ushort_t* __restrict__ wks,
    const float* __restrict__ wv, ushort_t* __restrict__ wvs,
    const float* __restrict__ wo, ushort_t* __restrict__ wos,
    const float* __restrict__ w1, ushort_t* __restrict__ w1s,
    const float* __restrict__ w2, ushort_t* __restrict__ w2s)
{
  int bid = blockIdx.x;
  if (bid < 512) {
    // xk fp32 row-major -> SWZ bf16
    int i4 = bid * 256 + threadIdx.x;
    int r = i4 >> 6;
    int c0 = (i4 & 63) * 4;
    float4 v = *(const float4*)(xk + (size_t)r * 256 + c0);
    ushort_t o[4] = {f2bf(v.x), f2bf(v.y), f2bf(v.z), f2bf(v.w)};
    *(uint2*)&xkb[swz(r, c0)] = *(uint2*)o;
    return;
  }
  int rr = bid - 512;
  const float* W; ushort_t* Ws; int N; int lb;
  if      (rr < 32)  { W = wq; Ws = wqs; N = 256;  lb = rr; }
  else if (rr < 64)  { W = wk; Ws = wks; N = 256;  lb = rr - 32; }
  else if (rr < 96)  { W = wv; Ws = wvs; N = 256;  lb = rr - 64; }
  else if (rr < 128) { W = wo; Ws = wos; N = 256;  lb = rr - 96; }
  else if (rr < 256) { W = w1; Ws = w1s; N = 1024; lb = rr - 128; }
  else               { W = w2; Ws = w2s; N = 256;  lb = rr - 256; }
  int slot = lb * 256 + threadIdx.x;
  int lane = slot & 63;
  int fr   = slot >> 6;
  int NB   = N >> 4;
  int nb   = fr % NB, kc = fr / NB;
  int n    = nb * 16 + (lane & 15);
  int k0   = kc * 32 + (lane >> 4) * 8;
  ushort_t tmp[8];
  #pragma unroll
  for (int i = 0; i < 8; ++i) tmp[i] = f2bf(W[(size_t)(k0 + i) * N + n]);
  *(uint4*)&Ws[(size_t)slot * 8] = *(uint4*)tmp;
}

// ============ core GEMM: 64 rows x (4x16 cols/wave), K=256, N-split waves ============
__device__ __forceinline__ void gemm_k256(
    const ushort_t* __restrict__ A, const ushort_t* __restrict__ Ws,
    int rt0, int slot0, int NB, int lane, f32x4 c[4][4])
{
  #pragma unroll 2
  for (int kc = 0; kc < 8; ++kc) {
    short8 a[4];
    #pragma unroll
    for (int mf = 0; mf < 4; ++mf)
      a[mf] = *(const short8*)(A + (((size_t)(rt0 + mf) * 8 + kc) * 64 + lane) * 8);
    #pragma unroll
    for (int nb = 0; nb < 4; ++nb) {
      short8 b = *(const short8*)(Ws + (((size_t)kc * NB + slot0 + nb) * 64 + lane) * 8);
      #pragma unroll
      for (int mf = 0; mf < 4; ++mf)
        c[mf][nb] = __builtin_amdgcn_mfma_f32_16x16x32_bf16(a[mf], b, c[mf][nb], 0, 0, 0);
    }
  }
}

// ============ fused xq+LN1+Q-projection: -> Q row-major bf16 ============
// Phase 1: wave w computes LN1 rows of q = rt0+w (all 16 b) into LDS A-tile.
// Phase 2: MFMA GEMM from LDS.
__global__ __launch_bounds__(256, 4) void k_qnp(
    const int* __restrict__ tq, const float* __restrict__ spatial,
    const float* __restrict__ temporal, const float* __restrict__ g,
    const float* __restrict__ bt, const ushort_t* __restrict__ Ws,
    const float* __restrict__ Bi, ushort_t* __restrict__ Out)
{
  __shared__ ushort_t aT[64 * 256];    // frag-linear 64-row tile, 32 KB
  const int tid = threadIdx.x, lane = tid & 63, w = tid >> 6;
  const int rt0 = blockIdx.x * 4, row0 = blockIdx.x * 64;
  {
    int q = rt0 + w;                   // wave-uniform
    int s = q / cHW, hw = q % cHW;
    int c0 = lane * 4;
    float4 sv = *(const float4*)(spatial + (size_t)hw * cC + c0);
    float4 g4 = *(const float4*)(g + c0);
    float4 b4 = *(const float4*)(bt + c0);
    int kc = c0 >> 5, qq = (c0 >> 3) & 3, joff = c0 & 7;
    for (int rr = 0; rr < 16; ++rr) {
      int t = tq[s * cB + rr];
      float4 tv = *(const float4*)(temporal + (size_t)t * cC + c0);
      float v0 = tv.x + sv.x, v1 = tv.y + sv.y, v2 = tv.z + sv.z, v3 = tv.w + sv.w;
      float sum = v0 + v1 + v2 + v3;
      float sum2 = v0 * v0 + v1 * v1 + v2 * v2 + v3 * v3;
      #pragma unroll
      for (int off = 32; off >= 1; off >>= 1) {
        sum  += __shfl_xor(sum,  off, 64);
        sum2 += __shfl_xor(sum2, off, 64);
      }
      float mean = sum * (1.0f / cC);
      float var  = sum2 * (1.0f / cC) - mean * mean;
      float inv  = rsqrtf(var + 1e-5f);
      ushort_t o[4] = {f2bf((v0 - mean) * inv * g4.x + b4.x),
                       f2bf((v1 - mean) * inv * g4.y + b4.y),
                       f2bf((v2 - mean) * inv * g4.z + b4.z),
                       f2bf((v3 - mean) * inv * g4.w + b4.w)};
      *(uint2*)&aT[(((w * 8 + kc) * 64) + qq * 16 + rr) * 8 + joff] = *(uint2*)o;
    }
  }
  __syncthreads();
  f32x4 z = {0.f, 0.f, 0.f, 0.f};
  f32x4 c[4][4];
  #pragma unroll
  for (int mf = 0; mf < 4; ++mf)
    #pragma unroll
    for (int nb = 0; nb < 4; ++nb) c[mf][nb] = z;
  gemm_k256(aT, Ws, 0, w * 4, 16, lane, c);
  const int lane15 = lane & 15, kq = lane >> 4;
  #pragma unroll
  for (int nb = 0; nb < 4; ++nb) {
    int col = w * 64 + nb * 16 + lane15;
    float bias = Bi[col];
    #pragma unroll
    for (int mf = 0; mf < 4; ++mf)
      #pragma unroll
      for (int i = 0; i < 4; ++i) {
        int row = row0 + mf * 16 + kq * 4 + i;
        Out[(size_t)row * 256 + col] = f2bf(c[mf][nb][i] + bias);
      }
  }
}

// ============ K/V projections ============
__global__ __launch_bounds__(256, 4) void k_kv(
    const ushort_t* __restrict__ xkb, const ushort_t* __restrict__ wks,
    const ushort_t* __restrict__ wvs, const float* __restrict__ bk,
    const float* __restrict__ bv, ushort_t* __restrict__ Kb,
    ushort_t* __restrict__ Vb)
{
  const ushort_t* Ws = blockIdx.y ? wvs : wks;
  const float* Bi = blockIdx.y ? bv : bk;
  ushort_t* Out = blockIdx.y ? Vb : Kb;
  const int lane = threadIdx.x & 63, w = threadIdx.x >> 6;
  const int rt0 = blockIdx.x * 4, row0 = blockIdx.x * 64;
  f32x4 z = {0.f, 0.f, 0.f, 0.f};
  f32x4 c[4][4];
  #pragma unroll
  for (int mf = 0; mf < 4; ++mf)
    #pragma unroll
    for (int nb = 0; nb < 4; ++nb) c[mf][nb] = z;
  gemm_k256(xkb, Ws, rt0, w * 4, 16, lane, c);
  const int lane15 = lane & 15, kq = lane >> 4;
  #pragma unroll
  for (int nb = 0; nb < 4; ++nb) {
    int col = w * 64 + nb * 16 + lane15;
    float bias = Bi[col];
    #pragma unroll
    for (int mf = 0; mf < 4; ++mf)
      #pragma unroll
      for (int i = 0; i < 4; ++i) {
        int row = row0 + mf * 16 + kq * 4 + i;
        Out[(size_t)row * 256 + col] = f2bf(c[mf][nb][i] + bias);
      }
  }
}

// ============ fused wo projection + xq residual + LayerNorm2 ============
// Writes x (row-major bf16, for FFN residual + heads) AND xln (SWZ bf16).
__global__ __launch_bounds__(256, 4) void k_wo(
    const ushort_t* __restrict__ A, const ushort_t* __restrict__ Ws,
    const float* __restrict__ Bi, const int* __restrict__ tq,
    const float* __restrict__ spatial, const float* __restrict__ temporal,
    const float* __restrict__ g, const float* __restrict__ bt,
    ushort_t* __restrict__ Out, ushort_t* __restrict__ xln)
{
  __shared__ float red[4][64][2];      // [wave][row][sum,sumsq]
  const int lane = threadIdx.x & 63, w = threadIdx.x >> 6;
  const int rt0 = blockIdx.x * 4, row0 = blockIdx.x * 64;
  f32x4 z = {0.f, 0.f, 0.f, 0.f};
  f32x4 c[4][4];
  #pragma unroll
  for (int mf = 0; mf < 4; ++mf)
    #pragma unroll
    for (int nb = 0; nb < 4; ++nb) c[mf][nb] = z;
  gemm_k256(A, Ws, rt0, w * 4, 16, lane, c);
  const int lane15 = lane & 15, kq = lane >> 4;
  // rows: row = row0 + mf*16 + kq*4 + i ; b = kq*4+i ; q = rt0+mf (s, hw wave-uniform per mf)
  int tt[4][4], hws[4];
  #pragma unroll
  for (int mf = 0; mf < 4; ++mf) {
    int q = rt0 + mf;
    int s = q / cHW;
    hws[mf] = q % cHW;
    #pragma unroll
    for (int i = 0; i < 4; ++i) tt[mf][i] = tq[s * cB + kq * 4 + i];
  }
  // vals = c + bias + xq  (overwrite c)
  #pragma unroll
  for (int nb = 0; nb < 4; ++nb) {
    int col = w * 64 + nb * 16 + lane15;
    float bias = Bi[col];
    #pragma unroll
    for (int mf = 0; mf < 4; ++mf) {
      float sp = spatial[(size_t)hws[mf] * cC + col];
      #pragma unroll
      for (int i = 0; i < 4; ++i) {
        float xq = temporal[(size_t)tt[mf][i] * cC + col] + sp;
        c[mf][nb][i] += bias + xq;
      }
    }
  }
  // LN2 stats: per-row partial over the wave's 64 cols
  #pragma unroll
  for (int mf = 0; mf < 4; ++mf)
    #pragma unroll
    for (int i = 0; i < 4; ++i) {
      float s4 = c[mf][0][i] + c[mf][1][i] + c[mf][2][i] + c[mf][3][i];
      float q4 = c[mf][0][i] * c[mf][0][i] + c[mf][1][i] * c[mf][1][i] +
                 c[mf][2][i] * c[mf][2][i] + c[mf][3][i] * c[mf][3][i];
      #pragma unroll
      for (int off = 8; off >= 1; off >>= 1) {
        s4 += __shfl_xor(s4, off, 64);
        q4 += __shfl_xor(q4, off, 64);
      }
      if (lane15 == 0) {
        red[w][mf * 16 + kq * 4 + i][0] = s4;
        red[w][mf * 16 + kq * 4 + i][1] = q4;
      }
    }
  __syncthreads();
  float mean[4][4], inv[4][4];
  #pragma unroll
  for (int mf = 0; mf < 4; ++mf)
    #pragma unroll
    for (int i = 0; i < 4; ++i) {
      int rl = mf * 16 + kq * 4 + i;
      float S = red[0][rl][0] + red[1][rl][0] + red[2][rl][0] + red[3][rl][0];
      float Q = red[0][rl][1] + red[1][rl][1] + red[2][rl][1] + red[3][rl][1];
      float m = S * (1.0f / cC);
      float v = Q * (1.0f / cC) - m * m;
      mean[mf][i] = m;
      inv[mf][i] = rsqrtf(v + 1e-5f);
    }
  // stores: x row-major + xln SWZ
  #pragma unroll
  for (int nb = 0; nb < 4; ++nb) {
    int col = w * 64 + nb * 16 + lane15;
    float gc = g[col], bc = bt[col];
    #pragma unroll
    for (int mf = 0; mf < 4; ++mf)
      #pragma unroll
      for (int i = 0; i < 4; ++i) {
        int row = row0 + mf * 16 + kq * 4 + i;
        float val = c[mf][nb][i];
        Out[(size_t)row * 256 + col] = f2bf(val);
        float lv = (val - mean[mf][i]) * inv[mf][i] * gc + bc;
        xln[swz(row, col)] = f2bf(lv);
      }
  }
}

// ============ fused FFN: xln_swz @ w1 -> gelu -> @ w2 + resid(x) -> x2 in-place ====
// c1 split into two 2-colblock halves to fit <=128 VGPR (4 blocks/CU).
__global__ __launch_bounds__(256, 4) void k_ffn(
    const ushort_t* __restrict__ xln, const ushort_t* __restrict__ w1s,
    const float* __restrict__ b1, const ushort_t* __restrict__ w2s,
    const float* __restrict__ b2, ushort_t* __restrict__ xbuf)
{
  __shared__ ushort_t hL[8 * 4 * 64 * 8];    // 32 KB
  const int lane = threadIdx.x & 63, w = threadIdx.x >> 6;
  const int lane15 = lane & 15, kq = lane >> 4;
  const int rt0 = blockIdx.x * 4, row0 = blockIdx.x * 64;
  f32x4 z = {0.f, 0.f, 0.f, 0.f};
  f32x4 c2[4][4];
  #pragma unroll
  for (int mf = 0; mf < 4; ++mf)
    #pragma unroll
    for (int nb = 0; nb < 4; ++nb) c2[mf][nb] = z;

  for (int hc = 0; hc < 4; ++hc) {
    #pragma unroll
    for (int half = 0; half < 2; ++half) {
      f32x4 c1[4][2];
      #pragma unroll
      for (int mf = 0; mf < 4; ++mf)
        #pragma unroll
        for (int nb = 0; nb < 2; ++nb) c1[mf][nb] = z;
      #pragma unroll 2
      for (int kc = 0; kc < 8; ++kc) {
        short8 a[4];
        #pragma unroll
        for (int mf = 0; mf < 4; ++mf)
          a[mf] = *(const short8*)(xln + (((size_t)(rt0 + mf) * 8 + kc) * 64 + lane) * 8);
        #pragma unroll
        for (int nb = 0; nb < 2; ++nb) {
          int slot = hc * 16 + w * 4 + half * 2 + nb;
          short8 b = *(const short8*)(w1s + (((size_t)kc * 64 + slot) * 64 + lane) * 8);
          #pragma unroll
          for (int mf = 0; mf < 4; ++mf)
            c1[mf][nb] = __builtin_amdgcn_mfma_f32_16x16x32_bf16(a[mf], b, c1[mf][nb], 0, 0, 0);
        }
      }
      if (half == 0) __syncthreads();   // prior iteration's hL reads complete
      // GELU + scatter into hL frag layout
      #pragma unroll
      for (int nb = 0; nb < 2; ++nb) {
        int k2l = w * 64 + (half * 2 + nb) * 16 + lane15;
        float bias = b1[hc * 256 + k2l];
        int kc2l = k2l >> 5, kq2 = (k2l >> 3) & 3, j2 = k2l & 7;
        #pragma unroll
        for (int mf = 0; mf < 4; ++mf)
          #pragma unroll
          for (int i = 0; i < 4; ++i) {
            float xx = c1[mf][nb][i] + bias;
            float u = 0.7978845608028654f * (xx + 0.044715f * xx * xx * xx);
            u = fminf(fmaxf(u, -15.f), 15.f);
            float e = __expf(2.f * u);
            float t = (e - 1.f) / (e + 1.f);
            hL[(((kc2l * 4 + mf) * 64) + kq2 * 16 + kq * 4 + i) * 8 + j2] =
                f2bf(0.5f * xx * (1.f + t));
          }
      }
    }
    __syncthreads();
    // FFN2 accumulate: c2 += h(64x256) @ w2[hc*256.., w*64..+64)
    #pragma unroll 2
    for (int kc2 = 0; kc2 < 8; ++kc2) {
      short8 a2[4];
      #pragma unroll
      for (int mf = 0; mf < 4; ++mf)
        a2[mf] = *(const short8*)&hL[((kc2 * 4 + mf) * 64 + lane) * 8];
      #pragma unroll
      for (int nb = 0; nb < 4; ++nb) {
        short8 b = *(const short8*)(w2s +
            (((size_t)(hc * 8 + kc2) * 16 + w * 4 + nb) * 64 + lane) * 8);
        #pragma unroll
        for (int mf = 0; mf < 4; ++mf)
          c2[mf][nb] = __builtin_amdgcn_mfma_f32_16x16x32_bf16(a2[mf], b, c2[mf][nb], 0, 0, 0);
      }
    }
  }
  #pragma unroll
  for (int nb = 0; nb < 4; ++nb) {
    int col = w * 64 + nb * 16 + lane15;
    float bias = b2[col];
    #pragma unroll
    for (int mf = 0; mf < 4; ++mf)
      #pragma unroll
      for (int i = 0; i < 4; ++i) {
        size_t idx = (size_t)(row0 + mf * 16 + kq * 4 + i) * 256 + col;
        float val = c2[mf][nb][i] + bias + bf2f(xbuf[idx]);
        xbuf[idx] = f2bf(val);
      }
  }
}

// ============ MFMA attention: per (b,h), 16 q-tiles per block ============
__global__ __launch_bounds__(256) void k_attn(
    const ushort_t* __restrict__ Qb, const ushort_t* __restrict__ Kb,
    const ushort_t* __restrict__ Vb, const int* __restrict__ tq,
    const int* __restrict__ tk, const int* __restrict__ pad_q,
    const int* __restrict__ pad_k, ushort_t* __restrict__ aout)
{
  __shared__ ushort_t KL[128 * 72];     // [k][d]
  __shared__ ushort_t VtL[64 * 136];    // [d][k]
  __shared__ ushort_t pL[4][16 * 136];  // per-wave P tile
  __shared__ int tkL[128];

  const int h = blockIdx.y, b = blockIdx.z;
  const int tid = threadIdx.x, lane = tid & 63, w = tid >> 6;
  const int m15 = lane & 15, quad = lane >> 4;

  for (int i = tid; i < 128 * 16; i += 256) {
    int k = i >> 4, d4 = (i & 15) * 4;
    size_t src = (size_t)(k * cB + b) * 256 + h * 64 + d4;
    uint2 kv = *(const uint2*)&Kb[src];
    uint2 vv = *(const uint2*)&Vb[src];
    *(uint2*)&KL[k * 72 + d4] = kv;
    const ushort_t* vvp = (const ushort_t*)&vv;
    #pragma unroll
    for (int t = 0; t < 4; ++t) VtL[(d4 + t) * 136 + k] = vvp[t];
  }
  if (tid < 128) tkL[tid] = tk[tid * cB + b];
  __syncthreads();
  const int pk = pad_k[b];
  const int pq = pad_q[b] * cHW;
  ushort_t* pRow = pL[w];
  const f32x4 z = {0.f, 0.f, 0.f, 0.f};

  for (int pr = 0; pr < 4; ++pr) {
    int qt = blockIdx.x * 16 + pr * 4 + w;
    if (qt >= 293) break;                       // wave-uniform
    const ushort_t* qrow =
        Qb + ((size_t)((qt * 16 + m15) * cB + b)) * 256 + h * 64 + quad * 8;
    short8 qa0 = *(const short8*)(qrow);
    short8 qa1 = *(const short8*)(qrow + 32);
    f32x4 s[8];
    #pragma unroll
    for (int nf = 0; nf < 8; ++nf) {
      const ushort_t* kp = KL + (nf * 16 + m15) * 72 + quad * 8;
      short8 b0 = *(const short8*)(kp);
      short8 b1 = *(const short8*)(kp + 32);
      s[nf] = __builtin_amdgcn_mfma_f32_16x16x32_bf16(qa0, b0, z, 0, 0, 0);
      s[nf] = __builtin_amdgcn_mfma_f32_16x16x32_bf16(qa1, b1, s[nf], 0, 0, 0);
    }
    int tqv[4], qok[4];
    #pragma unroll
    for (int i = 0; i < 4; ++i) {
      int qg = qt * 16 + quad * 4 + i;
      int sidx = (qg * 3579) >> 20;            // exact q/293 for q<14768
      tqv[i] = tq[sidx * cB + b];
      qok[i] = (qg < pq);
    }
    #pragma unroll
    for (int nf = 0; nf < 8; ++nf) {
      int kidx = nf * 16 + m15;
      int tkc = tkL[kidx];
      bool kok = (kidx < pk);
      #pragma unroll
      for (int i = 0; i < 4; ++i) {
        bool ok = kok && qok[i] && (tkc <= tqv[i]);
        s[nf][i] = ok ? s[nf][i] * 0.125f : -1e9f;
      }
    }
    float mx[4], l[4];
    #pragma unroll
    for (int i = 0; i < 4; ++i) {
      float m = s[0][i];
      #pragma unroll
      for (int nf = 1; nf < 8; ++nf) m = fmaxf(m, s[nf][i]);
      #pragma unroll
      for (int off = 8; off >= 1; off >>= 1) m = fmaxf(m, __shfl_xor(m, off, 64));
      mx[i] = m;
    }
    #pragma unroll
    for (int i = 0; i < 4; ++i) l[i] = 0.f;
    #pragma unroll
    for (int nf = 0; nf < 8; ++nf)
      #pragma unroll
      for (int i = 0; i < 4; ++i) {
        float p = __expf(s[nf][i] - mx[i]);
        s[nf][i] = p;
        l[i] += p;
      }
    #pragma unroll
    for (int i = 0; i < 4; ++i) {
      float t = l[i];
      #pragma unroll
      for (int off = 8; off >= 1; off >>= 1) t += __shfl_xor(t, off, 64);
      l[i] = 1.0f / t;
    }
    #pragma unroll
    for (int nf = 0; nf < 8; ++nf)
      #pragma unroll
      for (int i = 0; i < 4; ++i)
        pRow[(quad * 4 + i) * 136 + nf * 16 + m15] = f2bf(s[nf][i]);
    f32x4 o[4];
    #pragma unroll
    for (int nf = 0; nf < 4; ++nf) o[nf] = z;
    #pragma unroll
    for (int kc = 0; kc < 4; ++kc) {
      short8 pa = *(const short8*)(pRow + m15 * 136 + kc * 32 + quad * 8);
      #pragma unroll
      for (int nf = 0; nf < 4; ++nf) {
        short8 vb = *(const short8*)(VtL + (nf * 16 + m15) * 136 + kc * 32 + quad * 8);
        o[nf] = __builtin_amdgcn_mfma_f32_16x16x32_bf16(pa, vb, o[nf], 0, 0, 0);
      }
    }
    #pragma unroll
    for (int nf = 0; nf < 4; ++nf) {
      int c = h * 64 + nf * 16 + m15;
      size_t base = ((size_t)(c >> 5)) * 64 + ((c >> 3) & 3) * 16 + b;
      int cj = c & 7;
      #pragma unroll
      for (int i = 0; i < 4; ++i) {
        int qg = qt * 16 + quad * 4 + i;
        aout[(((size_t)qg * 8) * 64 + base) * 8 + cj] = f2bf(o[nf][i] * l[i]);
      }
    }
  }
}

// ============ table/hand heads + upsample scatter ============
__global__ __launch_bounds__(256) void k_th(
    const ushort_t* __restrict__ x2, const float* __restrict__ tw,
    const float* __restrict__ tb, const float* __restrict__ hwgt,
    const float* __restrict__ hb, float* __restrict__ out)
{
  int x = blockIdx.x;                 // s*584 + hw*2 + half
  int s = x / 584;
  int rem = x % 584;
  int hw = rem >> 1, half = rem & 1;
  int j = threadIdx.x & 31, rr = threadIdx.x >> 5;
  int b = half * 8 + rr;
  const float* W;
  const float* Bi;
  if (hw < 256) { W = tw; Bi = tb; } else { W = hwgt; Bi = hb; }
  const ushort_t* row = x2 + ((size_t)(s * cHW + hw) * cB + b) * cC;
  float acc = Bi[j];
  for (int c = 0; c < cC; c += 4) {
    uint2 hv = *(const uint2*)(row + c);
    acc = fmaf(bf2f((ushort_t)(hv.x & 0xffff)), W[(c + 0) * 32 + j], acc);
    acc = fmaf(bf2f((ushort_t)(hv.x >> 16)),   W[(c + 1) * 32 + j], acc);
    acc = fmaf(bf2f((ushort_t)(hv.y & 0xffff)), W[(c + 2) * 32 + j], acc);
    acc = fmaf(bf2f((ushort_t)(hv.y >> 16)),   W[(c + 3) * 32 + j], acc);
  }
  int uh = j >> 3, uw = (j >> 1) & 3, uc = j & 1;
  size_t idx;
  if (hw < 256) {
    int th = hw >> 4, twi = hw & 15;
    idx = TX_OFF + ((((size_t)(s * cB + b)) * 2 + uc) * 64 + (th * 4 + uh)) * 64 + (twi * 4 + uw);
  } else {
    int h2 = hw - 256;
    int hh = h2 / 6, ww = h2 % 6;
    idx = HX_OFF + ((((size_t)(s * cB + b)) * 2 + uc) * 24 + (hh * 4 + uh)) * 24 + (ww * 4 + uw);
  }
  out[idx] = acc;
}

// ============ gx heads: mode / shape / color ============
__global__ __launch_bounds__(128) void k_gx(
    const ushort_t* __restrict__ x2,
    const float* __restrict__ mw, const float* __restrict__ mbi,
    const float* __restrict__ sw, const float* __restrict__ sbi,
    const float* __restrict__ cw, const float* __restrict__ cbi,
    float* __restrict__ out)
{
  int sb = blockIdx.x;              // s*16 + b
  int s = sb >> 4, b = sb & 15;
  __shared__ float rowL[256];
  const ushort_t* row = x2 + ((size_t)(s * cHW + 292) * cB + b) * cC;
  for (int i = threadIdx.x; i < 256; i += 128) rowL[i] = bf2f(row[i]);
  __syncthreads();
  int j = threadIdx.x;
  if (j < 100) {
    const float* W;
    const float* Bi;
    int jj, M;
    size_t off;
    if (j < 20)      { W = mw; Bi = mbi; jj = j;      M = 20; off = 0;     }
    else if (j < 84) { W = sw; Bi = sbi; jj = j - 20; M = 64; off = 5120;  }
    else             { W = cw; Bi = cbi; jj = j - 84; M = 16; off = 21504; }
    float acc = Bi[jj];
    for (int c = 0; c < 256; ++c) acc = fmaf(rowL[c], W[c * M + jj], acc);
    out[off + (size_t)sb * M + jj] = acc;
  }
}

extern "C" void kernel_launch(void* const* d_in, const int* in_sizes, int n_in,
                              void* d_out, int out_size, void* d_ws, size_t ws_size,
                              hipStream_t stream)
{
  const int*   tq       = (const int*)d_in[0];
  const int*   pad_q    = (const int*)d_in[1];
  const float* xk       = (const float*)d_in[2];
  const int*   tk       = (const int*)d_in[3];
  const int*   pad_k    = (const int*)d_in[4];
  const float* spatial  = (const float*)d_in[8];
  const float* temporal = (const float*)d_in[9];
  const float* ln1_g    = (const float*)d_in[10];
  const float* ln1_b    = (const float*)d_in[11];
  const float* wq       = (const float*)d_in[12];
  const float* bq       = (const float*)d_in[13];
  const float* wk       = (const float*)d_in[14];
  const float* bk       = (const float*)d_in[15];
  const float* wv       = (const float*)d_in[16];
  const float* bv       = (const float*)d_in[17];
  const float* wo       = (const float*)d_in[18];
  const float* bo       = (const float*)d_in[19];
  const float* ln2_g    = (const float*)d_in[20];
  const float* ln2_b    = (const float*)d_in[21];
  const float* w1       = (const float*)d_in[22];
  const float* b1       = (const float*)d_in[23];
  const float* w2       = (const float*)d_in[24];
  const float* b2       = (const float*)d_in[25];
  const float* table_w  = (const float*)d_in[26];
  const float* table_b  = (const float*)d_in[27];
  const float* hand_w   = (const float*)d_in[28];
  const float* hand_b   = (const float*)d_in[29];
  const float* mode_w   = (const float*)d_in[30];
  const float* mode_b   = (const float*)d_in[31];
  const float* shape_w  = (const float*)d_in[32];
  const float* shape_b  = (const float*)d_in[33];
  const float* color_w  = (const float*)d_in[34];
  const float* color_b  = (const float*)d_in[35];
  float* out = (float*)d_out;

  // Workspace layout (~82 MB)
  char* ws = (char*)d_ws;
  const size_t NB2 = (size_t)cNN * cC * sizeof(ushort_t);      // 38,404,096
  ushort_t* buf1 = (ushort_t*)ws;                              // a_swz -> xln_swz
  ushort_t* buf2 = (ushort_t*)(ws + NB2);                      // Q -> x -> x2 (in-place)
  char* p = ws + 2 * NB2;
  ushort_t* Kb  = (ushort_t*)p;  p += (size_t)cLK * cB * 256 * 2;
  ushort_t* Vb  = (ushort_t*)p;  p += (size_t)cLK * cB * 256 * 2;
  ushort_t* xkb = (ushort_t*)p;  p += (size_t)cLK * cB * 256 * 2;
  ushort_t* wqs = (ushort_t*)p;  p += 256 * 256 * 2;
  ushort_t* wks = (ushort_t*)p;  p += 256 * 256 * 2;
  ushort_t* wvs = (ushort_t*)p;  p += 256 * 256 * 2;
  ushort_t* wos = (ushort_t*)p;  p += 256 * 256 * 2;
  ushort_t* w1s = (ushort_t*)p;  p += 256 * 1024 * 2;
  ushort_t* w2s = (ushort_t*)p;  p += 1024 * 256 * 2;

  k_prep<<<896, 256, 0, stream>>>(xk, xkb, wq, wqs, wk, wks, wv, wvs,
                                  wo, wos, w1, w1s, w2, w2s);
  k_kv<<<dim3(32, 2), 256, 0, stream>>>(xkb, wks, wvs, bk, bv, Kb, Vb);
  k_qnp<<<cNN / 64, 256, 0, stream>>>(tq, spatial, temporal, ln1_g, ln1_b,
                                      wqs, bq, buf2);
  k_attn<<<dim3(19, cH, cB), 256, 0, stream>>>(buf2, Kb, Vb, tq, tk,
                                               pad_q, pad_k, buf1);
  k_wo<<<cNN / 64, 256, 0, stream>>>(buf1, wos, bo, tq, spatial, temporal,
                                     ln2_g, ln2_b, buf2, buf1);
  k_ffn<<<cNN / 64, 256, 0, stream>>>(buf1, w1s, b1, w2s, b2, buf2);
  k_th<<<cS * 292 * 2, 256, 0, stream>>>(buf2, table_w, table_b, hand_w, hand_b, out);
  k_gx<<<cS * cB, 128, 0, stream>>>(buf2, mode_w, mode_b, shape_w, shape_b,
                                    color_w, color_b, out);
}

// Round 7
// 624.754 us; speedup vs baseline: 4.3441x; 1.0758x over previous
//
#include <hip/hip_runtime.h>
#include <hip/hip_bf16.h>

namespace {
constexpr int cS = 16, cB = 16, cC = 256, cH = 4, cDH = 64, cHW = 293;
constexpr int cLQ = cS * cHW;      // 4688
constexpr int cLK = 128;
constexpr int cNN = cLQ * cB;      // 75008
constexpr size_t TX_OFF = 25600;         // 5120 + 16384 + 4096
constexpr size_t HX_OFF = 2122752;       // TX_OFF + 16*16*2*64*64
}

typedef unsigned short ushort_t;
typedef unsigned int uint_t;
typedef __attribute__((ext_vector_type(8))) short short8;    // 8 bf16 (4 VGPRs)
typedef __attribute__((ext_vector_type(4))) float f32x4;     // MFMA C/D frag

__device__ __forceinline__ float bf2f(ushort_t u) {
  return __uint_as_float(((uint_t)u) << 16);
}
__device__ __forceinline__ ushort_t f2bf(float f) {
  __hip_bfloat16 h = __float2bfloat16(f);
  return *(ushort_t*)&h;
}

// SWZ frag-linear activation layout for a [rows][256] matrix:
// element (r, c) -> ((r>>4)*8 + (c>>5))*512 + ((c>>3)&3)*128 + (r&15)*8 + (c&7)
__device__ __forceinline__ size_t swz(int r, int c) {
  return (((size_t)(r >> 4) * 8 + (c >> 5)) * 64 + ((c >> 3) & 3) * 16 + (r & 15)) * 8 + (c & 7);
}

// ============ merged prep: xk cvt+swz, 6 weight swizzles ============
__global__ __launch_bounds__(256) void k_prep(
    const float* __restrict__ xk, ushort_t* __restrict__ xkb,
    const float* __restrict__ wq, ushort_t* __restrict__ wqs,
    const float* __restrict__ wk, ushort_t* __restrict__ wks,
    const float* __restrict__ wv, ushort_t* __restrict__ wvs,
    const float* __restrict__ wo, ushort_t* __restrict__ wos,
    const float* __restrict__ w1, ushort_t* __restrict__ w1s,
    const float* __restrict__ w2, ushort_t* __restrict__ w2s)
{
  int bid = blockIdx.x;
  if (bid < 512) {
    int i4 = bid * 256 + threadIdx.x;
    int r = i4 >> 6;
    int c0 = (i4 & 63) * 4;
    float4 v = *(const float4*)(xk + (size_t)r * 256 + c0);
    ushort_t o[4] = {f2bf(v.x), f2bf(v.y), f2bf(v.z), f2bf(v.w)};
    *(uint2*)&xkb[swz(r, c0)] = *(uint2*)o;
    return;
  }
  int rr = bid - 512;
  const float* W; ushort_t* Ws; int N; int lb;
  if      (rr < 32)  { W = wq; Ws = wqs; N = 256;  lb = rr; }
  else if (rr < 64)  { W = wk; Ws = wks; N = 256;  lb = rr - 32; }
  else if (rr < 96)  { W = wv; Ws = wvs; N = 256;  lb = rr - 64; }
  else if (rr < 128) { W = wo; Ws = wos; N = 256;  lb = rr - 96; }
  else if (rr < 256) { W = w1; Ws = w1s; N = 1024; lb = rr - 128; }
  else               { W = w2; Ws = w2s; N = 256;  lb = rr - 256; }
  int slot = lb * 256 + threadIdx.x;
  int lane = slot & 63;
  int fr   = slot >> 6;
  int NB   = N >> 4;
  int nb   = fr % NB, kc = fr / NB;
  int n    = nb * 16 + (lane & 15);
  int k0   = kc * 32 + (lane >> 4) * 8;
  ushort_t tmp[8];
  #pragma unroll
  for (int i = 0; i < 8; ++i) tmp[i] = f2bf(W[(size_t)(k0 + i) * N + n]);
  *(uint4*)&Ws[(size_t)slot * 8] = *(uint4*)tmp;
}

// ============ core GEMM: 64 rows x (4x16 cols/wave), K=256, N-split waves ============
__device__ __forceinline__ void gemm_k256(
    const ushort_t* __restrict__ A, const ushort_t* __restrict__ Ws,
    int rt0, int slot0, int NB, int lane, f32x4 c[4][4])
{
  #pragma unroll 2
  for (int kc = 0; kc < 8; ++kc) {
    short8 a[4];
    #pragma unroll
    for (int mf = 0; mf < 4; ++mf)
      a[mf] = *(const short8*)(A + (((size_t)(rt0 + mf) * 8 + kc) * 64 + lane) * 8);
    #pragma unroll
    for (int nb = 0; nb < 4; ++nb) {
      short8 b = *(const short8*)(Ws + (((size_t)kc * NB + slot0 + nb) * 64 + lane) * 8);
      #pragma unroll
      for (int mf = 0; mf < 4; ++mf)
        c[mf][nb] = __builtin_amdgcn_mfma_f32_16x16x32_bf16(a[mf], b, c[mf][nb], 0, 0, 0);
    }
  }
}

// ============ fused xq+LN1+Q-projection -> Q row-major bf16 (coalesced epi) ======
__global__ __launch_bounds__(256, 4) void k_qnp(
    const int* __restrict__ tq, const float* __restrict__ spatial,
    const float* __restrict__ temporal, const float* __restrict__ g,
    const float* __restrict__ bt, const ushort_t* __restrict__ Ws,
    const float* __restrict__ Bi, ushort_t* __restrict__ Out)
{
  __shared__ ushort_t aT[64 * 256];    // A frags, then reused as epilogue tile
  const int tid = threadIdx.x, lane = tid & 63, w = tid >> 6;
  const int rt0 = blockIdx.x * 4, row0 = blockIdx.x * 64;
  {
    int q = rt0 + w;                   // wave-uniform
    int s = q / cHW, hw = q % cHW;
    int c0 = lane * 4;
    float4 sv = *(const float4*)(spatial + (size_t)hw * cC + c0);
    float4 g4 = *(const float4*)(g + c0);
    float4 b4 = *(const float4*)(bt + c0);
    int kc = c0 >> 5, qq = (c0 >> 3) & 3, joff = c0 & 7;
    for (int rr = 0; rr < 16; ++rr) {
      int t = tq[s * cB + rr];
      float4 tv = *(const float4*)(temporal + (size_t)t * cC + c0);
      float v0 = tv.x + sv.x, v1 = tv.y + sv.y, v2 = tv.z + sv.z, v3 = tv.w + sv.w;
      float sum = v0 + v1 + v2 + v3;
      float sum2 = v0 * v0 + v1 * v1 + v2 * v2 + v3 * v3;
      #pragma unroll
      for (int off = 32; off >= 1; off >>= 1) {
        sum  += __shfl_xor(sum,  off, 64);
        sum2 += __shfl_xor(sum2, off, 64);
      }
      float mean = sum * (1.0f / cC);
      float var  = sum2 * (1.0f / cC) - mean * mean;
      float inv  = rsqrtf(var + 1e-5f);
      ushort_t o[4] = {f2bf((v0 - mean) * inv * g4.x + b4.x),
                       f2bf((v1 - mean) * inv * g4.y + b4.y),
                       f2bf((v2 - mean) * inv * g4.z + b4.z),
                       f2bf((v3 - mean) * inv * g4.w + b4.w)};
      *(uint2*)&aT[(((w * 8 + kc) * 64) + qq * 16 + rr) * 8 + joff] = *(uint2*)o;
    }
  }
  __syncthreads();
  f32x4 z = {0.f, 0.f, 0.f, 0.f};
  f32x4 c[4][4];
  #pragma unroll
  for (int mf = 0; mf < 4; ++mf)
    #pragma unroll
    for (int nb = 0; nb < 4; ++nb) c[mf][nb] = z;
  gemm_k256(aT, Ws, 0, w * 4, 16, lane, c);
  const int lane15 = lane & 15, kq = lane >> 4;
  __syncthreads();                     // all aT frag reads complete
  #pragma unroll
  for (int nb = 0; nb < 4; ++nb) {
    int col = w * 64 + nb * 16 + lane15;
    float bias = Bi[col];
    #pragma unroll
    for (int mf = 0; mf < 4; ++mf)
      #pragma unroll
      for (int i = 0; i < 4; ++i)
        aT[(mf * 16 + kq * 4 + i) * 256 + col] = f2bf(c[mf][nb][i] + bias);
  }
  __syncthreads();
  uint2* outp = (uint2*)(Out + (size_t)row0 * 256);
  #pragma unroll
  for (int it = 0; it < 16; ++it) {
    int f = tid + it * 256;
    int row = f >> 6, c0 = (f & 63) * 4;
    outp[f] = *(uint2*)&aT[row * 256 + c0];
  }
}

// ============ K/V projections ============
__global__ __launch_bounds__(256, 4) void k_kv(
    const ushort_t* __restrict__ xkb, const ushort_t* __restrict__ wks,
    const ushort_t* __restrict__ wvs, const float* __restrict__ bk,
    const float* __restrict__ bv, ushort_t* __restrict__ Kb,
    ushort_t* __restrict__ Vb)
{
  const ushort_t* Ws = blockIdx.y ? wvs : wks;
  const float* Bi = blockIdx.y ? bv : bk;
  ushort_t* Out = blockIdx.y ? Vb : Kb;
  const int lane = threadIdx.x & 63, w = threadIdx.x >> 6;
  const int rt0 = blockIdx.x * 4, row0 = blockIdx.x * 64;
  f32x4 z = {0.f, 0.f, 0.f, 0.f};
  f32x4 c[4][4];
  #pragma unroll
  for (int mf = 0; mf < 4; ++mf)
    #pragma unroll
    for (int nb = 0; nb < 4; ++nb) c[mf][nb] = z;
  gemm_k256(xkb, Ws, rt0, w * 4, 16, lane, c);
  const int lane15 = lane & 15, kq = lane >> 4;
  #pragma unroll
  for (int nb = 0; nb < 4; ++nb) {
    int col = w * 64 + nb * 16 + lane15;
    float bias = Bi[col];
    #pragma unroll
    for (int mf = 0; mf < 4; ++mf)
      #pragma unroll
      for (int i = 0; i < 4; ++i) {
        int row = row0 + mf * 16 + kq * 4 + i;
        Out[(size_t)row * 256 + col] = f2bf(c[mf][nb][i] + bias);
      }
  }
}

// ============ fused wo proj + xq residual + LN2, coalesced epilogue ============
// Outputs: x row-major bf16 (Out) and xln SWZ bf16.
__global__ __launch_bounds__(256, 4) void k_wo(
    const ushort_t* __restrict__ A, const ushort_t* __restrict__ Ws,
    const float* __restrict__ Bi, const int* __restrict__ tq,
    const float* __restrict__ spatial, const float* __restrict__ temporal,
    const float* __restrict__ g, const float* __restrict__ bt,
    ushort_t* __restrict__ Out, ushort_t* __restrict__ xln)
{
  __shared__ ushort_t xT[64 * 256];    // 32 KB epilogue tile
  __shared__ float red[4][64][2];      // [wave][row][sum,sumsq]
  __shared__ float meanL[64], invL[64];
  const int tid = threadIdx.x, lane = tid & 63, w = tid >> 6;
  const int rt0 = blockIdx.x * 4, row0 = blockIdx.x * 64;
  f32x4 z = {0.f, 0.f, 0.f, 0.f};
  f32x4 c[4][4];
  #pragma unroll
  for (int mf = 0; mf < 4; ++mf)
    #pragma unroll
    for (int nb = 0; nb < 4; ++nb) c[mf][nb] = z;
  gemm_k256(A, Ws, rt0, w * 4, 16, lane, c);
  const int lane15 = lane & 15, kq = lane >> 4;
  int tt[4][4], hws[4];
  #pragma unroll
  for (int mf = 0; mf < 4; ++mf) {
    int q = rt0 + mf;
    int s = q / cHW;
    hws[mf] = q % cHW;
    #pragma unroll
    for (int i = 0; i < 4; ++i) tt[mf][i] = tq[s * cB + kq * 4 + i];
  }
  #pragma unroll
  for (int nb = 0; nb < 4; ++nb) {
    int col = w * 64 + nb * 16 + lane15;
    float bias = Bi[col];
    #pragma unroll
    for (int mf = 0; mf < 4; ++mf) {
      float sp = spatial[(size_t)hws[mf] * cC + col];
      #pragma unroll
      for (int i = 0; i < 4; ++i) {
        float xq = temporal[(size_t)tt[mf][i] * cC + col] + sp;
        c[mf][nb][i] += bias + xq;
      }
    }
  }
  #pragma unroll
  for (int mf = 0; mf < 4; ++mf)
    #pragma unroll
    for (int i = 0; i < 4; ++i) {
      float s4 = c[mf][0][i] + c[mf][1][i] + c[mf][2][i] + c[mf][3][i];
      float q4 = c[mf][0][i] * c[mf][0][i] + c[mf][1][i] * c[mf][1][i] +
                 c[mf][2][i] * c[mf][2][i] + c[mf][3][i] * c[mf][3][i];
      #pragma unroll
      for (int off = 8; off >= 1; off >>= 1) {
        s4 += __shfl_xor(s4, off, 64);
        q4 += __shfl_xor(q4, off, 64);
      }
      if (lane15 == 0) {
        red[w][mf * 16 + kq * 4 + i][0] = s4;
        red[w][mf * 16 + kq * 4 + i][1] = q4;
      }
    }
  __syncthreads();
  #pragma unroll
  for (int mf = 0; mf < 4; ++mf)
    #pragma unroll
    for (int i = 0; i < 4; ++i) {
      int rl = mf * 16 + kq * 4 + i;
      float S = red[0][rl][0] + red[1][rl][0] + red[2][rl][0] + red[3][rl][0];
      float Q = red[0][rl][1] + red[1][rl][1] + red[2][rl][1] + red[3][rl][1];
      float m = S * (1.0f / cC);
      float v = Q * (1.0f / cC) - m * m;
      if (w == 0 && lane15 == 0) {
        meanL[rl] = m;
        invL[rl] = rsqrtf(v + 1e-5f);
      }
    }
  // store x-vals into tile
  #pragma unroll
  for (int nb = 0; nb < 4; ++nb) {
    int col = w * 64 + nb * 16 + lane15;
    #pragma unroll
    for (int mf = 0; mf < 4; ++mf)
      #pragma unroll
      for (int i = 0; i < 4; ++i)
        xT[(mf * 16 + kq * 4 + i) * 256 + col] = f2bf(c[mf][nb][i]);
  }
  __syncthreads();
  uint2* outp = (uint2*)(Out + (size_t)row0 * 256);
  #pragma unroll
  for (int it = 0; it < 16; ++it) {
    int f = tid + it * 256;
    int row = f >> 6, c0 = (f & 63) * 4;
    uint2 v = *(uint2*)&xT[row * 256 + c0];
    outp[f] = v;
    float m = meanL[row], iv = invL[row];
    float4 g4 = *(const float4*)(g + c0);
    float4 b4 = *(const float4*)(bt + c0);
    const ushort_t* vp = (const ushort_t*)&v;
    ushort_t o[4] = {f2bf((bf2f(vp[0]) - m) * iv * g4.x + b4.x),
                     f2bf((bf2f(vp[1]) - m) * iv * g4.y + b4.y),
                     f2bf((bf2f(vp[2]) - m) * iv * g4.z + b4.z),
                     f2bf((bf2f(vp[3]) - m) * iv * g4.w + b4.w)};
    *(uint2*)&xln[swz(row0 + row, c0)] = *(uint2*)o;
  }
}

// ============ fused FFN: A in LDS, h in LDS, coalesced epilogue ============
// LDS: aT 32 KB + hL 32 KB = 64 KB -> 2 blocks/CU.
__global__ __launch_bounds__(256, 2) void k_ffn(
    const ushort_t* __restrict__ xln, const ushort_t* __restrict__ w1s,
    const float* __restrict__ b1, const ushort_t* __restrict__ w2s,
    const float* __restrict__ b2, ushort_t* __restrict__ xbuf)
{
  __shared__ ushort_t aT[64 * 256];    // A frags (staged once), later epi tile
  __shared__ ushort_t hL[64 * 256];    // h frag tile
  const int tid = threadIdx.x, lane = tid & 63, w = tid >> 6;
  const int lane15 = lane & 15, kq = lane >> 4;
  const int row0 = blockIdx.x * 64;
  // ---- stage A tile (contiguous 32 KB, coalesced)
  {
    const uint4* src = (const uint4*)(xln + (size_t)row0 * 256);
    uint4* dst = (uint4*)aT;
    #pragma unroll
    for (int it = 0; it < 8; ++it)
      dst[tid + it * 256] = src[tid + it * 256];
  }
  __syncthreads();
  f32x4 z = {0.f, 0.f, 0.f, 0.f};
  f32x4 c2[4][4];
  #pragma unroll
  for (int mf = 0; mf < 4; ++mf)
    #pragma unroll
    for (int nb = 0; nb < 4; ++nb) c2[mf][nb] = z;

  for (int hc = 0; hc < 4; ++hc) {
    #pragma unroll
    for (int half = 0; half < 2; ++half) {
      f32x4 c1[4][2];
      #pragma unroll
      for (int mf = 0; mf < 4; ++mf)
        #pragma unroll
        for (int nb = 0; nb < 2; ++nb) c1[mf][nb] = z;
      #pragma unroll 2
      for (int kc = 0; kc < 8; ++kc) {
        short8 a[4];
        #pragma unroll
        for (int mf = 0; mf < 4; ++mf)
          a[mf] = *(const short8*)&aT[((mf * 8 + kc) * 64 + lane) * 8];
        #pragma unroll
        for (int nb = 0; nb < 2; ++nb) {
          int slot = hc * 16 + w * 4 + half * 2 + nb;
          short8 b = *(const short8*)(w1s + (((size_t)kc * 64 + slot) * 64 + lane) * 8);
          #pragma unroll
          for (int mf = 0; mf < 4; ++mf)
            c1[mf][nb] = __builtin_amdgcn_mfma_f32_16x16x32_bf16(a[mf], b, c1[mf][nb], 0, 0, 0);
        }
      }
      if (half == 0) __syncthreads();   // prior iteration's hL reads complete
      // GELU + scatter into hL frag layout
      #pragma unroll
      for (int nb = 0; nb < 2; ++nb) {
        int k2l = w * 64 + (half * 2 + nb) * 16 + lane15;
        float bias = b1[hc * 256 + k2l];
        int kc2l = k2l >> 5, kq2 = (k2l >> 3) & 3, j2 = k2l & 7;
        #pragma unroll
        for (int mf = 0; mf < 4; ++mf)
          #pragma unroll
          for (int i = 0; i < 4; ++i) {
            float xx = c1[mf][nb][i] + bias;
            float u = 0.7978845608028654f * (xx + 0.044715f * xx * xx * xx);
            u = fminf(fmaxf(u, -15.f), 15.f);
            float e = __expf(2.f * u);
            float t = (e - 1.f) / (e + 1.f);
            hL[(((kc2l * 4 + mf) * 64) + kq2 * 16 + kq * 4 + i) * 8 + j2] =
                f2bf(0.5f * xx * (1.f + t));
          }
      }
    }
    __syncthreads();
    // FFN2 accumulate
    #pragma unroll 2
    for (int kc2 = 0; kc2 < 8; ++kc2) {
      short8 a2[4];
      #pragma unroll
      for (int mf = 0; mf < 4; ++mf)
        a2[mf] = *(const short8*)&hL[((kc2 * 4 + mf) * 64 + lane) * 8];
      #pragma unroll
      for (int nb = 0; nb < 4; ++nb) {
        short8 b = *(const short8*)(w2s +
            (((size_t)(hc * 8 + kc2) * 16 + w * 4 + nb) * 64 + lane) * 8);
        #pragma unroll
        for (int mf = 0; mf < 4; ++mf)
          c2[mf][nb] = __builtin_amdgcn_mfma_f32_16x16x32_bf16(a2[mf], b, c2[mf][nb], 0, 0, 0);
      }
    }
  }
  __syncthreads();                     // all aT/hL frag reads complete
  // epilogue: c2+bias -> aT row-major tile
  #pragma unroll
  for (int nb = 0; nb < 4; ++nb) {
    int col = w * 64 + nb * 16 + lane15;
    float bias = b2[col];
    #pragma unroll
    for (int mf = 0; mf < 4; ++mf)
      #pragma unroll
      for (int i = 0; i < 4; ++i)
        aT[(mf * 16 + kq * 4 + i) * 256 + col] = f2bf(c2[mf][nb][i] + bias);
  }
  __syncthreads();
  // coalesced copy-out with residual add (in-place on xbuf)
  uint2* xp = (uint2*)(xbuf + (size_t)row0 * 256);
  #pragma unroll
  for (int it = 0; it < 16; ++it) {
    int f = tid + it * 256;
    int row = f >> 6, c0 = (f & 63) * 4;
    uint2 hv = *(uint2*)&aT[row * 256 + c0];
    uint2 rv = xp[f];
    const ushort_t* hp = (const ushort_t*)&hv;
    const ushort_t* rp = (const ushort_t*)&rv;
    ushort_t o[4];
    #pragma unroll
    for (int j = 0; j < 4; ++j) o[j] = f2bf(bf2f(hp[j]) + bf2f(rp[j]));
    xp[f] = *(uint2*)o;
  }
}

// ============ MFMA attention: per (b,h), 16 q-tiles per block ============
__global__ __launch_bounds__(256) void k_attn(
    const ushort_t* __restrict__ Qb, const ushort_t* __restrict__ Kb,
    const ushort_t* __restrict__ Vb, const int* __restrict__ tq,
    const int* __restrict__ tk, const int* __restrict__ pad_q,
    const int* __restrict__ pad_k, ushort_t* __restrict__ aout)
{
  __shared__ ushort_t KL[128 * 72];     // [k][d]
  __shared__ ushort_t VtL[64 * 136];    // [d][k]
  __shared__ ushort_t pL[4][16 * 136];  // per-wave P tile
  __shared__ int tkL[128];

  const int h = blockIdx.y, b = blockIdx.z;
  const int tid = threadIdx.x, lane = tid & 63, w = tid >> 6;
  const int m15 = lane & 15, quad = lane >> 4;

  for (int i = tid; i < 128 * 16; i += 256) {
    int k = i >> 4, d4 = (i & 15) * 4;
    size_t src = (size_t)(k * cB + b) * 256 + h * 64 + d4;
    uint2 kv = *(const uint2*)&Kb[src];
    uint2 vv = *(const uint2*)&Vb[src];
    *(uint2*)&KL[k * 72 + d4] = kv;
    const ushort_t* vvp = (const ushort_t*)&vv;
    #pragma unroll
    for (int t = 0; t < 4; ++t) VtL[(d4 + t) * 136 + k] = vvp[t];
  }
  if (tid < 128) tkL[tid] = tk[tid * cB + b];
  __syncthreads();
  const int pk = pad_k[b];
  const int pq = pad_q[b] * cHW;
  ushort_t* pRow = pL[w];
  const f32x4 z = {0.f, 0.f, 0.f, 0.f};

  for (int pr = 0; pr < 4; ++pr) {
    int qt = blockIdx.x * 16 + pr * 4 + w;
    if (qt >= 293) break;                       // wave-uniform
    const ushort_t* qrow =
        Qb + ((size_t)((qt * 16 + m15) * cB + b)) * 256 + h * 64 + quad * 8;
    short8 qa0 = *(const short8*)(qrow);
    short8 qa1 = *(const short8*)(qrow + 32);
    f32x4 s[8];
    #pragma unroll
    for (int nf = 0; nf < 8; ++nf) {
      const ushort_t* kp = KL + (nf * 16 + m15) * 72 + quad * 8;
      short8 b0 = *(const short8*)(kp);
      short8 b1 = *(const short8*)(kp + 32);
      s[nf] = __builtin_amdgcn_mfma_f32_16x16x32_bf16(qa0, b0, z, 0, 0, 0);
      s[nf] = __builtin_amdgcn_mfma_f32_16x16x32_bf16(qa1, b1, s[nf], 0, 0, 0);
    }
    int tqv[4], qok[4];
    #pragma unroll
    for (int i = 0; i < 4; ++i) {
      int qg = qt * 16 + quad * 4 + i;
      int sidx = (qg * 3579) >> 20;            // exact q/293 for q<14768
      tqv[i] = tq[sidx * cB + b];
      qok[i] = (qg < pq);
    }
    #pragma unroll
    for (int nf = 0; nf < 8; ++nf) {
      int kidx = nf * 16 + m15;
      int tkc = tkL[kidx];
      bool kok = (kidx < pk);
      #pragma unroll
      for (int i = 0; i < 4; ++i) {
        bool ok = kok && qok[i] && (tkc <= tqv[i]);
        s[nf][i] = ok ? s[nf][i] * 0.125f : -1e9f;
      }
    }
    float mx[4], l[4];
    #pragma unroll
    for (int i = 0; i < 4; ++i) {
      float m = s[0][i];
      #pragma unroll
      for (int nf = 1; nf < 8; ++nf) m = fmaxf(m, s[nf][i]);
      #pragma unroll
      for (int off = 8; off >= 1; off >>= 1) m = fmaxf(m, __shfl_xor(m, off, 64));
      mx[i] = m;
    }
    #pragma unroll
    for (int i = 0; i < 4; ++i) l[i] = 0.f;
    #pragma unroll
    for (int nf = 0; nf < 8; ++nf)
      #pragma unroll
      for (int i = 0; i < 4; ++i) {
        float p = __expf(s[nf][i] - mx[i]);
        s[nf][i] = p;
        l[i] += p;
      }
    #pragma unroll
    for (int i = 0; i < 4; ++i) {
      float t = l[i];
      #pragma unroll
      for (int off = 8; off >= 1; off >>= 1) t += __shfl_xor(t, off, 64);
      l[i] = 1.0f / t;
    }
    #pragma unroll
    for (int nf = 0; nf < 8; ++nf)
      #pragma unroll
      for (int i = 0; i < 4; ++i)
        pRow[(quad * 4 + i) * 136 + nf * 16 + m15] = f2bf(s[nf][i]);
    f32x4 o[4];
    #pragma unroll
    for (int nf = 0; nf < 4; ++nf) o[nf] = z;
    #pragma unroll
    for (int kc = 0; kc < 4; ++kc) {
      short8 pa = *(const short8*)(pRow + m15 * 136 + kc * 32 + quad * 8);
      #pragma unroll
      for (int nf = 0; nf < 4; ++nf) {
        short8 vb = *(const short8*)(VtL + (nf * 16 + m15) * 136 + kc * 32 + quad * 8);
        o[nf] = __builtin_amdgcn_mfma_f32_16x16x32_bf16(pa, vb, o[nf], 0, 0, 0);
      }
    }
    #pragma unroll
    for (int nf = 0; nf < 4; ++nf) {
      int c = h * 64 + nf * 16 + m15;
      size_t base = ((size_t)(c >> 5)) * 64 + ((c >> 3) & 3) * 16 + b;
      int cj = c & 7;
      #pragma unroll
      for (int i = 0; i < 4; ++i) {
        int qg = qt * 16 + quad * 4 + i;
        aout[(((size_t)qg * 8) * 64 + base) * 8 + cj] = f2bf(o[nf][i] * l[i]);
      }
    }
  }
}

// ============ table/hand heads + upsample scatter ============
__global__ __launch_bounds__(256) void k_th(
    const ushort_t* __restrict__ x2, const float* __restrict__ tw,
    const float* __restrict__ tb, const float* __restrict__ hwgt,
    const float* __restrict__ hb, float* __restrict__ out)
{
  int x = blockIdx.x;                 // s*584 + hw*2 + half
  int s = x / 584;
  int rem = x % 584;
  int hw = rem >> 1, half = rem & 1;
  int j = threadIdx.x & 31, rr = threadIdx.x >> 5;
  int b = half * 8 + rr;
  const float* W;
  const float* Bi;
  if (hw < 256) { W = tw; Bi = tb; } else { W = hwgt; Bi = hb; }
  const ushort_t* row = x2 + ((size_t)(s * cHW + hw) * cB + b) * cC;
  float acc = Bi[j];
  for (int c = 0; c < cC; c += 4) {
    uint2 hv = *(const uint2*)(row + c);
    acc = fmaf(bf2f((ushort_t)(hv.x & 0xffff)), W[(c + 0) * 32 + j], acc);
    acc = fmaf(bf2f((ushort_t)(hv.x >> 16)),   W[(c + 1) * 32 + j], acc);
    acc = fmaf(bf2f((ushort_t)(hv.y & 0xffff)), W[(c + 2) * 32 + j], acc);
    acc = fmaf(bf2f((ushort_t)(hv.y >> 16)),   W[(c + 3) * 32 + j], acc);
  }
  int uh = j >> 3, uw = (j >> 1) & 3, uc = j & 1;
  size_t idx;
  if (hw < 256) {
    int th = hw >> 4, twi = hw & 15;
    idx = TX_OFF + ((((size_t)(s * cB + b)) * 2 + uc) * 64 + (th * 4 + uh)) * 64 + (twi * 4 + uw);
  } else {
    int h2 = hw - 256;
    int hh = h2 / 6, ww = h2 % 6;
    idx = HX_OFF + ((((size_t)(s * cB + b)) * 2 + uc) * 24 + (hh * 4 + uh)) * 24 + (ww * 4 + uw);
  }
  out[idx] = acc;
}

// ============ gx heads: mode / shape / color ============
__global__ __launch_bounds__(128) void k_gx(
    const ushort_t* __restrict__ x2,
    const float* __restrict__ mw, const float* __restrict__ mbi,
    const float* __restrict__ sw, const float* __restrict__ sbi,
    const float* __restrict__ cw, const float* __restrict__ cbi,
    float* __restrict__ out)
{
  int sb = blockIdx.x;              // s*16 + b
  int s = sb >> 4, b = sb & 15;
  __shared__ float rowL[256];
  const ushort_t* row = x2 + ((size_t)(s * cHW + 292) * cB + b) * cC;
  for (int i = threadIdx.x; i < 256; i += 128) rowL[i] = bf2f(row[i]);
  __syncthreads();
  int j = threadIdx.x;
  if (j < 100) {
    const float* W;
    const float* Bi;
    int jj, M;
    size_t off;
    if (j < 20)      { W = mw; Bi = mbi; jj = j;      M = 20; off = 0;     }
    else if (j < 84) { W = sw; Bi = sbi; jj = j - 20; M = 64; off = 5120;  }
    else             { W = cw; Bi = cbi; jj = j - 84; M = 16; off = 21504; }
    float acc = Bi[jj];
    for (int c = 0; c < 256; ++c) acc = fmaf(rowL[c], W[c * M + jj], acc);
    out[off + (size_t)sb * M + jj] = acc;
  }
}

extern "C" void kernel_launch(void* const* d_in, const int* in_sizes, int n_in,
                              void* d_out, int out_size, void* d_ws, size_t ws_size,
                              hipStream_t stream)
{
  const int*   tq       = (const int*)d_in[0];
  const int*   pad_q    = (const int*)d_in[1];
  const float* xk       = (const float*)d_in[2];
  const int*   tk       = (const int*)d_in[3];
  const int*   pad_k    = (const int*)d_in[4];
  const float* spatial  = (const float*)d_in[8];
  const float* temporal = (const float*)d_in[9];
  const float* ln1_g    = (const float*)d_in[10];
  const float* ln1_b    = (const float*)d_in[11];
  const float* wq       = (const float*)d_in[12];
  const float* bq       = (const float*)d_in[13];
  const float* wk       = (const float*)d_in[14];
  const float* bk       = (const float*)d_in[15];
  const float* wv       = (const float*)d_in[16];
  const float* bv       = (const float*)d_in[17];
  const float* wo       = (const float*)d_in[18];
  const float* bo       = (const float*)d_in[19];
  const float* ln2_g    = (const float*)d_in[20];
  const float* ln2_b    = (const float*)d_in[21];
  const float* w1       = (const float*)d_in[22];
  const float* b1       = (const float*)d_in[23];
  const float* w2       = (const float*)d_in[24];
  const float* b2       = (const float*)d_in[25];
  const float* table_w  = (const float*)d_in[26];
  const float* table_b  = (const float*)d_in[27];
  const float* hand_w   = (const float*)d_in[28];
  const float* hand_b   = (const float*)d_in[29];
  const float* mode_w   = (const float*)d_in[30];
  const float* mode_b   = (const float*)d_in[31];
  const float* shape_w  = (const float*)d_in[32];
  const float* shape_b  = (const float*)d_in[33];
  const float* color_w  = (const float*)d_in[34];
  const float* color_b  = (const float*)d_in[35];
  float* out = (float*)d_out;

  char* ws = (char*)d_ws;
  const size_t NB2 = (size_t)cNN * cC * sizeof(ushort_t);      // 38,404,096
  ushort_t* buf1 = (ushort_t*)ws;                              // a_swz -> xln_swz
  ushort_t* buf2 = (ushort_t*)(ws + NB2);                      // Q -> x -> x2 (in-place)
  char* p = ws + 2 * NB2;
  ushort_t* Kb  = (ushort_t*)p;  p += (size_t)cLK * cB * 256 * 2;
  ushort_t* Vb  = (ushort_t*)p;  p += (size_t)cLK * cB * 256 * 2;
  ushort_t* xkb = (ushort_t*)p;  p += (size_t)cLK * cB * 256 * 2;
  ushort_t* wqs = (ushort_t*)p;  p += 256 * 256 * 2;
  ushort_t* wks = (ushort_t*)p;  p += 256 * 256 * 2;
  ushort_t* wvs = (ushort_t*)p;  p += 256 * 256 * 2;
  ushort_t* wos = (ushort_t*)p;  p += 256 * 256 * 2;
  ushort_t* w1s = (ushort_t*)p;  p += 256 * 1024 * 2;
  ushort_t* w2s = (ushort_t*)p;  p += 1024 * 256 * 2;

  k_prep<<<896, 256, 0, stream>>>(xk, xkb, wq, wqs, wk, wks, wv, wvs,
                                  wo, wos, w1, w1s, w2, w2s);
  k_kv<<<dim3(32, 2), 256, 0, stream>>>(xkb, wks, wvs, bk, bv, Kb, Vb);
  k_qnp<<<cNN / 64, 256, 0, stream>>>(tq, spatial, temporal, ln1_g, ln1_b,
                                      wqs, bq, buf2);
  k_attn<<<dim3(19, cH, cB), 256, 0, stream>>>(buf2, Kb, Vb, tq, tk,
                                               pad_q, pad_k, buf1);
  k_wo<<<cNN / 64, 256, 0, stream>>>(buf1, wos, bo, tq, spatial, temporal,
                                     ln2_g, ln2_b, buf2, buf1);
  k_ffn<<<cNN / 64, 256, 0, stream>>>(buf1, w1s, b1, w2s, b2, buf2);
  k_th<<<cS * 292 * 2, 256, 0, stream>>>(buf2, table_w, table_b, hand_w, hand_b, out);
  k_gx<<<cS * cB, 128, 0, stream>>>(buf2, mode_w, mode_b, shape_w, shape_b,
                                    color_w, color_b, out);
}

// Round 8
// 558.021 us; speedup vs baseline: 4.8636x; 1.1196x over previous
//
#include <hip/hip_runtime.h>
#include <hip/hip_bf16.h>

namespace {
constexpr int cS = 16, cB = 16, cC = 256, cH = 4, cDH = 64, cHW = 293;
constexpr int cLQ = cS * cHW;      // 4688
constexpr int cLK = 128;
constexpr int cNN = cLQ * cB;      // 75008
constexpr size_t TX_OFF = 25600;         // 5120 + 16384 + 4096
constexpr size_t HX_OFF = 2122752;       // TX_OFF + 16*16*2*64*64
}

typedef unsigned short ushort_t;
typedef unsigned int uint_t;
typedef __attribute__((ext_vector_type(8))) short short8;    // 8 bf16 (4 VGPRs)
typedef __attribute__((ext_vector_type(4))) float f32x4;     // MFMA C/D frag

__device__ __forceinline__ float bf2f(ushort_t u) {
  return __uint_as_float(((uint_t)u) << 16);
}
__device__ __forceinline__ ushort_t f2bf(float f) {
  __hip_bfloat16 h = __float2bfloat16(f);
  return *(ushort_t*)&h;
}

// SWZ frag-linear activation layout for a [rows][256] matrix:
// element (r, c) -> ((r>>4)*8 + (c>>5))*512 + ((c>>3)&3)*128 + (r&15)*8 + (c&7)
__device__ __forceinline__ size_t swz(int r, int c) {
  return (((size_t)(r >> 4) * 8 + (c >> 5)) * 64 + ((c >> 3) & 3) * 16 + (r & 15)) * 8 + (c & 7);
}

// ============ merged prep: xk cvt+swz, 6 weight swizzles ============
__global__ __launch_bounds__(256) void k_prep(
    const float* __restrict__ xk, ushort_t* __restrict__ xkb,
    const float* __restrict__ wq, ushort_t* __restrict__ wqs,
    const float* __restrict__ wk, ushort_t* __restrict__ wks,
    const float* __restrict__ wv, ushort_t* __restrict__ wvs,
    const float* __restrict__ wo, ushort_t* __restrict__ wos,
    const float* __restrict__ w1, ushort_t* __restrict__ w1s,
    const float* __restrict__ w2, ushort_t* __restrict__ w2s)
{
  int bid = blockIdx.x;
  if (bid < 512) {
    int i4 = bid * 256 + threadIdx.x;
    int r = i4 >> 6;
    int c0 = (i4 & 63) * 4;
    float4 v = *(const float4*)(xk + (size_t)r * 256 + c0);
    ushort_t o[4] = {f2bf(v.x), f2bf(v.y), f2bf(v.z), f2bf(v.w)};
    *(uint2*)&xkb[swz(r, c0)] = *(uint2*)o;
    return;
  }
  int rr = bid - 512;
  const float* W; ushort_t* Ws; int N; int lb;
  if      (rr < 32)  { W = wq; Ws = wqs; N = 256;  lb = rr; }
  else if (rr < 64)  { W = wk; Ws = wks; N = 256;  lb = rr - 32; }
  else if (rr < 96)  { W = wv; Ws = wvs; N = 256;  lb = rr - 64; }
  else if (rr < 128) { W = wo; Ws = wos; N = 256;  lb = rr - 96; }
  else if (rr < 256) { W = w1; Ws = w1s; N = 1024; lb = rr - 128; }
  else               { W = w2; Ws = w2s; N = 256;  lb = rr - 256; }
  int slot = lb * 256 + threadIdx.x;
  int lane = slot & 63;
  int fr   = slot >> 6;
  int NB   = N >> 4;
  int nb   = fr % NB, kc = fr / NB;
  int n    = nb * 16 + (lane & 15);
  int k0   = kc * 32 + (lane >> 4) * 8;
  ushort_t tmp[8];
  #pragma unroll
  for (int i = 0; i < 8; ++i) tmp[i] = f2bf(W[(size_t)(k0 + i) * N + n]);
  *(uint4*)&Ws[(size_t)slot * 8] = *(uint4*)tmp;
}

// ============ core GEMM: 64 rows x (4x16 cols/wave), K=256, N-split waves ============
__device__ __forceinline__ void gemm_k256(
    const ushort_t* __restrict__ A, const ushort_t* __restrict__ Ws,
    int rt0, int slot0, int NB, int lane, f32x4 c[4][4])
{
  #pragma unroll 2
  for (int kc = 0; kc < 8; ++kc) {
    short8 a[4];
    #pragma unroll
    for (int mf = 0; mf < 4; ++mf)
      a[mf] = *(const short8*)(A + (((size_t)(rt0 + mf) * 8 + kc) * 64 + lane) * 8);
    #pragma unroll
    for (int nb = 0; nb < 4; ++nb) {
      short8 b = *(const short8*)(Ws + (((size_t)kc * NB + slot0 + nb) * 64 + lane) * 8);
      #pragma unroll
      for (int mf = 0; mf < 4; ++mf)
        c[mf][nb] = __builtin_amdgcn_mfma_f32_16x16x32_bf16(a[mf], b, c[mf][nb], 0, 0, 0);
    }
  }
}

// ============ fused xq+LN1+Q-projection -> Q row-major bf16 (coalesced epi) ======
__global__ __launch_bounds__(256, 4) void k_qnp(
    const int* __restrict__ tq, const float* __restrict__ spatial,
    const float* __restrict__ temporal, const float* __restrict__ g,
    const float* __restrict__ bt, const ushort_t* __restrict__ Ws,
    const float* __restrict__ Bi, ushort_t* __restrict__ Out)
{
  __shared__ ushort_t aT[64 * 256];    // A frags, then reused as epilogue tile
  const int tid = threadIdx.x, lane = tid & 63, w = tid >> 6;
  const int rt0 = blockIdx.x * 4, row0 = blockIdx.x * 64;
  {
    int q = rt0 + w;                   // wave-uniform
    int s = q / cHW, hw = q % cHW;
    int c0 = lane * 4;
    float4 sv = *(const float4*)(spatial + (size_t)hw * cC + c0);
    float4 g4 = *(const float4*)(g + c0);
    float4 b4 = *(const float4*)(bt + c0);
    int kc = c0 >> 5, qq = (c0 >> 3) & 3, joff = c0 & 7;
    for (int rr = 0; rr < 16; ++rr) {
      int t = tq[s * cB + rr];
      float4 tv = *(const float4*)(temporal + (size_t)t * cC + c0);
      float v0 = tv.x + sv.x, v1 = tv.y + sv.y, v2 = tv.z + sv.z, v3 = tv.w + sv.w;
      float sum = v0 + v1 + v2 + v3;
      float sum2 = v0 * v0 + v1 * v1 + v2 * v2 + v3 * v3;
      #pragma unroll
      for (int off = 32; off >= 1; off >>= 1) {
        sum  += __shfl_xor(sum,  off, 64);
        sum2 += __shfl_xor(sum2, off, 64);
      }
      float mean = sum * (1.0f / cC);
      float var  = sum2 * (1.0f / cC) - mean * mean;
      float inv  = rsqrtf(var + 1e-5f);
      ushort_t o[4] = {f2bf((v0 - mean) * inv * g4.x + b4.x),
                       f2bf((v1 - mean) * inv * g4.y + b4.y),
                       f2bf((v2 - mean) * inv * g4.z + b4.z),
                       f2bf((v3 - mean) * inv * g4.w + b4.w)};
      *(uint2*)&aT[(((w * 8 + kc) * 64) + qq * 16 + rr) * 8 + joff] = *(uint2*)o;
    }
  }
  __syncthreads();
  f32x4 z = {0.f, 0.f, 0.f, 0.f};
  f32x4 c[4][4];
  #pragma unroll
  for (int mf = 0; mf < 4; ++mf)
    #pragma unroll
    for (int nb = 0; nb < 4; ++nb) c[mf][nb] = z;
  gemm_k256(aT, Ws, 0, w * 4, 16, lane, c);
  const int lane15 = lane & 15, kq = lane >> 4;
  __syncthreads();                     // all aT frag reads complete
  #pragma unroll
  for (int nb = 0; nb < 4; ++nb) {
    int col = w * 64 + nb * 16 + lane15;
    float bias = Bi[col];
    #pragma unroll
    for (int mf = 0; mf < 4; ++mf)
      #pragma unroll
      for (int i = 0; i < 4; ++i)
        aT[(mf * 16 + kq * 4 + i) * 256 + col] = f2bf(c[mf][nb][i] + bias);
  }
  __syncthreads();
  uint2* outp = (uint2*)(Out + (size_t)row0 * 256);
  #pragma unroll
  for (int it = 0; it < 16; ++it) {
    int f = tid + it * 256;
    int row = f >> 6, c0 = (f & 63) * 4;
    outp[f] = *(uint2*)&aT[row * 256 + c0];
  }
}

// ============ K/V projections ============
__global__ __launch_bounds__(256, 4) void k_kv(
    const ushort_t* __restrict__ xkb, const ushort_t* __restrict__ wks,
    const ushort_t* __restrict__ wvs, const float* __restrict__ bk,
    const float* __restrict__ bv, ushort_t* __restrict__ Kb,
    ushort_t* __restrict__ Vb)
{
  const ushort_t* Ws = blockIdx.y ? wvs : wks;
  const float* Bi = blockIdx.y ? bv : bk;
  ushort_t* Out = blockIdx.y ? Vb : Kb;
  const int lane = threadIdx.x & 63, w = threadIdx.x >> 6;
  const int rt0 = blockIdx.x * 4, row0 = blockIdx.x * 64;
  f32x4 z = {0.f, 0.f, 0.f, 0.f};
  f32x4 c[4][4];
  #pragma unroll
  for (int mf = 0; mf < 4; ++mf)
    #pragma unroll
    for (int nb = 0; nb < 4; ++nb) c[mf][nb] = z;
  gemm_k256(xkb, Ws, rt0, w * 4, 16, lane, c);
  const int lane15 = lane & 15, kq = lane >> 4;
  #pragma unroll
  for (int nb = 0; nb < 4; ++nb) {
    int col = w * 64 + nb * 16 + lane15;
    float bias = Bi[col];
    #pragma unroll
    for (int mf = 0; mf < 4; ++mf)
      #pragma unroll
      for (int i = 0; i < 4; ++i) {
        int row = row0 + mf * 16 + kq * 4 + i;
        Out[(size_t)row * 256 + col] = f2bf(c[mf][nb][i] + bias);
      }
  }
}

// ============ fused wo proj + xq residual + LN2, coalesced epilogue ============
__global__ __launch_bounds__(256, 4) void k_wo(
    const ushort_t* __restrict__ A, const ushort_t* __restrict__ Ws,
    const float* __restrict__ Bi, const int* __restrict__ tq,
    const float* __restrict__ spatial, const float* __restrict__ temporal,
    const float* __restrict__ g, const float* __restrict__ bt,
    ushort_t* __restrict__ Out, ushort_t* __restrict__ xln)
{
  __shared__ ushort_t xT[64 * 256];    // 32 KB epilogue tile
  __shared__ float red[4][64][2];      // [wave][row][sum,sumsq]
  __shared__ float meanL[64], invL[64];
  const int tid = threadIdx.x, lane = tid & 63, w = tid >> 6;
  const int rt0 = blockIdx.x * 4, row0 = blockIdx.x * 64;
  f32x4 z = {0.f, 0.f, 0.f, 0.f};
  f32x4 c[4][4];
  #pragma unroll
  for (int mf = 0; mf < 4; ++mf)
    #pragma unroll
    for (int nb = 0; nb < 4; ++nb) c[mf][nb] = z;
  gemm_k256(A, Ws, rt0, w * 4, 16, lane, c);
  const int lane15 = lane & 15, kq = lane >> 4;
  int tt[4][4], hws[4];
  #pragma unroll
  for (int mf = 0; mf < 4; ++mf) {
    int q = rt0 + mf;
    int s = q / cHW;
    hws[mf] = q % cHW;
    #pragma unroll
    for (int i = 0; i < 4; ++i) tt[mf][i] = tq[s * cB + kq * 4 + i];
  }
  #pragma unroll
  for (int nb = 0; nb < 4; ++nb) {
    int col = w * 64 + nb * 16 + lane15;
    float bias = Bi[col];
    #pragma unroll
    for (int mf = 0; mf < 4; ++mf) {
      float sp = spatial[(size_t)hws[mf] * cC + col];
      #pragma unroll
      for (int i = 0; i < 4; ++i) {
        float xq = temporal[(size_t)tt[mf][i] * cC + col] + sp;
        c[mf][nb][i] += bias + xq;
      }
    }
  }
  #pragma unroll
  for (int mf = 0; mf < 4; ++mf)
    #pragma unroll
    for (int i = 0; i < 4; ++i) {
      float s4 = c[mf][0][i] + c[mf][1][i] + c[mf][2][i] + c[mf][3][i];
      float q4 = c[mf][0][i] * c[mf][0][i] + c[mf][1][i] * c[mf][1][i] +
                 c[mf][2][i] * c[mf][2][i] + c[mf][3][i] * c[mf][3][i];
      #pragma unroll
      for (int off = 8; off >= 1; off >>= 1) {
        s4 += __shfl_xor(s4, off, 64);
        q4 += __shfl_xor(q4, off, 64);
      }
      if (lane15 == 0) {
        red[w][mf * 16 + kq * 4 + i][0] = s4;
        red[w][mf * 16 + kq * 4 + i][1] = q4;
      }
    }
  __syncthreads();
  #pragma unroll
  for (int mf = 0; mf < 4; ++mf)
    #pragma unroll
    for (int i = 0; i < 4; ++i) {
      int rl = mf * 16 + kq * 4 + i;
      float S = red[0][rl][0] + red[1][rl][0] + red[2][rl][0] + red[3][rl][0];
      float Q = red[0][rl][1] + red[1][rl][1] + red[2][rl][1] + red[3][rl][1];
      float m = S * (1.0f / cC);
      float v = Q * (1.0f / cC) - m * m;
      if (w == 0 && lane15 == 0) {
        meanL[rl] = m;
        invL[rl] = rsqrtf(v + 1e-5f);
      }
    }
  #pragma unroll
  for (int nb = 0; nb < 4; ++nb) {
    int col = w * 64 + nb * 16 + lane15;
    #pragma unroll
    for (int mf = 0; mf < 4; ++mf)
      #pragma unroll
      for (int i = 0; i < 4; ++i)
        xT[(mf * 16 + kq * 4 + i) * 256 + col] = f2bf(c[mf][nb][i]);
  }
  __syncthreads();
  uint2* outp = (uint2*)(Out + (size_t)row0 * 256);
  #pragma unroll
  for (int it = 0; it < 16; ++it) {
    int f = tid + it * 256;
    int row = f >> 6, c0 = (f & 63) * 4;
    uint2 v = *(uint2*)&xT[row * 256 + c0];
    outp[f] = v;
    float m = meanL[row], iv = invL[row];
    float4 g4 = *(const float4*)(g + c0);
    float4 b4 = *(const float4*)(bt + c0);
    const ushort_t* vp = (const ushort_t*)&v;
    ushort_t o[4] = {f2bf((bf2f(vp[0]) - m) * iv * g4.x + b4.x),
                     f2bf((bf2f(vp[1]) - m) * iv * g4.y + b4.y),
                     f2bf((bf2f(vp[2]) - m) * iv * g4.z + b4.z),
                     f2bf((bf2f(vp[3]) - m) * iv * g4.w + b4.w)};
    *(uint2*)&xln[swz(row0 + row, c0)] = *(uint2*)o;
  }
}

// ============ fused FFN: 512 threads, 8-way col-split waves ============
// LDS: aT 32 KB + hL 32 KB = 64 KB -> 2 blocks/CU = 16 waves/CU (4/SIMD).
__global__ __launch_bounds__(512, 4) void k_ffn(
    const ushort_t* __restrict__ xln, const ushort_t* __restrict__ w1s,
    const float* __restrict__ b1, const ushort_t* __restrict__ w2s,
    const float* __restrict__ b2, ushort_t* __restrict__ xbuf)
{
  __shared__ ushort_t aT[64 * 256];    // A frags (staged once), later epi tile
  __shared__ ushort_t hL[64 * 256];    // h frag tile
  const int tid = threadIdx.x, lane = tid & 63, w = tid >> 6;   // w in [0,8)
  const int lane15 = lane & 15, kq = lane >> 4;
  const int row0 = blockIdx.x * 64;
  // ---- stage A tile (contiguous 32 KB, coalesced)
  {
    const uint4* src = (const uint4*)(xln + (size_t)row0 * 256);
    uint4* dst = (uint4*)aT;
    #pragma unroll
    for (int it = 0; it < 4; ++it)
      dst[tid + it * 512] = src[tid + it * 512];
  }
  __syncthreads();
  f32x4 z = {0.f, 0.f, 0.f, 0.f};
  f32x4 c2[4][2];                      // wave owns 32 out cols
  #pragma unroll
  for (int mf = 0; mf < 4; ++mf)
    #pragma unroll
    for (int nb = 0; nb < 2; ++nb) c2[mf][nb] = z;

  for (int hc = 0; hc < 4; ++hc) {
    // ---- FFN1: wave computes h-slots (hc*16 + w*2, +1): 32 h-cols
    f32x4 c1[4][2];
    #pragma unroll
    for (int mf = 0; mf < 4; ++mf)
      #pragma unroll
      for (int nb = 0; nb < 2; ++nb) c1[mf][nb] = z;
    #pragma unroll 2
    for (int kc = 0; kc < 8; ++kc) {
      short8 a[4];
      #pragma unroll
      for (int mf = 0; mf < 4; ++mf)
        a[mf] = *(const short8*)&aT[((mf * 8 + kc) * 64 + lane) * 8];
      #pragma unroll
      for (int nb = 0; nb < 2; ++nb) {
        int slot = hc * 16 + w * 2 + nb;
        short8 b = *(const short8*)(w1s + (((size_t)kc * 64 + slot) * 64 + lane) * 8);
        #pragma unroll
        for (int mf = 0; mf < 4; ++mf)
          c1[mf][nb] = __builtin_amdgcn_mfma_f32_16x16x32_bf16(a[mf], b, c1[mf][nb], 0, 0, 0);
      }
    }
    __syncthreads();                   // prior FFN2's hL reads complete
    // ---- GELU + scatter into hL frag layout
    #pragma unroll
    for (int nb = 0; nb < 2; ++nb) {
      int k2l = w * 32 + nb * 16 + lane15;     // h-col within 256-chunk
      float bias = b1[hc * 256 + k2l];
      int kc2l = k2l >> 5, kq2 = (k2l >> 3) & 3, j2 = k2l & 7;
      #pragma unroll
      for (int mf = 0; mf < 4; ++mf)
        #pragma unroll
        for (int i = 0; i < 4; ++i) {
          float xx = c1[mf][nb][i] + bias;
          float u = 0.7978845608028654f * (xx + 0.044715f * xx * xx * xx);
          u = fminf(fmaxf(u, -15.f), 15.f);
          float e = __expf(2.f * u);
          float t = (e - 1.f) / (e + 1.f);
          hL[(((kc2l * 4 + mf) * 64) + kq2 * 16 + kq * 4 + i) * 8 + j2] =
              f2bf(0.5f * xx * (1.f + t));
        }
    }
    __syncthreads();
    // ---- FFN2 accumulate: c2 += h(64x256) @ w2[hc*256.., w*32..+32)
    #pragma unroll 2
    for (int kc2 = 0; kc2 < 8; ++kc2) {
      short8 a2[4];
      #pragma unroll
      for (int mf = 0; mf < 4; ++mf)
        a2[mf] = *(const short8*)&hL[((kc2 * 4 + mf) * 64 + lane) * 8];
      #pragma unroll
      for (int nb = 0; nb < 2; ++nb) {
        short8 b = *(const short8*)(w2s +
            (((size_t)(hc * 8 + kc2) * 16 + w * 2 + nb) * 64 + lane) * 8);
        #pragma unroll
        for (int mf = 0; mf < 4; ++mf)
          c2[mf][nb] = __builtin_amdgcn_mfma_f32_16x16x32_bf16(a2[mf], b, c2[mf][nb], 0, 0, 0);
      }
    }
  }
  __syncthreads();                     // all aT/hL frag reads complete
  // epilogue: c2+bias -> aT row-major tile
  #pragma unroll
  for (int nb = 0; nb < 2; ++nb) {
    int col = w * 32 + nb * 16 + lane15;
    float bias = b2[col];
    #pragma unroll
    for (int mf = 0; mf < 4; ++mf)
      #pragma unroll
      for (int i = 0; i < 4; ++i)
        aT[(mf * 16 + kq * 4 + i) * 256 + col] = f2bf(c2[mf][nb][i] + bias);
  }
  __syncthreads();
  // coalesced copy-out with residual add (in-place on xbuf)
  uint2* xp = (uint2*)(xbuf + (size_t)row0 * 256);
  #pragma unroll
  for (int it = 0; it < 8; ++it) {
    int f = tid + it * 512;
    int row = f >> 6, c0 = (f & 63) * 4;
    uint2 hv = *(uint2*)&aT[row * 256 + c0];
    uint2 rv = xp[f];
    const ushort_t* hp = (const ushort_t*)&hv;
    const ushort_t* rp = (const ushort_t*)&rv;
    ushort_t o[4];
    #pragma unroll
    for (int j = 0; j < 4; ++j) o[j] = f2bf(bf2f(hp[j]) + bf2f(rp[j]));
    xp[f] = *(uint2*)o;
  }
}

// ============ MFMA attention: 512 threads, per (b,h), 32 q-tiles per block ============
// LDS: KL 18432 + VtL 17408 + pL 8x4352 + tk 512 = 71168 B -> 2 blocks/CU.
__global__ __launch_bounds__(512, 4) void k_attn(
    const ushort_t* __restrict__ Qb, const ushort_t* __restrict__ Kb,
    const ushort_t* __restrict__ Vb, const int* __restrict__ tq,
    const int* __restrict__ tk, const int* __restrict__ pad_q,
    const int* __restrict__ pad_k, ushort_t* __restrict__ aout)
{
  __shared__ ushort_t KL[128 * 72];     // [k][d]
  __shared__ ushort_t VtL[64 * 136];    // [d][k]
  __shared__ ushort_t pL[8][16 * 136];  // per-wave P tile
  __shared__ int tkL[128];

  const int h = blockIdx.y, b = blockIdx.z;
  const int tid = threadIdx.x, lane = tid & 63, w = tid >> 6;   // w in [0,8)
  const int m15 = lane & 15, quad = lane >> 4;

  for (int i = tid; i < 128 * 16; i += 512) {
    int k = i >> 4, d4 = (i & 15) * 4;
    size_t src = (size_t)(k * cB + b) * 256 + h * 64 + d4;
    uint2 kv = *(const uint2*)&Kb[src];
    uint2 vv = *(const uint2*)&Vb[src];
    *(uint2*)&KL[k * 72 + d4] = kv;
    const ushort_t* vvp = (const ushort_t*)&vv;
    #pragma unroll
    for (int t = 0; t < 4; ++t) VtL[(d4 + t) * 136 + k] = vvp[t];
  }
  if (tid < 128) tkL[tid] = tk[tid * cB + b];
  __syncthreads();
  const int pk = pad_k[b];
  const int pq = pad_q[b] * cHW;
  ushort_t* pRow = pL[w];
  const f32x4 z = {0.f, 0.f, 0.f, 0.f};

  for (int pr = 0; pr < 4; ++pr) {
    int qt = blockIdx.x * 32 + pr * 8 + w;
    if (qt >= 293) break;                       // wave-uniform
    const ushort_t* qrow =
        Qb + ((size_t)((qt * 16 + m15) * cB + b)) * 256 + h * 64 + quad * 8;
    short8 qa0 = *(const short8*)(qrow);
    short8 qa1 = *(const short8*)(qrow + 32);
    f32x4 s[8];
    #pragma unroll
    for (int nf = 0; nf < 8; ++nf) {
      const ushort_t* kp = KL + (nf * 16 + m15) * 72 + quad * 8;
      short8 b0 = *(const short8*)(kp);
      short8 b1 = *(const short8*)(kp + 32);
      s[nf] = __builtin_amdgcn_mfma_f32_16x16x32_bf16(qa0, b0, z, 0, 0, 0);
      s[nf] = __builtin_amdgcn_mfma_f32_16x16x32_bf16(qa1, b1, s[nf], 0, 0, 0);
    }
    int tqv[4], qok[4];
    #pragma unroll
    for (int i = 0; i < 4; ++i) {
      int qg = qt * 16 + quad * 4 + i;
      int sidx = (qg * 3579) >> 20;            // exact q/293 for q<14768
      tqv[i] = tq[sidx * cB + b];
      qok[i] = (qg < pq);
    }
    #pragma unroll
    for (int nf = 0; nf < 8; ++nf) {
      int kidx = nf * 16 + m15;
      int tkc = tkL[kidx];
      bool kok = (kidx < pk);
      #pragma unroll
      for (int i = 0; i < 4; ++i) {
        bool ok = kok && qok[i] && (tkc <= tqv[i]);
        s[nf][i] = ok ? s[nf][i] * 0.125f : -1e9f;
      }
    }
    float mx[4], l[4];
    #pragma unroll
    for (int i = 0; i < 4; ++i) {
      float m = s[0][i];
      #pragma unroll
      for (int nf = 1; nf < 8; ++nf) m = fmaxf(m, s[nf][i]);
      #pragma unroll
      for (int off = 8; off >= 1; off >>= 1) m = fmaxf(m, __shfl_xor(m, off, 64));
      mx[i] = m;
    }
    #pragma unroll
    for (int i = 0; i < 4; ++i) l[i] = 0.f;
    #pragma unroll
    for (int nf = 0; nf < 8; ++nf)
      #pragma unroll
      for (int i = 0; i < 4; ++i) {
        float p = __expf(s[nf][i] - mx[i]);
        s[nf][i] = p;
        l[i] += p;
      }
    #pragma unroll
    for (int i = 0; i < 4; ++i) {
      float t = l[i];
      #pragma unroll
      for (int off = 8; off >= 1; off >>= 1) t += __shfl_xor(t, off, 64);
      l[i] = 1.0f / t;
    }
    #pragma unroll
    for (int nf = 0; nf < 8; ++nf)
      #pragma unroll
      for (int i = 0; i < 4; ++i)
        pRow[(quad * 4 + i) * 136 + nf * 16 + m15] = f2bf(s[nf][i]);
    f32x4 o[4];
    #pragma unroll
    for (int nf = 0; nf < 4; ++nf) o[nf] = z;
    #pragma unroll
    for (int kc = 0; kc < 4; ++kc) {
      short8 pa = *(const short8*)(pRow + m15 * 136 + kc * 32 + quad * 8);
      #pragma unroll
      for (int nf = 0; nf < 4; ++nf) {
        short8 vb = *(const short8*)(VtL + (nf * 16 + m15) * 136 + kc * 32 + quad * 8);
        o[nf] = __builtin_amdgcn_mfma_f32_16x16x32_bf16(pa, vb, o[nf], 0, 0, 0);
      }
    }
    #pragma unroll
    for (int nf = 0; nf < 4; ++nf) {
      int c = h * 64 + nf * 16 + m15;
      size_t base = ((size_t)(c >> 5)) * 64 + ((c >> 3) & 3) * 16 + b;
      int cj = c & 7;
      #pragma unroll
      for (int i = 0; i < 4; ++i) {
        int qg = qt * 16 + quad * 4 + i;
        aout[(((size_t)qg * 8) * 64 + base) * 8 + cj] = f2bf(o[nf][i] * l[i]);
      }
    }
  }
}

// ============ table/hand heads + upsample scatter ============
__global__ __launch_bounds__(256) void k_th(
    const ushort_t* __restrict__ x2, const float* __restrict__ tw,
    const float* __restrict__ tb, const float* __restrict__ hwgt,
    const float* __restrict__ hb, float* __restrict__ out)
{
  int x = blockIdx.x;                 // s*584 + hw*2 + half
  int s = x / 584;
  int rem = x % 584;
  int hw = rem >> 1, half = rem & 1;
  int j = threadIdx.x & 31, rr = threadIdx.x >> 5;
  int b = half * 8 + rr;
  const float* W;
  const float* Bi;
  if (hw < 256) { W = tw; Bi = tb; } else { W = hwgt; Bi = hb; }
  const ushort_t* row = x2 + ((size_t)(s * cHW + hw) * cB + b) * cC;
  float acc = Bi[j];
  for (int c = 0; c < cC; c += 4) {
    uint2 hv = *(const uint2*)(row + c);
    acc = fmaf(bf2f((ushort_t)(hv.x & 0xffff)), W[(c + 0) * 32 + j], acc);
    acc = fmaf(bf2f((ushort_t)(hv.x >> 16)),   W[(c + 1) * 32 + j], acc);
    acc = fmaf(bf2f((ushort_t)(hv.y & 0xffff)), W[(c + 2) * 32 + j], acc);
    acc = fmaf(bf2f((ushort_t)(hv.y >> 16)),   W[(c + 3) * 32 + j], acc);
  }
  int uh = j >> 3, uw = (j >> 1) & 3, uc = j & 1;
  size_t idx;
  if (hw < 256) {
    int th = hw >> 4, twi = hw & 15;
    idx = TX_OFF + ((((size_t)(s * cB + b)) * 2 + uc) * 64 + (th * 4 + uh)) * 64 + (twi * 4 + uw);
  } else {
    int h2 = hw - 256;
    int hh = h2 / 6, ww = h2 % 6;
    idx = HX_OFF + ((((size_t)(s * cB + b)) * 2 + uc) * 24 + (hh * 4 + uh)) * 24 + (ww * 4 + uw);
  }
  out[idx] = acc;
}

// ============ gx heads: mode / shape / color ============
__global__ __launch_bounds__(128) void k_gx(
    const ushort_t* __restrict__ x2,
    const float* __restrict__ mw, const float* __restrict__ mbi,
    const float* __restrict__ sw, const float* __restrict__ sbi,
    const float* __restrict__ cw, const float* __restrict__ cbi,
    float* __restrict__ out)
{
  int sb = blockIdx.x;              // s*16 + b
  int s = sb >> 4, b = sb & 15;
  __shared__ float rowL[256];
  const ushort_t* row = x2 + ((size_t)(s * cHW + 292) * cB + b) * cC;
  for (int i = threadIdx.x; i < 256; i += 128) rowL[i] = bf2f(row[i]);
  __syncthreads();
  int j = threadIdx.x;
  if (j < 100) {
    const float* W;
    const float* Bi;
    int jj, M;
    size_t off;
    if (j < 20)      { W = mw; Bi = mbi; jj = j;      M = 20; off = 0;     }
    else if (j < 84) { W = sw; Bi = sbi; jj = j - 20; M = 64; off = 5120;  }
    else             { W = cw; Bi = cbi; jj = j - 84; M = 16; off = 21504; }
    float acc = Bi[jj];
    for (int c = 0; c < 256; ++c) acc = fmaf(rowL[c], W[c * M + jj], acc);
    out[off + (size_t)sb * M + jj] = acc;
  }
}

extern "C" void kernel_launch(void* const* d_in, const int* in_sizes, int n_in,
                              void* d_out, int out_size, void* d_ws, size_t ws_size,
                              hipStream_t stream)
{
  const int*   tq       = (const int*)d_in[0];
  const int*   pad_q    = (const int*)d_in[1];
  const float* xk       = (const float*)d_in[2];
  const int*   tk       = (const int*)d_in[3];
  const int*   pad_k    = (const int*)d_in[4];
  const float* spatial  = (const float*)d_in[8];
  const float* temporal = (const float*)d_in[9];
  const float* ln1_g    = (const float*)d_in[10];
  const float* ln1_b    = (const float*)d_in[11];
  const float* wq       = (const float*)d_in[12];
  const float* bq       = (const float*)d_in[13];
  const float* wk       = (const float*)d_in[14];
  const float* bk       = (const float*)d_in[15];
  const float* wv       = (const float*)d_in[16];
  const float* bv       = (const float*)d_in[17];
  const float* wo       = (const float*)d_in[18];
  const float* bo       = (const float*)d_in[19];
  const float* ln2_g    = (const float*)d_in[20];
  const float* ln2_b    = (const float*)d_in[21];
  const float* w1       = (const float*)d_in[22];
  const float* b1       = (const float*)d_in[23];
  const float* w2       = (const float*)d_in[24];
  const float* b2       = (const float*)d_in[25];
  const float* table_w  = (const float*)d_in[26];
  const float* table_b  = (const float*)d_in[27];
  const float* hand_w   = (const float*)d_in[28];
  const float* hand_b   = (const float*)d_in[29];
  const float* mode_w   = (const float*)d_in[30];
  const float* mode_b   = (const float*)d_in[31];
  const float* shape_w  = (const float*)d_in[32];
  const float* shape_b  = (const float*)d_in[33];
  const float* color_w  = (const float*)d_in[34];
  const float* color_b  = (const float*)d_in[35];
  float* out = (float*)d_out;

  char* ws = (char*)d_ws;
  const size_t NB2 = (size_t)cNN * cC * sizeof(ushort_t);      // 38,404,096
  ushort_t* buf1 = (ushort_t*)ws;                              // a_swz -> xln_swz
  ushort_t* buf2 = (ushort_t*)(ws + NB2);                      // Q -> x -> x2 (in-place)
  char* p = ws + 2 * NB2;
  ushort_t* Kb  = (ushort_t*)p;  p += (size_t)cLK * cB * 256 * 2;
  ushort_t* Vb  = (ushort_t*)p;  p += (size_t)cLK * cB * 256 * 2;
  ushort_t* xkb = (ushort_t*)p;  p += (size_t)cLK * cB * 256 * 2;
  ushort_t* wqs = (ushort_t*)p;  p += 256 * 256 * 2;
  ushort_t* wks = (ushort_t*)p;  p += 256 * 256 * 2;
  ushort_t* wvs = (ushort_t*)p;  p += 256 * 256 * 2;
  ushort_t* wos = (ushort_t*)p;  p += 256 * 256 * 2;
  ushort_t* w1s = (ushort_t*)p;  p += 256 * 1024 * 2;
  ushort_t* w2s = (ushort_t*)p;  p += 1024 * 256 * 2;

  k_prep<<<896, 256, 0, stream>>>(xk, xkb, wq, wqs, wk, wks, wv, wvs,
                                  wo, wos, w1, w1s, w2, w2s);
  k_kv<<<dim3(32, 2), 256, 0, stream>>>(xkb, wks, wvs, bk, bv, Kb, Vb);
  k_qnp<<<cNN / 64, 256, 0, stream>>>(tq, spatial, temporal, ln1_g, ln1_b,
                                      wqs, bq, buf2);
  k_attn<<<dim3(10, cH, cB), 512, 0, stream>>>(buf2, Kb, Vb, tq, tk,
                                               pad_q, pad_k, buf1);
  k_wo<<<cNN / 64, 256, 0, stream>>>(buf1, wos, bo, tq, spatial, temporal,
                                     ln2_g, ln2_b, buf2, buf1);
  k_ffn<<<cNN / 64, 512, 0, stream>>>(buf1, w1s, b1, w2s, b2, buf2);
  k_th<<<cS * 292 * 2, 256, 0, stream>>>(buf2, table_w, table_b, hand_w, hand_b, out);
  k_gx<<<cS * cB, 128, 0, stream>>>(buf2, mode_w, mode_b, shape_w, shape_b,
                                    color_w, color_b, out);
}